// Round 1
// baseline (1367.244 us; speedup 1.0000x reference)
//
#include <hip/hip_runtime.h>
#include <hip/hip_bf16.h>
#include <math.h>

#define DIMX 1536
#define SEQ 2048
#define L2X 512
#define NHEAD 12
#define HDIM 128
#define NBLK 32
#define FFNX 8960
#define SCALE_ATT 0.08838834764831845f

typedef __attribute__((ext_vector_type(4))) float f4;
typedef __attribute__((ext_vector_type(4))) float f32x4;
typedef __attribute__((ext_vector_type(8))) short bf16x8;
typedef __attribute__((ext_vector_type(4))) unsigned short us4;
typedef __attribute__((ext_vector_type(8))) unsigned short us8;

static __device__ __forceinline__ unsigned short f2bf(float f) {
  union { float f; unsigned u; } v; v.f = f;
  unsigned r = v.u + 0x7FFFu + ((v.u >> 16) & 1u);
  return (unsigned short)(r >> 16);
}

// ---------------------------------------------------------------------------
// e = scale_shift_table + temb   (6 x 1536)
__global__ void __launch_bounds__(256) prep_e_kernel(const float* __restrict__ sst,
                                                     const float* __restrict__ temb,
                                                     float* __restrict__ e) {
  int i = blockIdx.x * 256 + threadIdx.x;
  if (i < 6 * DIMX) e[i] = sst[i] + temb[i];
}

// ---------------------------------------------------------------------------
// out[row] = LN(x[row]) * (a + add1) + b
__global__ void __launch_bounds__(256) ln_affine_kernel(
    const float* __restrict__ X, const float* __restrict__ a,
    const float* __restrict__ b, int add1, float* __restrict__ Out) {
  __shared__ float lds4[4];
  int row = blockIdx.x, t = threadIdx.x;
  const float* x = X + (size_t)row * DIMX;
  float v[6]; float s = 0.f;
#pragma unroll
  for (int i = 0; i < 6; i++) { v[i] = x[t + 256 * i]; s += v[i]; }
  for (int o = 1; o < 64; o <<= 1) s += __shfl_xor(s, o, 64);
  if ((t & 63) == 0) lds4[t >> 6] = s;
  __syncthreads();
  float mean = (lds4[0] + lds4[1] + lds4[2] + lds4[3]) * (1.f / DIMX);
  __syncthreads();
  float s2 = 0.f;
#pragma unroll
  for (int i = 0; i < 6; i++) { float c = v[i] - mean; s2 += c * c; }
  for (int o = 1; o < 64; o <<= 1) s2 += __shfl_xor(s2, o, 64);
  if ((t & 63) == 0) lds4[t >> 6] = s2;
  __syncthreads();
  float var = (lds4[0] + lds4[1] + lds4[2] + lds4[3]) * (1.f / DIMX);
  float rstd = rsqrtf(var + 1e-6f);
#pragma unroll
  for (int i = 0; i < 6; i++) {
    int c = t + 256 * i;
    float av = a[c] + (add1 ? 1.f : 0.f);
    Out[(size_t)row * DIMX + c] = (v[i] - mean) * rstd * av + b[c];
  }
}

// ---------------------------------------------------------------------------
// in-place: x = x * rsqrt(mean(x^2)+eps) * w ; optional interleaved RoPE per head
__global__ void __launch_bounds__(256) rms_rope_kernel(
    float* __restrict__ X, const float* __restrict__ wgt,
    const float* __restrict__ cosT, const float* __restrict__ sinT, int do_rope) {
  __shared__ float lds4[4];
  int row = blockIdx.x, t = threadIdx.x;
  float* x = X + (size_t)row * DIMX;
  int base = t * 6;
  float v[6]; float s2 = 0.f;
#pragma unroll
  for (int i = 0; i < 6; i++) { v[i] = x[base + i]; s2 += v[i] * v[i]; }
  for (int o = 1; o < 64; o <<= 1) s2 += __shfl_xor(s2, o, 64);
  if ((t & 63) == 0) lds4[t >> 6] = s2;
  __syncthreads();
  float ms = (lds4[0] + lds4[1] + lds4[2] + lds4[3]) * (1.f / DIMX);
  float rstd = rsqrtf(ms + 1e-6f);
#pragma unroll
  for (int i = 0; i < 6; i++) v[i] *= rstd * wgt[base + i];
  if (do_rope) {
#pragma unroll
    for (int j = 0; j < 3; j++) {
      int c = base + 2 * j;
      int pi = (c & (HDIM - 1)) >> 1;
      float cs = cosT[row * (HDIM / 2) + pi], sn = sinT[row * (HDIM / 2) + pi];
      float ev = v[2 * j], ov = v[2 * j + 1];
      v[2 * j] = ev * cs - ov * sn;
      v[2 * j + 1] = ov * cs + ev * sn;
    }
  }
#pragma unroll
  for (int i = 0; i < 6; i++) x[base + i] = v[i];
}

// ---------------------------------------------------------------------------
// generic bf16-MFMA GEMM: C(MxN) = A(MxK,f32) @ B(KxN,f32) + bias [; gelu]
#define GST 56  // LDS row stride in bf16 elems (32 + 24 pad) -> 112B, 16B aligned
__global__ void __launch_bounds__(256) gemm_kernel(
    const float* __restrict__ A, const float* __restrict__ B,
    const float* __restrict__ bias, float* __restrict__ C,
    int M, int N, int K, int do_gelu) {
  __shared__ unsigned short As[128 * GST];
  __shared__ unsigned short Bs[128 * GST];
  const int tid = threadIdx.x;
  const int lane = tid & 63;
  const int w = tid >> 6;
  const int wr = w >> 1, wc = w & 1;
  const int fr = lane & 15;
  const int k8 = (lane >> 4) * 8;
  const int q4 = (lane >> 4) * 4;
  const int tm = blockIdx.y * 128;
  const int tn = blockIdx.x * 128;

  f32x4 acc[4][4];
#pragma unroll
  for (int m = 0; m < 4; m++)
#pragma unroll
    for (int n = 0; n < 4; n++) acc[m][n] = (f32x4)(0.f);

  const int bn = tid & 127;
  const int bkh = (tid >> 7) * 16;

  for (int k0 = 0; k0 < K; k0 += 32) {
    // stage A (128x32): 4 float4 per thread
#pragma unroll
    for (int i = 0; i < 4; i++) {
      int s = tid + 256 * i;
      int row = s >> 3;
      int kq = (s & 7) * 4;
      f4 v = *reinterpret_cast<const f4*>(&A[(size_t)(tm + row) * K + k0 + kq]);
      us4 h;
      h[0] = f2bf(v[0]); h[1] = f2bf(v[1]); h[2] = f2bf(v[2]); h[3] = f2bf(v[3]);
      *reinterpret_cast<us4*>(&As[row * GST + kq]) = h;
    }
    // stage B (32x128) transposed into Bs[n][k]
#pragma unroll
    for (int j = 0; j < 2; j++) {
      us8 hv;
#pragma unroll
      for (int q = 0; q < 8; q++)
        hv[q] = f2bf(B[(size_t)(k0 + bkh + j * 8 + q) * N + tn + bn]);
      *reinterpret_cast<us8*>(&Bs[bn * GST + bkh + j * 8]) = hv;
    }
    __syncthreads();
    bf16x8 af[4], bfv[4];
#pragma unroll
    for (int m = 0; m < 4; m++)
      af[m] = *reinterpret_cast<const bf16x8*>(&As[(wr * 64 + m * 16 + fr) * GST + k8]);
#pragma unroll
    for (int n = 0; n < 4; n++)
      bfv[n] = *reinterpret_cast<const bf16x8*>(&Bs[(wc * 64 + n * 16 + fr) * GST + k8]);
#pragma unroll
    for (int m = 0; m < 4; m++)
#pragma unroll
      for (int n = 0; n < 4; n++)
        acc[m][n] = __builtin_amdgcn_mfma_f32_16x16x32_bf16(af[m], bfv[n], acc[m][n], 0, 0, 0);
    __syncthreads();
  }
#pragma unroll
  for (int m = 0; m < 4; m++) {
#pragma unroll
    for (int n = 0; n < 4; n++) {
      int col = tn + wc * 64 + n * 16 + fr;
      float bv = bias ? bias[col] : 0.f;
#pragma unroll
      for (int r = 0; r < 4; r++) {
        int row = tm + wr * 64 + m * 16 + q4 + r;
        float v = acc[m][n][r] + bv;
        if (do_gelu)
          v = 0.5f * v * (1.f + tanhf(0.7978845608028654f * (v + 0.044715f * v * v * v)));
        C[(size_t)row * N + col] = v;
      }
    }
  }
}

// ---------------------------------------------------------------------------
// block-sparse flash attention over 8 key-blocks of 64 tokens.
// grid (qblocks=32, heads=12), 256 threads.  idx==null -> blocks 0..7 (cross).
// G/CB != null -> out = O + G*CB[qblock]  (fine + gate*coarse)
__global__ void __launch_bounds__(256) attn_kernel(
    const float* __restrict__ Q, const float* __restrict__ Kx,
    const float* __restrict__ V, const int* __restrict__ idx,
    const float* __restrict__ G, const float* __restrict__ CB,
    float* __restrict__ Out) {
  __shared__ unsigned short q_s[64 * 136];
  __shared__ unsigned short k_s[64 * 136];
  __shared__ unsigned short vT_s[128 * 72];
  __shared__ unsigned short p_s[64 * 72];
  __shared__ float red[4 * 64];
  __shared__ float m_run[64], l_run[64], alpha_s[64];

  const int qb = blockIdx.x;
  const int h = blockIdx.y;
  const int tid = threadIdx.x;
  const int lane = tid & 63;
  const int w = tid >> 6;
  const int fr = lane & 15;
  const int k8 = (lane >> 4) * 8;
  const int q4 = (lane >> 4) * 4;

  // stage Q block (64 x 128)
#pragma unroll
  for (int i = 0; i < 8; i++) {
    int s = tid + 256 * i;
    int row = s >> 5, cq = (s & 31) * 4;
    f4 v = *reinterpret_cast<const f4*>(&Q[(size_t)(qb * 64 + row) * DIMX + h * HDIM + cq]);
    us4 hh; hh[0] = f2bf(v[0]); hh[1] = f2bf(v[1]); hh[2] = f2bf(v[2]); hh[3] = f2bf(v[3]);
    *reinterpret_cast<us4*>(&q_s[row * 136 + cq]) = hh;
  }
  if (tid < 64) { m_run[tid] = -1e30f; l_run[tid] = 0.f; }

  f32x4 acc_o[4][2];
#pragma unroll
  for (int m = 0; m < 4; m++)
#pragma unroll
    for (int n = 0; n < 2; n++) acc_o[m][n] = (f32x4)(0.f);

  for (int ib = 0; ib < 8; ib++) {
    int blk = idx ? idx[(h * NBLK + qb) * 8 + ib] : ib;
    __syncthreads();  // prev iteration done with k_s/vT_s/p_s ; q_s staged ; stats init
    // stage K block (64x128)
#pragma unroll
    for (int i = 0; i < 8; i++) {
      int s = tid + 256 * i;
      int row = s >> 5, cq = (s & 31) * 4;
      f4 v = *reinterpret_cast<const f4*>(&Kx[(size_t)(blk * 64 + row) * DIMX + h * HDIM + cq]);
      us4 hh; hh[0] = f2bf(v[0]); hh[1] = f2bf(v[1]); hh[2] = f2bf(v[2]); hh[3] = f2bf(v[3]);
      *reinterpret_cast<us4*>(&k_s[row * 136 + cq]) = hh;
    }
    // stage V^T : vT_s[d][tok]
    {
      int d = tid & 127, th = (tid >> 7) * 32;
#pragma unroll
      for (int j = 0; j < 4; j++) {
        us8 hv;
#pragma unroll
        for (int qq = 0; qq < 8; qq++)
          hv[qq] = f2bf(V[(size_t)(blk * 64 + th + j * 8 + qq) * DIMX + h * HDIM + d]);
        *reinterpret_cast<us8*>(&vT_s[d * 72 + th + j * 8]) = hv;
      }
    }
    __syncthreads();
    // S = Q K^T  (wave w: key cols w*16 .. w*16+15)
    f32x4 accs[4];
#pragma unroll
    for (int m = 0; m < 4; m++) accs[m] = (f32x4)(0.f);
#pragma unroll
    for (int kk = 0; kk < 128; kk += 32) {
      bf16x8 bfr = *reinterpret_cast<const bf16x8*>(&k_s[(w * 16 + fr) * 136 + kk + k8]);
#pragma unroll
      for (int m = 0; m < 4; m++) {
        bf16x8 afr = *reinterpret_cast<const bf16x8*>(&q_s[(m * 16 + fr) * 136 + kk + k8]);
        accs[m] = __builtin_amdgcn_mfma_f32_16x16x32_bf16(afr, bfr, accs[m], 0, 0, 0);
      }
    }
    // scale + per-wave row-max over its 16 cols
#pragma unroll
    for (int m = 0; m < 4; m++) {
#pragma unroll
      for (int r = 0; r < 4; r++) {
        accs[m][r] *= SCALE_ATT;
        float v = accs[m][r];
        for (int o = 1; o < 16; o <<= 1) v = fmaxf(v, __shfl_xor(v, o, 64));
        if (fr == 0) red[w * 64 + m * 16 + q4 + r] = v;
      }
    }
    __syncthreads();
    if (tid < 64) {
      float bm = fmaxf(fmaxf(red[tid], red[64 + tid]), fmaxf(red[128 + tid], red[192 + tid]));
      float mo = m_run[tid];
      float mn = fmaxf(mo, bm);
      float al = __expf(mo - mn);
      alpha_s[tid] = al;
      m_run[tid] = mn;
      l_run[tid] *= al;
    }
    __syncthreads();
    // P = exp(S - m_new), write bf16, partial row sums
#pragma unroll
    for (int m = 0; m < 4; m++) {
#pragma unroll
      for (int r = 0; r < 4; r++) {
        int row = m * 16 + q4 + r;
        float p = __expf(accs[m][r] - m_run[row]);
        p_s[row * 72 + w * 16 + fr] = f2bf(p);
        float sv = p;
        for (int o = 1; o < 16; o <<= 1) sv += __shfl_xor(sv, o, 64);
        if (fr == 0) red[w * 64 + row] = sv;
      }
    }
    // rescale O accumulators by alpha
#pragma unroll
    for (int m = 0; m < 4; m++) {
      float a0 = alpha_s[m * 16 + q4 + 0];
      float a1 = alpha_s[m * 16 + q4 + 1];
      float a2 = alpha_s[m * 16 + q4 + 2];
      float a3 = alpha_s[m * 16 + q4 + 3];
#pragma unroll
      for (int n = 0; n < 2; n++) {
        acc_o[m][n][0] *= a0; acc_o[m][n][1] *= a1;
        acc_o[m][n][2] *= a2; acc_o[m][n][3] *= a3;
      }
    }
    __syncthreads();  // p_s visible; red sums ready
    if (tid < 64) l_run[tid] += red[tid] + red[64 + tid] + red[128 + tid] + red[192 + tid];
    // PV : O += P @ V   (wave w: out dims w*32 .. w*32+31)
#pragma unroll
    for (int kk = 0; kk < 64; kk += 32) {
      bf16x8 pa[4];
#pragma unroll
      for (int m = 0; m < 4; m++)
        pa[m] = *reinterpret_cast<const bf16x8*>(&p_s[(m * 16 + fr) * 72 + kk + k8]);
#pragma unroll
      for (int n = 0; n < 2; n++) {
        bf16x8 vb = *reinterpret_cast<const bf16x8*>(&vT_s[(w * 32 + n * 16 + fr) * 72 + kk + k8]);
#pragma unroll
        for (int m = 0; m < 4; m++)
          acc_o[m][n] = __builtin_amdgcn_mfma_f32_16x16x32_bf16(pa[m], vb, acc_o[m][n], 0, 0, 0);
      }
    }
  }
  __syncthreads();  // final l_run visible
#pragma unroll
  for (int m = 0; m < 4; m++) {
#pragma unroll
    for (int n = 0; n < 2; n++) {
#pragma unroll
      for (int r = 0; r < 4; r++) {
        int row = m * 16 + q4 + r;
        int srow = qb * 64 + row;
        int d = w * 32 + n * 16 + fr;
        float o = acc_o[m][n][r] / l_run[row];
        size_t oi = (size_t)srow * DIMX + h * HDIM + d;
        if (G) o += G[oi] * CB[(size_t)qb * DIMX + h * HDIM + d];
        Out[oi] = o;
      }
    }
  }
}

// ---------------------------------------------------------------------------
// block means: out[(n*12+h)*128+d] = mean over 64 tokens
__global__ void __launch_bounds__(128) block_mean_kernel(const float* __restrict__ X,
                                                         float* __restrict__ Outc) {
  int n = blockIdx.x, h = blockIdx.y, d = threadIdx.x;
  float s = 0.f;
  for (int t = 0; t < 64; t++) s += X[(size_t)(n * 64 + t) * DIMX + h * HDIM + d];
  Outc[(n * NHEAD + h) * HDIM + d] = s * (1.f / 64.f);
}

// per head: pc = softmax(qc kc^T * scale), topk-8 indices
__global__ void __launch_bounds__(256) coarse_attn_kernel(const float* __restrict__ qc,
                                                          const float* __restrict__ kc,
                                                          float* __restrict__ pc,
                                                          int* __restrict__ idxout) {
  int h = blockIdx.x, t = threadIdx.x;
  __shared__ float sm[32][32];
  for (int p = t; p < 1024; p += 256) {
    int n = p >> 5, m = p & 31;
    float dot = 0.f;
    for (int d = 0; d < HDIM; d++)
      dot += qc[n * DIMX + h * HDIM + d] * kc[m * DIMX + h * HDIM + d];
    sm[n][m] = dot * SCALE_ATT;
  }
  __syncthreads();
  if (t < 32) {
    int n = t;
    float mx = -1e30f;
#pragma unroll
    for (int m = 0; m < 32; m++) mx = fmaxf(mx, sm[n][m]);
    float pv[32]; float ssum = 0.f;
#pragma unroll
    for (int m = 0; m < 32; m++) { pv[m] = __expf(sm[n][m] - mx); ssum += pv[m]; }
    float inv = 1.f / ssum;
#pragma unroll
    for (int m = 0; m < 32; m++) { pv[m] *= inv; pc[(h * 32 + n) * 32 + m] = pv[m]; }
    unsigned chosen = 0;
    for (int i = 0; i < 8; i++) {
      float best = -1.f; int bi = 0;
#pragma unroll
      for (int m = 0; m < 32; m++)
        if (!((chosen >> m) & 1u) && pv[m] > best) { best = pv[m]; bi = m; }
      chosen |= 1u << bi;
      idxout[(h * 32 + n) * 8 + i] = bi;
    }
  }
}

// coarse context: cb[n,h,:] = sum_m pc[h,n,m] * vc[m,h,:]
__global__ void __launch_bounds__(128) coarse_ctx_kernel(const float* __restrict__ pc,
                                                         const float* __restrict__ vc,
                                                         float* __restrict__ cb) {
  int n = blockIdx.x, h = blockIdx.y, d = threadIdx.x;
  float s = 0.f;
  for (int m = 0; m < 32; m++)
    s += pc[(h * 32 + n) * 32 + m] * vc[(m * NHEAD + h) * HDIM + d];
  cb[(n * NHEAD + h) * HDIM + d] = s;
}

// O = A + g[d]*B   (g null -> 1)
__global__ void __launch_bounds__(256) addmul_kernel(const float* __restrict__ A,
                                                     const float* __restrict__ Bv,
                                                     const float* __restrict__ g,
                                                     float* __restrict__ O, int n) {
  for (int i = blockIdx.x * 256 + threadIdx.x; i < n; i += gridDim.x * 256) {
    float gv = g ? g[i % DIMX] : 1.f;
    O[i] = A[i] + gv * Bv[i];
  }
}

// ---------------------------------------------------------------------------
extern "C" void kernel_launch(void* const* d_in, const int* in_sizes, int n_in,
                              void* d_out, int out_size, void* d_ws, size_t ws_size,
                              hipStream_t stream) {
  (void)in_sizes; (void)n_in; (void)out_size; (void)ws_size;
  const float* hidden = (const float*)d_in[0];
  const float* enc    = (const float*)d_in[1];
  const float* temb   = (const float*)d_in[2];
  const float* cosT   = (const float*)d_in[3];
  const float* sinT   = (const float*)d_in[4];
  const float* sst    = (const float*)d_in[5];
  const float* Wq = (const float*)d_in[6];   const float* bq = (const float*)d_in[7];
  const float* Wk = (const float*)d_in[8];   const float* bk = (const float*)d_in[9];
  const float* Wv = (const float*)d_in[10];  const float* bv = (const float*)d_in[11];
  const float* Wg = (const float*)d_in[12];  const float* bg = (const float*)d_in[13];
  const float* Wo = (const float*)d_in[14];  const float* bo = (const float*)d_in[15];
  const float* qnw = (const float*)d_in[16]; const float* knw = (const float*)d_in[17];
  const float* saw = (const float*)d_in[18]; const float* sab = (const float*)d_in[19];
  const float* cWq = (const float*)d_in[20]; const float* cbq = (const float*)d_in[21];
  const float* cWk = (const float*)d_in[22]; const float* cbk = (const float*)d_in[23];
  const float* cWv = (const float*)d_in[24]; const float* cbv = (const float*)d_in[25];
  const float* cWo = (const float*)d_in[26]; const float* cbo = (const float*)d_in[27];
  const float* cqnw = (const float*)d_in[28]; const float* cknw = (const float*)d_in[29];
  const float* W1 = (const float*)d_in[30];  const float* b1 = (const float*)d_in[31];
  const float* W2 = (const float*)d_in[32];  const float* b2 = (const float*)d_in[33];

  char* ws = (char*)d_ws;
  size_t off = 0;
  auto alloc = [&](size_t bytes) -> void* {
    void* p = ws + off;
    off += (bytes + 255) & ~(size_t)255;
    return p;
  };
  const size_t SD = (size_t)SEQ * DIMX * 4;
  float* e     = (float*)alloc(6 * DIMX * 4);
  float* normb = (float*)alloc(SD);
  float* qb_   = (float*)alloc(SD);
  float* kb_   = (float*)alloc(SD);
  float* vb_   = (float*)alloc(SD);
  float* gb_   = (float*)alloc(SD);
  float* qc    = (float*)alloc((size_t)NBLK * DIMX * 4);
  float* kc    = (float*)alloc((size_t)NBLK * DIMX * 4);
  float* vc    = (float*)alloc((size_t)NBLK * DIMX * 4);
  float* pc    = (float*)alloc(NHEAD * 32 * 32 * 4);
  int*   idx   = (int*)alloc(NHEAD * 32 * 8 * 4);
  float* cb    = (float*)alloc((size_t)NBLK * DIMX * 4);
  float* mix   = (float*)alloc(SD);
  float* proj  = (float*)alloc(SD);
  float* res   = (float*)alloc(SD);
  float* ffh   = (float*)alloc((size_t)SEQ * FFNX * 4);
  float* outf  = (float*)d_out;

  prep_e_kernel<<<36, 256, 0, stream>>>(sst, temb, e);
  // norm_hs = LN(hidden)*(1+scale_msa)+shift_msa
  ln_affine_kernel<<<SEQ, 256, 0, stream>>>(hidden, e + DIMX, e, 1, normb);
  dim3 g16(DIMX / 128, SEQ / 128);
  gemm_kernel<<<g16, 256, 0, stream>>>(normb, Wq, bq, qb_, SEQ, DIMX, DIMX, 0);
  gemm_kernel<<<g16, 256, 0, stream>>>(normb, Wk, bk, kb_, SEQ, DIMX, DIMX, 0);
  gemm_kernel<<<g16, 256, 0, stream>>>(normb, Wv, bv, vb_, SEQ, DIMX, DIMX, 0);
  gemm_kernel<<<g16, 256, 0, stream>>>(normb, Wg, bg, gb_, SEQ, DIMX, DIMX, 0);
  rms_rope_kernel<<<SEQ, 256, 0, stream>>>(qb_, qnw, cosT, sinT, 1);
  rms_rope_kernel<<<SEQ, 256, 0, stream>>>(kb_, knw, cosT, sinT, 1);
  dim3 gbm(NBLK, NHEAD);
  block_mean_kernel<<<gbm, 128, 0, stream>>>(qb_, qc);
  block_mean_kernel<<<gbm, 128, 0, stream>>>(kb_, kc);
  block_mean_kernel<<<gbm, 128, 0, stream>>>(vb_, vc);
  coarse_attn_kernel<<<NHEAD, 256, 0, stream>>>(qc, kc, pc, idx);
  coarse_ctx_kernel<<<gbm, 128, 0, stream>>>(pc, vc, cb);
  // fine block-sparse attention fused with + g*coarse
  attn_kernel<<<dim3(NBLK, NHEAD), 256, 0, stream>>>(qb_, kb_, vb_, idx, gb_, cb, mix);
  gemm_kernel<<<g16, 256, 0, stream>>>(mix, Wo, bo, proj, SEQ, DIMX, DIMX, 0);
  addmul_kernel<<<2048, 256, 0, stream>>>(hidden, proj, e + 2 * DIMX, res, SEQ * DIMX);
  // cross attention
  ln_affine_kernel<<<SEQ, 256, 0, stream>>>(res, saw, sab, 0, normb);
  gemm_kernel<<<g16, 256, 0, stream>>>(normb, cWq, cbq, qb_, SEQ, DIMX, DIMX, 0);
  rms_rope_kernel<<<SEQ, 256, 0, stream>>>(qb_, cqnw, cosT, sinT, 0);
  dim3 g4(DIMX / 128, L2X / 128);
  gemm_kernel<<<g4, 256, 0, stream>>>(enc, cWk, cbk, kb_, L2X, DIMX, DIMX, 0);
  rms_rope_kernel<<<L2X, 256, 0, stream>>>(kb_, cknw, cosT, sinT, 0);
  gemm_kernel<<<g4, 256, 0, stream>>>(enc, cWv, cbv, vb_, L2X, DIMX, DIMX, 0);
  attn_kernel<<<dim3(NBLK, NHEAD), 256, 0, stream>>>(qb_, kb_, vb_, nullptr, nullptr, nullptr, gb_);
  gemm_kernel<<<g16, 256, 0, stream>>>(gb_, cWo, cbo, proj, SEQ, DIMX, DIMX, 0);
  addmul_kernel<<<2048, 256, 0, stream>>>(res, proj, nullptr, outf, SEQ * DIMX);
  // FFN
  ln_affine_kernel<<<SEQ, 256, 0, stream>>>(outf, e + 4 * DIMX, e + 3 * DIMX, 1, normb);
  dim3 gff(FFNX / 128, SEQ / 128);
  gemm_kernel<<<gff, 256, 0, stream>>>(normb, W1, b1, ffh, SEQ, FFNX, DIMX, 1);
  gemm_kernel<<<g16, 256, 0, stream>>>(ffh, W2, b2, proj, SEQ, DIMX, FFNX, 0);
  addmul_kernel<<<2048, 256, 0, stream>>>(outf, proj, e + 5 * DIMX, outf, SEQ * DIMX);
}

// Round 2
// 1010.143 us; speedup vs baseline: 1.3535x; 1.3535x over previous
//
#include <hip/hip_runtime.h>
#include <hip/hip_bf16.h>
#include <math.h>

#define DIMX 1536
#define SEQ 2048
#define L2X 512
#define NHEAD 12
#define HDIM 128
#define NBLK 32
#define FFNX 8960
#define SCALE_ATT 0.08838834764831845f

typedef __attribute__((ext_vector_type(4))) float f4;
typedef __attribute__((ext_vector_type(4))) float f32x4;
typedef __attribute__((ext_vector_type(8))) short bf16x8;
typedef __attribute__((ext_vector_type(4))) unsigned short us4;
typedef __attribute__((ext_vector_type(8))) unsigned short us8;

static __device__ __forceinline__ unsigned short f2bf(float f) {
  union { float f; unsigned u; } v; v.f = f;
  unsigned r = v.u + 0x7FFFu + ((v.u >> 16) & 1u);
  return (unsigned short)(r >> 16);
}

static __device__ __forceinline__ void gl_lds16(const unsigned short* g, unsigned short* l) {
  __builtin_amdgcn_global_load_lds(
      (const __attribute__((address_space(1))) void*)g,
      (__attribute__((address_space(3))) void*)l, 16, 0, 0);
}

// ---------------------------------------------------------------------------
__global__ void __launch_bounds__(256) prep_e_kernel(const float* __restrict__ sst,
                                                     const float* __restrict__ temb,
                                                     float* __restrict__ e) {
  int i = blockIdx.x * 256 + threadIdx.x;
  if (i < 6 * DIMX) e[i] = sst[i] + temb[i];
}

// ---------------------------------------------------------------------------
// W[K][N] f32 -> Wt[N][K] bf16   (32x32 tiles via LDS)
__global__ void __launch_bounds__(256) pack_t_kernel(const float* __restrict__ W,
                                                     unsigned short* __restrict__ Wt,
                                                     int K, int N) {
  __shared__ float t[32][33];
  int n0 = blockIdx.x * 32, k0 = blockIdx.y * 32;
  int tx = threadIdx.x & 31, ty = threadIdx.x >> 5;
#pragma unroll
  for (int i = 0; i < 4; i++)
    t[ty * 4 + i][tx] = W[(size_t)(k0 + ty * 4 + i) * N + n0 + tx];
  __syncthreads();
#pragma unroll
  for (int i = 0; i < 4; i++)
    Wt[(size_t)(n0 + ty * 4 + i) * K + k0 + tx] = f2bf(t[tx][ty * 4 + i]);
}

// f32 -> bf16 elementwise
__global__ void __launch_bounds__(256) pack_cvt_kernel(const float* __restrict__ X,
                                                       unsigned short* __restrict__ Y, int n) {
  int i = blockIdx.x * 256 + threadIdx.x;
  if (i < n) {
    f4 v = *reinterpret_cast<const f4*>(&X[(size_t)i * 4]);
    us4 h; h[0] = f2bf(v[0]); h[1] = f2bf(v[1]); h[2] = f2bf(v[2]); h[3] = f2bf(v[3]);
    *reinterpret_cast<us4*>(&Y[(size_t)i * 4]) = h;
  }
  (void)n;
}

// ---------------------------------------------------------------------------
// out[row] = LN(x[row]) * (a + add1) + b   -> bf16
__global__ void __launch_bounds__(256) ln_affine_kernel(
    const float* __restrict__ X, const float* __restrict__ a,
    const float* __restrict__ b, int add1, unsigned short* __restrict__ Out) {
  __shared__ float lds4[4];
  int row = blockIdx.x, t = threadIdx.x;
  const float* x = X + (size_t)row * DIMX;
  float v[6]; float s = 0.f;
#pragma unroll
  for (int i = 0; i < 6; i++) { v[i] = x[t + 256 * i]; s += v[i]; }
  for (int o = 1; o < 64; o <<= 1) s += __shfl_xor(s, o, 64);
  if ((t & 63) == 0) lds4[t >> 6] = s;
  __syncthreads();
  float mean = (lds4[0] + lds4[1] + lds4[2] + lds4[3]) * (1.f / DIMX);
  __syncthreads();
  float s2 = 0.f;
#pragma unroll
  for (int i = 0; i < 6; i++) { float c = v[i] - mean; s2 += c * c; }
  for (int o = 1; o < 64; o <<= 1) s2 += __shfl_xor(s2, o, 64);
  if ((t & 63) == 0) lds4[t >> 6] = s2;
  __syncthreads();
  float var = (lds4[0] + lds4[1] + lds4[2] + lds4[3]) * (1.f / DIMX);
  float rstd = rsqrtf(var + 1e-6f);
#pragma unroll
  for (int i = 0; i < 6; i++) {
    int c = t + 256 * i;
    float av = a[c] + (add1 ? 1.f : 0.f);
    Out[(size_t)row * DIMX + c] = f2bf((v[i] - mean) * rstd * av + b[c]);
  }
}

// ---------------------------------------------------------------------------
// in-place f32: x = x * rsqrt(mean(x^2)+eps) * w ; optional interleaved RoPE
__global__ void __launch_bounds__(256) rms_rope_kernel(
    float* __restrict__ X, const float* __restrict__ wgt,
    const float* __restrict__ cosT, const float* __restrict__ sinT, int do_rope) {
  __shared__ float lds4[4];
  int row = blockIdx.x, t = threadIdx.x;
  float* x = X + (size_t)row * DIMX;
  int base = t * 6;
  float v[6]; float s2 = 0.f;
#pragma unroll
  for (int i = 0; i < 6; i++) { v[i] = x[base + i]; s2 += v[i] * v[i]; }
  for (int o = 1; o < 64; o <<= 1) s2 += __shfl_xor(s2, o, 64);
  if ((t & 63) == 0) lds4[t >> 6] = s2;
  __syncthreads();
  float ms = (lds4[0] + lds4[1] + lds4[2] + lds4[3]) * (1.f / DIMX);
  float rstd = rsqrtf(ms + 1e-6f);
#pragma unroll
  for (int i = 0; i < 6; i++) v[i] *= rstd * wgt[base + i];
  if (do_rope) {
#pragma unroll
    for (int j = 0; j < 3; j++) {
      int c = base + 2 * j;
      int pi = (c & (HDIM - 1)) >> 1;
      float cs = cosT[row * (HDIM / 2) + pi], sn = sinT[row * (HDIM / 2) + pi];
      float ev = v[2 * j], ov = v[2 * j + 1];
      v[2 * j] = ev * cs - ov * sn;
      v[2 * j + 1] = ov * cs + ev * sn;
    }
  }
#pragma unroll
  for (int i = 0; i < 6; i++) x[base + i] = v[i];
}

// ---------------------------------------------------------------------------
// m97-structure GEMM: C(MxN) = A(MxK,bf16) @ Bt(NxK,bf16)^T + bias
// 128x128 tile, BK=32, 4 waves, global_load_lds width=16, linear LDS.
template<int OUT_BF16, int DO_GELU>
__global__ void __launch_bounds__(256) gemm_bf16(
    const unsigned short* __restrict__ A,
    const unsigned short* __restrict__ Bt,
    const float* __restrict__ bias,
    float* __restrict__ Cf, unsigned short* __restrict__ Cb,
    int M, int N, int K) {
  __shared__ __align__(16) unsigned short As[128 * 32];
  __shared__ __align__(16) unsigned short Bs[128 * 32];
  const int tid = threadIdx.x;
  const int lane = tid & 63;
  const int w = tid >> 6;
  const int wr = w >> 1, wc = w & 1;
  const int fr = lane & 15;
  const int k8 = (lane >> 4) * 8;
  const int q4 = (lane >> 4) * 4;
  const int tm = blockIdx.y * 128;
  const int tn = blockIdx.x * 128;

  const int srow = w * 16 + (lane >> 2);  // 0..63
  const int skel = (lane & 3) * 8;        // k element offset of this lane's 16B
  const unsigned short* aG0 = A + (size_t)(tm + srow) * K + skel;
  const unsigned short* aG1 = A + (size_t)(tm + 64 + srow) * K + skel;
  const unsigned short* bG0 = Bt + (size_t)(tn + srow) * K + skel;
  const unsigned short* bG1 = Bt + (size_t)(tn + 64 + srow) * K + skel;
  unsigned short* aL0 = As + w * 512;
  unsigned short* aL1 = As + 2048 + w * 512;
  unsigned short* bL0 = Bs + w * 512;
  unsigned short* bL1 = Bs + 2048 + w * 512;

  f32x4 acc[4][4];
#pragma unroll
  for (int m = 0; m < 4; m++)
#pragma unroll
    for (int n = 0; n < 4; n++) acc[m][n] = (f32x4)(0.f);

  for (int k0 = 0; k0 < K; k0 += 32) {
    gl_lds16(aG0 + k0, aL0);
    gl_lds16(aG1 + k0, aL1);
    gl_lds16(bG0 + k0, bL0);
    gl_lds16(bG1 + k0, bL1);
    __syncthreads();
    bf16x8 af[4], bfv[4];
#pragma unroll
    for (int m = 0; m < 4; m++)
      af[m] = *reinterpret_cast<const bf16x8*>(&As[(wr * 64 + m * 16 + fr) * 32 + k8]);
#pragma unroll
    for (int n = 0; n < 4; n++)
      bfv[n] = *reinterpret_cast<const bf16x8*>(&Bs[(wc * 64 + n * 16 + fr) * 32 + k8]);
#pragma unroll
    for (int m = 0; m < 4; m++)
#pragma unroll
      for (int n = 0; n < 4; n++)
        acc[m][n] = __builtin_amdgcn_mfma_f32_16x16x32_bf16(af[m], bfv[n], acc[m][n], 0, 0, 0);
    __syncthreads();
  }
#pragma unroll
  for (int m = 0; m < 4; m++) {
#pragma unroll
    for (int n = 0; n < 4; n++) {
      int col = tn + wc * 64 + n * 16 + fr;
      float bv = bias ? bias[col] : 0.f;
#pragma unroll
      for (int r = 0; r < 4; r++) {
        int row = tm + wr * 64 + m * 16 + q4 + r;
        float v = acc[m][n][r] + bv;
        if (DO_GELU) {
          float u = 1.5957691216057308f * (v + 0.044715f * v * v * v);  // 2*0.79788456*(...)
          v = v / (1.f + __expf(-u));
        }
        if (OUT_BF16)
          Cb[(size_t)row * N + col] = f2bf(v);
        else
          Cf[(size_t)row * N + col] = v;
      }
    }
  }
}

// ---------------------------------------------------------------------------
// block-sparse flash attention over 8 key-blocks of 64 tokens. bf16 output.
__global__ void __launch_bounds__(256) attn_kernel(
    const float* __restrict__ Q, const float* __restrict__ Kx,
    const float* __restrict__ V, const int* __restrict__ idx,
    const float* __restrict__ G, const float* __restrict__ CB,
    unsigned short* __restrict__ Out) {
  __shared__ unsigned short q_s[64 * 136];
  __shared__ unsigned short k_s[64 * 136];
  __shared__ unsigned short vT_s[128 * 72];
  __shared__ unsigned short p_s[64 * 72];
  __shared__ float red[4 * 64];
  __shared__ float m_run[64], l_run[64], alpha_s[64];

  const int qb = blockIdx.x;
  const int h = blockIdx.y;
  const int tid = threadIdx.x;
  const int lane = tid & 63;
  const int w = tid >> 6;
  const int fr = lane & 15;
  const int k8 = (lane >> 4) * 8;
  const int q4 = (lane >> 4) * 4;

#pragma unroll
  for (int i = 0; i < 8; i++) {
    int s = tid + 256 * i;
    int row = s >> 5, cq = (s & 31) * 4;
    f4 v = *reinterpret_cast<const f4*>(&Q[(size_t)(qb * 64 + row) * DIMX + h * HDIM + cq]);
    us4 hh; hh[0] = f2bf(v[0]); hh[1] = f2bf(v[1]); hh[2] = f2bf(v[2]); hh[3] = f2bf(v[3]);
    *reinterpret_cast<us4*>(&q_s[row * 136 + cq]) = hh;
  }
  if (tid < 64) { m_run[tid] = -1e30f; l_run[tid] = 0.f; }

  f32x4 acc_o[4][2];
#pragma unroll
  for (int m = 0; m < 4; m++)
#pragma unroll
    for (int n = 0; n < 2; n++) acc_o[m][n] = (f32x4)(0.f);

  for (int ib = 0; ib < 8; ib++) {
    int blk = idx ? idx[(h * NBLK + qb) * 8 + ib] : ib;
    __syncthreads();
#pragma unroll
    for (int i = 0; i < 8; i++) {
      int s = tid + 256 * i;
      int row = s >> 5, cq = (s & 31) * 4;
      f4 v = *reinterpret_cast<const f4*>(&Kx[(size_t)(blk * 64 + row) * DIMX + h * HDIM + cq]);
      us4 hh; hh[0] = f2bf(v[0]); hh[1] = f2bf(v[1]); hh[2] = f2bf(v[2]); hh[3] = f2bf(v[3]);
      *reinterpret_cast<us4*>(&k_s[row * 136 + cq]) = hh;
    }
    {
      int d = tid & 127, th = (tid >> 7) * 32;
#pragma unroll
      for (int j = 0; j < 4; j++) {
        us8 hv;
#pragma unroll
        for (int qq = 0; qq < 8; qq++)
          hv[qq] = f2bf(V[(size_t)(blk * 64 + th + j * 8 + qq) * DIMX + h * HDIM + d]);
        *reinterpret_cast<us8*>(&vT_s[d * 72 + th + j * 8]) = hv;
      }
    }
    __syncthreads();
    f32x4 accs[4];
#pragma unroll
    for (int m = 0; m < 4; m++) accs[m] = (f32x4)(0.f);
#pragma unroll
    for (int kk = 0; kk < 128; kk += 32) {
      bf16x8 bfr = *reinterpret_cast<const bf16x8*>(&k_s[(w * 16 + fr) * 136 + kk + k8]);
#pragma unroll
      for (int m = 0; m < 4; m++) {
        bf16x8 afr = *reinterpret_cast<const bf16x8*>(&q_s[(m * 16 + fr) * 136 + kk + k8]);
        accs[m] = __builtin_amdgcn_mfma_f32_16x16x32_bf16(afr, bfr, accs[m], 0, 0, 0);
      }
    }
#pragma unroll
    for (int m = 0; m < 4; m++) {
#pragma unroll
      for (int r = 0; r < 4; r++) {
        accs[m][r] *= SCALE_ATT;
        float v = accs[m][r];
        for (int o = 1; o < 16; o <<= 1) v = fmaxf(v, __shfl_xor(v, o, 64));
        if (fr == 0) red[w * 64 + m * 16 + q4 + r] = v;
      }
    }
    __syncthreads();
    if (tid < 64) {
      float bm = fmaxf(fmaxf(red[tid], red[64 + tid]), fmaxf(red[128 + tid], red[192 + tid]));
      float mo = m_run[tid];
      float mn = fmaxf(mo, bm);
      float al = __expf(mo - mn);
      alpha_s[tid] = al;
      m_run[tid] = mn;
      l_run[tid] *= al;
    }
    __syncthreads();
#pragma unroll
    for (int m = 0; m < 4; m++) {
#pragma unroll
      for (int r = 0; r < 4; r++) {
        int row = m * 16 + q4 + r;
        float p = __expf(accs[m][r] - m_run[row]);
        p_s[row * 72 + w * 16 + fr] = f2bf(p);
        float sv = p;
        for (int o = 1; o < 16; o <<= 1) sv += __shfl_xor(sv, o, 64);
        if (fr == 0) red[w * 64 + row] = sv;
      }
    }
#pragma unroll
    for (int m = 0; m < 4; m++) {
      float a0 = alpha_s[m * 16 + q4 + 0];
      float a1 = alpha_s[m * 16 + q4 + 1];
      float a2 = alpha_s[m * 16 + q4 + 2];
      float a3 = alpha_s[m * 16 + q4 + 3];
#pragma unroll
      for (int n = 0; n < 2; n++) {
        acc_o[m][n][0] *= a0; acc_o[m][n][1] *= a1;
        acc_o[m][n][2] *= a2; acc_o[m][n][3] *= a3;
      }
    }
    __syncthreads();
    if (tid < 64) l_run[tid] += red[tid] + red[64 + tid] + red[128 + tid] + red[192 + tid];
#pragma unroll
    for (int kk = 0; kk < 64; kk += 32) {
      bf16x8 pa[4];
#pragma unroll
      for (int m = 0; m < 4; m++)
        pa[m] = *reinterpret_cast<const bf16x8*>(&p_s[(m * 16 + fr) * 72 + kk + k8]);
#pragma unroll
      for (int n = 0; n < 2; n++) {
        bf16x8 vb = *reinterpret_cast<const bf16x8*>(&vT_s[(w * 32 + n * 16 + fr) * 72 + kk + k8]);
#pragma unroll
        for (int m = 0; m < 4; m++)
          acc_o[m][n] = __builtin_amdgcn_mfma_f32_16x16x32_bf16(pa[m], vb, acc_o[m][n], 0, 0, 0);
      }
    }
  }
  __syncthreads();
#pragma unroll
  for (int m = 0; m < 4; m++) {
#pragma unroll
    for (int n = 0; n < 2; n++) {
#pragma unroll
      for (int r = 0; r < 4; r++) {
        int row = m * 16 + q4 + r;
        int srow = qb * 64 + row;
        int d = w * 32 + n * 16 + fr;
        float o = acc_o[m][n][r] / l_run[row];
        size_t oi = (size_t)srow * DIMX + h * HDIM + d;
        if (G) o += G[oi] * CB[(size_t)qb * DIMX + h * HDIM + d];
        Out[oi] = f2bf(o);
      }
    }
  }
}

// ---------------------------------------------------------------------------
__global__ void __launch_bounds__(128) block_mean_kernel(const float* __restrict__ X,
                                                         float* __restrict__ Outc) {
  int n = blockIdx.x, h = blockIdx.y, d = threadIdx.x;
  float s = 0.f;
  for (int t = 0; t < 64; t++) s += X[(size_t)(n * 64 + t) * DIMX + h * HDIM + d];
  Outc[(n * NHEAD + h) * HDIM + d] = s * (1.f / 64.f);
}

__global__ void __launch_bounds__(256) coarse_attn_kernel(const float* __restrict__ qc,
                                                          const float* __restrict__ kc,
                                                          float* __restrict__ pc,
                                                          int* __restrict__ idxout) {
  int h = blockIdx.x, t = threadIdx.x;
  __shared__ float sm[32][32];
  for (int p = t; p < 1024; p += 256) {
    int n = p >> 5, m = p & 31;
    float dot = 0.f;
    for (int d = 0; d < HDIM; d++)
      dot += qc[n * DIMX + h * HDIM + d] * kc[m * DIMX + h * HDIM + d];
    sm[n][m] = dot * SCALE_ATT;
  }
  __syncthreads();
  if (t < 32) {
    int n = t;
    float mx = -1e30f;
#pragma unroll
    for (int m = 0; m < 32; m++) mx = fmaxf(mx, sm[n][m]);
    float pv[32]; float ssum = 0.f;
#pragma unroll
    for (int m = 0; m < 32; m++) { pv[m] = __expf(sm[n][m] - mx); ssum += pv[m]; }
    float inv = 1.f / ssum;
#pragma unroll
    for (int m = 0; m < 32; m++) { pv[m] *= inv; pc[(h * 32 + n) * 32 + m] = pv[m]; }
    unsigned chosen = 0;
    for (int i = 0; i < 8; i++) {
      float best = -1.f; int bi = 0;
#pragma unroll
      for (int m = 0; m < 32; m++)
        if (!((chosen >> m) & 1u) && pv[m] > best) { best = pv[m]; bi = m; }
      chosen |= 1u << bi;
      idxout[(h * 32 + n) * 8 + i] = bi;
    }
  }
}

__global__ void __launch_bounds__(128) coarse_ctx_kernel(const float* __restrict__ pc,
                                                         const float* __restrict__ vc,
                                                         float* __restrict__ cb) {
  int n = blockIdx.x, h = blockIdx.y, d = threadIdx.x;
  float s = 0.f;
  for (int m = 0; m < 32; m++)
    s += pc[(h * 32 + n) * 32 + m] * vc[(m * NHEAD + h) * HDIM + d];
  cb[(n * NHEAD + h) * HDIM + d] = s;
}

__global__ void __launch_bounds__(256) addmul_kernel(const float* __restrict__ A,
                                                     const float* __restrict__ Bv,
                                                     const float* __restrict__ g,
                                                     float* __restrict__ O, int n) {
  for (int i = blockIdx.x * 256 + threadIdx.x; i < n; i += gridDim.x * 256) {
    float gv = g ? g[i % DIMX] : 1.f;
    O[i] = A[i] + gv * Bv[i];
  }
}

// ---------------------------------------------------------------------------
extern "C" void kernel_launch(void* const* d_in, const int* in_sizes, int n_in,
                              void* d_out, int out_size, void* d_ws, size_t ws_size,
                              hipStream_t stream) {
  (void)in_sizes; (void)n_in; (void)out_size; (void)ws_size;
  const float* hidden = (const float*)d_in[0];
  const float* enc    = (const float*)d_in[1];
  const float* temb   = (const float*)d_in[2];
  const float* cosT   = (const float*)d_in[3];
  const float* sinT   = (const float*)d_in[4];
  const float* sst    = (const float*)d_in[5];
  const float* Wq = (const float*)d_in[6];   const float* bq = (const float*)d_in[7];
  const float* Wk = (const float*)d_in[8];   const float* bk = (const float*)d_in[9];
  const float* Wv = (const float*)d_in[10];  const float* bv = (const float*)d_in[11];
  const float* Wg = (const float*)d_in[12];  const float* bg = (const float*)d_in[13];
  const float* Wo = (const float*)d_in[14];  const float* bo = (const float*)d_in[15];
  const float* qnw = (const float*)d_in[16]; const float* knw = (const float*)d_in[17];
  const float* saw = (const float*)d_in[18]; const float* sab = (const float*)d_in[19];
  const float* cWq = (const float*)d_in[20]; const float* cbq = (const float*)d_in[21];
  const float* cWk = (const float*)d_in[22]; const float* cbk = (const float*)d_in[23];
  const float* cWv = (const float*)d_in[24]; const float* cbv = (const float*)d_in[25];
  const float* cWo = (const float*)d_in[26]; const float* cbo = (const float*)d_in[27];
  const float* cqnw = (const float*)d_in[28]; const float* cknw = (const float*)d_in[29];
  const float* W1 = (const float*)d_in[30];  const float* b1 = (const float*)d_in[31];
  const float* W2 = (const float*)d_in[32];  const float* b2 = (const float*)d_in[33];

  char* ws = (char*)d_ws;
  size_t off = 0;
  auto alloc = [&](size_t bytes) -> void* {
    void* p = ws + off;
    off += (bytes + 255) & ~(size_t)255;
    return p;
  };
  const size_t SD = (size_t)SEQ * DIMX * 4;       // f32 seq x dim
  const size_t SDh = (size_t)SEQ * DIMX * 2;      // bf16 seq x dim
  const size_t WSQ = (size_t)DIMX * DIMX * 2;     // bf16 1536^2
  float* e     = (float*)alloc(6 * DIMX * 4);
  unsigned short* normb = (unsigned short*)alloc(SDh);
  float* qb_   = (float*)alloc(SD);
  float* kb_   = (float*)alloc(SD);
  float* vb_   = (float*)alloc(SD);
  float* gb_   = (float*)alloc(SD);
  float* qc    = (float*)alloc((size_t)NBLK * DIMX * 4);
  float* kc    = (float*)alloc((size_t)NBLK * DIMX * 4);
  float* vc    = (float*)alloc((size_t)NBLK * DIMX * 4);
  float* pc    = (float*)alloc(NHEAD * 32 * 32 * 4);
  int*   idx   = (int*)alloc(NHEAD * 32 * 8 * 4);
  float* cb    = (float*)alloc((size_t)NBLK * DIMX * 4);
  unsigned short* mixb = (unsigned short*)alloc(SDh);
  float* proj  = (float*)alloc(SD);
  float* res   = (float*)alloc(SD);
  unsigned short* encb = (unsigned short*)alloc((size_t)L2X * DIMX * 2);
  unsigned short* Wqt  = (unsigned short*)alloc(WSQ);
  unsigned short* Wkt  = (unsigned short*)alloc(WSQ);
  unsigned short* Wvt  = (unsigned short*)alloc(WSQ);
  unsigned short* Wgt  = (unsigned short*)alloc(WSQ);
  unsigned short* Wot  = (unsigned short*)alloc(WSQ);
  unsigned short* cWqt = (unsigned short*)alloc(WSQ);
  unsigned short* cWkt = (unsigned short*)alloc(WSQ);
  unsigned short* cWvt = (unsigned short*)alloc(WSQ);
  unsigned short* cWot = (unsigned short*)alloc(WSQ);
  unsigned short* W1t  = (unsigned short*)alloc((size_t)DIMX * FFNX * 2);
  unsigned short* W2t  = (unsigned short*)alloc((size_t)FFNX * DIMX * 2);
  // aliases (lifetimes disjoint):
  unsigned short* ffh    = (unsigned short*)qb_;   // 36.7MB <= qb_+kb_+vb_ (37.7MB)
  unsigned short* crossb = (unsigned short*)gb_;   // 6.3MB <= 12.6MB
  float* outf = (float*)d_out;

  // ---- pack weights (bf16, transposed to [N][K]) ----
  dim3 pg(DIMX / 32, DIMX / 32);
  pack_t_kernel<<<pg, 256, 0, stream>>>(Wq, Wqt, DIMX, DIMX);
  pack_t_kernel<<<pg, 256, 0, stream>>>(Wk, Wkt, DIMX, DIMX);
  pack_t_kernel<<<pg, 256, 0, stream>>>(Wv, Wvt, DIMX, DIMX);
  pack_t_kernel<<<pg, 256, 0, stream>>>(Wg, Wgt, DIMX, DIMX);
  pack_t_kernel<<<pg, 256, 0, stream>>>(Wo, Wot, DIMX, DIMX);
  pack_t_kernel<<<pg, 256, 0, stream>>>(cWq, cWqt, DIMX, DIMX);
  pack_t_kernel<<<pg, 256, 0, stream>>>(cWk, cWkt, DIMX, DIMX);
  pack_t_kernel<<<pg, 256, 0, stream>>>(cWv, cWvt, DIMX, DIMX);
  pack_t_kernel<<<pg, 256, 0, stream>>>(cWo, cWot, DIMX, DIMX);
  pack_t_kernel<<<dim3(FFNX / 32, DIMX / 32), 256, 0, stream>>>(W1, W1t, DIMX, FFNX);
  pack_t_kernel<<<dim3(DIMX / 32, FFNX / 32), 256, 0, stream>>>(W2, W2t, FFNX, DIMX);
  pack_cvt_kernel<<<(L2X * DIMX / 4 + 255) / 256, 256, 0, stream>>>(enc, encb, L2X * DIMX / 4);

  prep_e_kernel<<<36, 256, 0, stream>>>(sst, temb, e);
  ln_affine_kernel<<<SEQ, 256, 0, stream>>>(hidden, e + DIMX, e, 1, normb);
  dim3 g16(DIMX / 128, SEQ / 128);
  gemm_bf16<0, 0><<<g16, 256, 0, stream>>>(normb, Wqt, bq, qb_, nullptr, SEQ, DIMX, DIMX);
  gemm_bf16<0, 0><<<g16, 256, 0, stream>>>(normb, Wkt, bk, kb_, nullptr, SEQ, DIMX, DIMX);
  gemm_bf16<0, 0><<<g16, 256, 0, stream>>>(normb, Wvt, bv, vb_, nullptr, SEQ, DIMX, DIMX);
  gemm_bf16<0, 0><<<g16, 256, 0, stream>>>(normb, Wgt, bg, gb_, nullptr, SEQ, DIMX, DIMX);
  rms_rope_kernel<<<SEQ, 256, 0, stream>>>(qb_, qnw, cosT, sinT, 1);
  rms_rope_kernel<<<SEQ, 256, 0, stream>>>(kb_, knw, cosT, sinT, 1);
  dim3 gbm(NBLK, NHEAD);
  block_mean_kernel<<<gbm, 128, 0, stream>>>(qb_, qc);
  block_mean_kernel<<<gbm, 128, 0, stream>>>(kb_, kc);
  block_mean_kernel<<<gbm, 128, 0, stream>>>(vb_, vc);
  coarse_attn_kernel<<<NHEAD, 256, 0, stream>>>(qc, kc, pc, idx);
  coarse_ctx_kernel<<<gbm, 128, 0, stream>>>(pc, vc, cb);
  attn_kernel<<<dim3(NBLK, NHEAD), 256, 0, stream>>>(qb_, kb_, vb_, idx, gb_, cb, mixb);
  gemm_bf16<0, 0><<<g16, 256, 0, stream>>>(mixb, Wot, bo, proj, nullptr, SEQ, DIMX, DIMX);
  addmul_kernel<<<2048, 256, 0, stream>>>(hidden, proj, e + 2 * DIMX, res, SEQ * DIMX);
  // cross attention
  ln_affine_kernel<<<SEQ, 256, 0, stream>>>(res, saw, sab, 0, normb);
  gemm_bf16<0, 0><<<g16, 256, 0, stream>>>(normb, cWqt, cbq, qb_, nullptr, SEQ, DIMX, DIMX);
  rms_rope_kernel<<<SEQ, 256, 0, stream>>>(qb_, cqnw, cosT, sinT, 0);
  dim3 g4(DIMX / 128, L2X / 128);
  gemm_bf16<0, 0><<<g4, 256, 0, stream>>>(encb, cWkt, cbk, kb_, nullptr, L2X, DIMX, DIMX);
  rms_rope_kernel<<<L2X, 256, 0, stream>>>(kb_, cknw, cosT, sinT, 0);
  gemm_bf16<0, 0><<<g4, 256, 0, stream>>>(encb, cWvt, cbv, vb_, nullptr, L2X, DIMX, DIMX);
  attn_kernel<<<dim3(NBLK, NHEAD), 256, 0, stream>>>(qb_, kb_, vb_, nullptr, nullptr, nullptr, crossb);
  gemm_bf16<0, 0><<<g16, 256, 0, stream>>>(crossb, cWot, cbo, proj, nullptr, SEQ, DIMX, DIMX);
  addmul_kernel<<<2048, 256, 0, stream>>>(res, proj, nullptr, outf, SEQ * DIMX);
  // FFN
  ln_affine_kernel<<<SEQ, 256, 0, stream>>>(outf, e + 4 * DIMX, e + 3 * DIMX, 1, normb);
  dim3 gff(FFNX / 128, SEQ / 128);
  gemm_bf16<1, 1><<<gff, 256, 0, stream>>>(normb, W1t, b1, nullptr, ffh, SEQ, FFNX, DIMX);
  dim3 g16b(DIMX / 128, SEQ / 128);
  gemm_bf16<0, 0><<<g16b, 256, 0, stream>>>(ffh, W2t, b2, proj, nullptr, SEQ, DIMX, FFNX);
  addmul_kernel<<<2048, 256, 0, stream>>>(outf, proj, e + 5 * DIMX, outf, SEQ * DIMX);
}

// Round 3
// 710.152 us; speedup vs baseline: 1.9253x; 1.4224x over previous
//
#include <hip/hip_runtime.h>
#include <hip/hip_bf16.h>
#include <math.h>

#define DIMX 1536
#define SEQ 2048
#define L2X 512
#define NHEAD 12
#define HDIM 128
#define NBLK 32
#define FFNX 8960
#define SCALE_ATT 0.08838834764831845f

typedef __attribute__((ext_vector_type(4))) float f4;
typedef __attribute__((ext_vector_type(4))) float f32x4;
typedef __attribute__((ext_vector_type(8))) short bf16x8;
typedef __attribute__((ext_vector_type(4))) unsigned short us4;
typedef __attribute__((ext_vector_type(8))) unsigned short us8;

static __device__ __forceinline__ unsigned short f2bf(float f) {
  union { float f; unsigned u; } v; v.f = f;
  unsigned r = v.u + 0x7FFFu + ((v.u >> 16) & 1u);
  return (unsigned short)(r >> 16);
}

static __device__ __forceinline__ void gl_lds16(const unsigned short* g, unsigned short* l) {
  __builtin_amdgcn_global_load_lds(
      (const __attribute__((address_space(1))) void*)g,
      (__attribute__((address_space(3))) void*)l, 16, 0, 0);
}

// bijective XCD swizzle (requires gridDim.x*gridDim.y % 8 == 0)
static __device__ __forceinline__ void xcd_map2(int& bx, int& by) {
  int gx = gridDim.x, gy = gridDim.y;
  int nwg = gx * gy;
  int lin = by * gx + bx;
  int q = nwg >> 3;
  lin = (lin & 7) * q + (lin >> 3);
  bx = lin % gx;
  by = lin / gx;
}

// ---------------------------------------------------------------------------
__global__ void __launch_bounds__(256) prep_e_kernel(const float* __restrict__ sst,
                                                     const float* __restrict__ temb,
                                                     float* __restrict__ e) {
  int i = blockIdx.x * 256 + threadIdx.x;
  if (i < 6 * DIMX) e[i] = sst[i] + temb[i];
}

// ---------------------------------------------------------------------------
// 9x DIMxDIM weight pack: W[K][N] f32 -> Wt[N][K] bf16, slab per z
struct P9 { const float* s[9]; };
__global__ void __launch_bounds__(256) pack9_kernel(P9 ps, unsigned short* __restrict__ dst) {
  const float* __restrict__ W = ps.s[blockIdx.z];
  unsigned short* __restrict__ Wt = dst + (size_t)blockIdx.z * DIMX * DIMX;
  __shared__ float t[32][33];
  int n0 = blockIdx.x * 32, k0 = blockIdx.y * 32;
  int tx = threadIdx.x & 31, ty = threadIdx.x >> 5;
#pragma unroll
  for (int i = 0; i < 4; i++)
    t[ty * 4 + i][tx] = W[(size_t)(k0 + ty * 4 + i) * DIMX + n0 + tx];
  __syncthreads();
#pragma unroll
  for (int i = 0; i < 4; i++)
    Wt[(size_t)(n0 + ty * 4 + i) * DIMX + k0 + tx] = f2bf(t[tx][ty * 4 + i]);
}

// generic single pack for W1/W2
__global__ void __launch_bounds__(256) pack_t_kernel(const float* __restrict__ W,
                                                     unsigned short* __restrict__ Wt,
                                                     int K, int N) {
  __shared__ float t[32][33];
  int n0 = blockIdx.x * 32, k0 = blockIdx.y * 32;
  int tx = threadIdx.x & 31, ty = threadIdx.x >> 5;
#pragma unroll
  for (int i = 0; i < 4; i++)
    t[ty * 4 + i][tx] = W[(size_t)(k0 + ty * 4 + i) * N + n0 + tx];
  __syncthreads();
#pragma unroll
  for (int i = 0; i < 4; i++)
    Wt[(size_t)(n0 + ty * 4 + i) * K + k0 + tx] = f2bf(t[tx][ty * 4 + i]);
}

__global__ void __launch_bounds__(256) pack_cvt_kernel(const float* __restrict__ X,
                                                       unsigned short* __restrict__ Y, int n4) {
  int i = blockIdx.x * 256 + threadIdx.x;
  if (i < n4) {
    f4 v = *reinterpret_cast<const f4*>(&X[(size_t)i * 4]);
    us4 h; h[0] = f2bf(v[0]); h[1] = f2bf(v[1]); h[2] = f2bf(v[2]); h[3] = f2bf(v[3]);
    *reinterpret_cast<us4*>(&Y[(size_t)i * 4]) = h;
  }
}

// ---------------------------------------------------------------------------
// out[row] = LN(x[row]) * (a + add1) + b   -> bf16
__global__ void __launch_bounds__(256) ln_affine_kernel(
    const float* __restrict__ X, const float* __restrict__ a,
    const float* __restrict__ b, int add1, unsigned short* __restrict__ Out) {
  __shared__ float lds4[4];
  int row = blockIdx.x, t = threadIdx.x;
  const float* x = X + (size_t)row * DIMX;
  float v[6]; float s = 0.f;
#pragma unroll
  for (int i = 0; i < 6; i++) { v[i] = x[t + 256 * i]; s += v[i]; }
  for (int o = 1; o < 64; o <<= 1) s += __shfl_xor(s, o, 64);
  if ((t & 63) == 0) lds4[t >> 6] = s;
  __syncthreads();
  float mean = (lds4[0] + lds4[1] + lds4[2] + lds4[3]) * (1.f / DIMX);
  __syncthreads();
  float s2 = 0.f;
#pragma unroll
  for (int i = 0; i < 6; i++) { float c = v[i] - mean; s2 += c * c; }
  for (int o = 1; o < 64; o <<= 1) s2 += __shfl_xor(s2, o, 64);
  if ((t & 63) == 0) lds4[t >> 6] = s2;
  __syncthreads();
  float var = (lds4[0] + lds4[1] + lds4[2] + lds4[3]) * (1.f / DIMX);
  float rstd = rsqrtf(var + 1e-6f);
#pragma unroll
  for (int i = 0; i < 6; i++) {
    int c = t + 256 * i;
    float av = a[c] + (add1 ? 1.f : 0.f);
    Out[(size_t)row * DIMX + c] = f2bf((v[i] - mean) * rstd * av + b[c]);
  }
}

// ---------------------------------------------------------------------------
__global__ void __launch_bounds__(256) rms_rope_kernel(
    float* __restrict__ X, const float* __restrict__ wgt,
    const float* __restrict__ cosT, const float* __restrict__ sinT, int do_rope) {
  __shared__ float lds4[4];
  int row = blockIdx.x, t = threadIdx.x;
  float* x = X + (size_t)row * DIMX;
  int base = t * 6;
  float v[6]; float s2 = 0.f;
#pragma unroll
  for (int i = 0; i < 6; i++) { v[i] = x[base + i]; s2 += v[i] * v[i]; }
  for (int o = 1; o < 64; o <<= 1) s2 += __shfl_xor(s2, o, 64);
  if ((t & 63) == 0) lds4[t >> 6] = s2;
  __syncthreads();
  float ms = (lds4[0] + lds4[1] + lds4[2] + lds4[3]) * (1.f / DIMX);
  float rstd = rsqrtf(ms + 1e-6f);
#pragma unroll
  for (int i = 0; i < 6; i++) v[i] *= rstd * wgt[base + i];
  if (do_rope) {
#pragma unroll
    for (int j = 0; j < 3; j++) {
      int c = base + 2 * j;
      int pi = (c & (HDIM - 1)) >> 1;
      float cs = cosT[row * (HDIM / 2) + pi], sn = sinT[row * (HDIM / 2) + pi];
      float ev = v[2 * j], ov = v[2 * j + 1];
      v[2 * j] = ev * cs - ov * sn;
      v[2 * j + 1] = ov * cs + ev * sn;
    }
  }
#pragma unroll
  for (int i = 0; i < 6; i++) x[base + i] = v[i];
}

// ---------------------------------------------------------------------------
// GEMM core: 128x128 tile, BK=64, XOR-swizzled LDS (write-side pre-swizzled
// global source + swizzled ds_read), global_load_lds width=16.
struct Outs {
  float *o0, *o1, *o2, *o3;
  const float *b0, *b1, *b2, *b3;
  unsigned short* ob;
};

template<int NCHUNK, int OUT_BF16, int DO_GELU>
__global__ void __launch_bounds__(256) gemm_multi(
    const unsigned short* __restrict__ A,
    const unsigned short* __restrict__ Bt,
    Outs outs, int M, int N, int K) {
  __shared__ __align__(16) unsigned short As[128 * 64];
  __shared__ __align__(16) unsigned short Bs[128 * 64];
  const int tid = threadIdx.x;
  const int lane = tid & 63;
  const int w = tid >> 6;
  const int wr = w >> 1, wc = w & 1;
  const int fr = lane & 15;
  const int xo = lane >> 4;
  const int r7 = fr & 7;
  const int q4 = xo * 4;
  int bx = blockIdx.x, by = blockIdx.y;
  xcd_map2(bx, by);
  const int tm = by * 128, tn = bx * 128;

  f32x4 acc[4][4];
#pragma unroll
  for (int m = 0; m < 4; m++)
#pragma unroll
    for (int n = 0; n < 4; n++) acc[m][n] = (f32x4)(0.f);

  // staging constants: chunk c = j*256+tid ; row = c>>3 ; kc_src = (c&7)^(row&7)
  int srow[4], skc[4];
#pragma unroll
  for (int j = 0; j < 4; j++) {
    int c = j * 256 + tid;
    srow[j] = c >> 3;
    skc[j] = ((c & 7) ^ ((c >> 3) & 7)) * 8;
  }

  for (int k0 = 0; k0 < K; k0 += 64) {
#pragma unroll
    for (int j = 0; j < 4; j++) {
      gl_lds16(A + (size_t)(tm + srow[j]) * K + k0 + skc[j], As + (j * 256 + w * 64) * 8);
      gl_lds16(Bt + (size_t)(tn + srow[j]) * K + k0 + skc[j], Bs + (j * 256 + w * 64) * 8);
    }
    __syncthreads();
    bf16x8 af[2][4], bfv[2][4];
#pragma unroll
    for (int ks = 0; ks < 2; ks++) {
      const int koff = (((ks * 4 + xo) ^ r7) << 3);
#pragma unroll
      for (int m = 0; m < 4; m++)
        af[ks][m] = *reinterpret_cast<const bf16x8*>(&As[(wr * 64 + m * 16 + fr) * 64 + koff]);
#pragma unroll
      for (int n = 0; n < 4; n++)
        bfv[ks][n] = *reinterpret_cast<const bf16x8*>(&Bs[(wc * 64 + n * 16 + fr) * 64 + koff]);
    }
#pragma unroll
    for (int ks = 0; ks < 2; ks++)
#pragma unroll
      for (int m = 0; m < 4; m++)
#pragma unroll
        for (int n = 0; n < 4; n++)
          acc[m][n] = __builtin_amdgcn_mfma_f32_16x16x32_bf16(af[ks][m], bfv[ks][n], acc[m][n], 0, 0, 0);
    __syncthreads();
  }
#pragma unroll
  for (int m = 0; m < 4; m++) {
#pragma unroll
    for (int n = 0; n < 4; n++) {
      int col = tn + wc * 64 + n * 16 + fr;
      int c2; float* op; const float* bp;
      if constexpr (NCHUNK == 1) {
        c2 = col; op = outs.o0; bp = outs.b0;
      } else if constexpr (NCHUNK == 2) {
        int sel = col >= DIMX;
        c2 = col - sel * DIMX;
        op = sel ? outs.o1 : outs.o0;
        bp = sel ? outs.b1 : outs.b0;
      } else {
        int sel = col >= 3 * DIMX ? 3 : (col >= 2 * DIMX ? 2 : (col >= DIMX ? 1 : 0));
        c2 = col - sel * DIMX;
        op = sel == 0 ? outs.o0 : (sel == 1 ? outs.o1 : (sel == 2 ? outs.o2 : outs.o3));
        bp = sel == 0 ? outs.b0 : (sel == 1 ? outs.b1 : (sel == 2 ? outs.b2 : outs.b3));
      }
      const int rstride = (NCHUNK == 1) ? N : DIMX;
      float bv = bp[c2];
#pragma unroll
      for (int r = 0; r < 4; r++) {
        int row = tm + wr * 64 + m * 16 + q4 + r;
        float v = acc[m][n][r] + bv;
        if (DO_GELU) {
          float u = 1.5957691216057308f * (v + 0.044715f * v * v * v);
          v = v / (1.f + __expf(-u));
        }
        if (OUT_BF16)
          outs.ob[(size_t)row * N + col] = f2bf(v);
        else
          op[(size_t)row * rstride + c2] = v;
      }
    }
  }
}

// split-K variant: writes f32 partials (no bias)
__global__ void __launch_bounds__(256) gemm_splitk(
    const unsigned short* __restrict__ A,
    const unsigned short* __restrict__ Bt,
    float* __restrict__ P, int M, int N, int Kfull, int Ks) {
  __shared__ __align__(16) unsigned short As[128 * 64];
  __shared__ __align__(16) unsigned short Bs[128 * 64];
  const int tid = threadIdx.x;
  const int lane = tid & 63;
  const int w = tid >> 6;
  const int wr = w >> 1, wc = w & 1;
  const int fr = lane & 15;
  const int xo = lane >> 4;
  const int r7 = fr & 7;
  const int q4 = xo * 4;
  int bx = blockIdx.x, by = blockIdx.y;
  xcd_map2(bx, by);
  const int tm = by * 128, tn = bx * 128;
  const int slice = blockIdx.z;
  const int kbase = slice * Ks;
  float* __restrict__ Pout = P + (size_t)slice * M * N;

  f32x4 acc[4][4];
#pragma unroll
  for (int m = 0; m < 4; m++)
#pragma unroll
    for (int n = 0; n < 4; n++) acc[m][n] = (f32x4)(0.f);

  int srow[4], skc[4];
#pragma unroll
  for (int j = 0; j < 4; j++) {
    int c = j * 256 + tid;
    srow[j] = c >> 3;
    skc[j] = ((c & 7) ^ ((c >> 3) & 7)) * 8;
  }

  for (int k0 = 0; k0 < Ks; k0 += 64) {
#pragma unroll
    for (int j = 0; j < 4; j++) {
      gl_lds16(A + (size_t)(tm + srow[j]) * Kfull + kbase + k0 + skc[j], As + (j * 256 + w * 64) * 8);
      gl_lds16(Bt + (size_t)(tn + srow[j]) * Kfull + kbase + k0 + skc[j], Bs + (j * 256 + w * 64) * 8);
    }
    __syncthreads();
    bf16x8 af[2][4], bfv[2][4];
#pragma unroll
    for (int ks = 0; ks < 2; ks++) {
      const int koff = (((ks * 4 + xo) ^ r7) << 3);
#pragma unroll
      for (int m = 0; m < 4; m++)
        af[ks][m] = *reinterpret_cast<const bf16x8*>(&As[(wr * 64 + m * 16 + fr) * 64 + koff]);
#pragma unroll
      for (int n = 0; n < 4; n++)
        bfv[ks][n] = *reinterpret_cast<const bf16x8*>(&Bs[(wc * 64 + n * 16 + fr) * 64 + koff]);
    }
#pragma unroll
    for (int ks = 0; ks < 2; ks++)
#pragma unroll
      for (int m = 0; m < 4; m++)
#pragma unroll
        for (int n = 0; n < 4; n++)
          acc[m][n] = __builtin_amdgcn_mfma_f32_16x16x32_bf16(af[ks][m], bfv[ks][n], acc[m][n], 0, 0, 0);
    __syncthreads();
  }
#pragma unroll
  for (int m = 0; m < 4; m++)
#pragma unroll
    for (int n = 0; n < 4; n++) {
      int col = tn + wc * 64 + n * 16 + fr;
#pragma unroll
      for (int r = 0; r < 4; r++) {
        int row = tm + wr * 64 + m * 16 + q4 + r;
        Pout[(size_t)row * N + col] = acc[m][n][r];
      }
    }
}

// reduce split-K partials: O = [R +] [g *] (sum(P) + bias)
template<int S>
__global__ void __launch_bounds__(256) reduce_kernel(
    const float* __restrict__ P, const float* __restrict__ bias,
    const float* __restrict__ R, const float* __restrict__ g,
    float* __restrict__ O, int total4, int ncol4) {
  const f4* P4 = (const f4*)P;
  const f4* R4 = (const f4*)R;
  f4* O4 = (f4*)O;
  for (int i = blockIdx.x * 256 + threadIdx.x; i < total4; i += gridDim.x * 256) {
    f4 s = P4[i];
#pragma unroll
    for (int sl = 1; sl < S; sl++) s += P4[(size_t)sl * total4 + i];
    int c4 = (i % ncol4) * 4;
    s += *reinterpret_cast<const f4*>(&bias[c4]);
    if (R) {
      if (g) {
        f4 gv = *reinterpret_cast<const f4*>(&g[c4]);
        s = R4[i] + gv * s;
      } else {
        s = R4[i] + s;
      }
    }
    O4[i] = s;
  }
}

// ---------------------------------------------------------------------------
// block-sparse flash attention (unchanged from round 2)
__global__ void __launch_bounds__(256) attn_kernel(
    const float* __restrict__ Q, const float* __restrict__ Kx,
    const float* __restrict__ V, const int* __restrict__ idx,
    const float* __restrict__ G, const float* __restrict__ CB,
    unsigned short* __restrict__ Out) {
  __shared__ unsigned short q_s[64 * 136];
  __shared__ unsigned short k_s[64 * 136];
  __shared__ unsigned short vT_s[128 * 72];
  __shared__ unsigned short p_s[64 * 72];
  __shared__ float red[4 * 64];
  __shared__ float m_run[64], l_run[64], alpha_s[64];

  const int qb = blockIdx.x;
  const int h = blockIdx.y;
  const int tid = threadIdx.x;
  const int lane = tid & 63;
  const int w = tid >> 6;
  const int fr = lane & 15;
  const int k8 = (lane >> 4) * 8;
  const int q4 = (lane >> 4) * 4;

#pragma unroll
  for (int i = 0; i < 8; i++) {
    int s = tid + 256 * i;
    int row = s >> 5, cq = (s & 31) * 4;
    f4 v = *reinterpret_cast<const f4*>(&Q[(size_t)(qb * 64 + row) * DIMX + h * HDIM + cq]);
    us4 hh; hh[0] = f2bf(v[0]); hh[1] = f2bf(v[1]); hh[2] = f2bf(v[2]); hh[3] = f2bf(v[3]);
    *reinterpret_cast<us4*>(&q_s[row * 136 + cq]) = hh;
  }
  if (tid < 64) { m_run[tid] = -1e30f; l_run[tid] = 0.f; }

  f32x4 acc_o[4][2];
#pragma unroll
  for (int m = 0; m < 4; m++)
#pragma unroll
    for (int n = 0; n < 2; n++) acc_o[m][n] = (f32x4)(0.f);

  for (int ib = 0; ib < 8; ib++) {
    int blk = idx ? idx[(h * NBLK + qb) * 8 + ib] : ib;
    __syncthreads();
#pragma unroll
    for (int i = 0; i < 8; i++) {
      int s = tid + 256 * i;
      int row = s >> 5, cq = (s & 31) * 4;
      f4 v = *reinterpret_cast<const f4*>(&Kx[(size_t)(blk * 64 + row) * DIMX + h * HDIM + cq]);
      us4 hh; hh[0] = f2bf(v[0]); hh[1] = f2bf(v[1]); hh[2] = f2bf(v[2]); hh[3] = f2bf(v[3]);
      *reinterpret_cast<us4*>(&k_s[row * 136 + cq]) = hh;
    }
    {
      int d = tid & 127, th = (tid >> 7) * 32;
#pragma unroll
      for (int j = 0; j < 4; j++) {
        us8 hv;
#pragma unroll
        for (int qq = 0; qq < 8; qq++)
          hv[qq] = f2bf(V[(size_t)(blk * 64 + th + j * 8 + qq) * DIMX + h * HDIM + d]);
        *reinterpret_cast<us8*>(&vT_s[d * 72 + th + j * 8]) = hv;
      }
    }
    __syncthreads();
    f32x4 accs[4];
#pragma unroll
    for (int m = 0; m < 4; m++) accs[m] = (f32x4)(0.f);
#pragma unroll
    for (int kk = 0; kk < 128; kk += 32) {
      bf16x8 bfr = *reinterpret_cast<const bf16x8*>(&k_s[(w * 16 + fr) * 136 + kk + k8]);
#pragma unroll
      for (int m = 0; m < 4; m++) {
        bf16x8 afr = *reinterpret_cast<const bf16x8*>(&q_s[(m * 16 + fr) * 136 + kk + k8]);
        accs[m] = __builtin_amdgcn_mfma_f32_16x16x32_bf16(afr, bfr, accs[m], 0, 0, 0);
      }
    }
#pragma unroll
    for (int m = 0; m < 4; m++) {
#pragma unroll
      for (int r = 0; r < 4; r++) {
        accs[m][r] *= SCALE_ATT;
        float v = accs[m][r];
        for (int o = 1; o < 16; o <<= 1) v = fmaxf(v, __shfl_xor(v, o, 64));
        if (fr == 0) red[w * 64 + m * 16 + q4 + r] = v;
      }
    }
    __syncthreads();
    if (tid < 64) {
      float bm = fmaxf(fmaxf(red[tid], red[64 + tid]), fmaxf(red[128 + tid], red[192 + tid]));
      float mo = m_run[tid];
      float mn = fmaxf(mo, bm);
      float al = __expf(mo - mn);
      alpha_s[tid] = al;
      m_run[tid] = mn;
      l_run[tid] *= al;
    }
    __syncthreads();
#pragma unroll
    for (int m = 0; m < 4; m++) {
#pragma unroll
      for (int r = 0; r < 4; r++) {
        int row = m * 16 + q4 + r;
        float p = __expf(accs[m][r] - m_run[row]);
        p_s[row * 72 + w * 16 + fr] = f2bf(p);
        float sv = p;
        for (int o = 1; o < 16; o <<= 1) sv += __shfl_xor(sv, o, 64);
        if (fr == 0) red[w * 64 + row] = sv;
      }
    }
#pragma unroll
    for (int m = 0; m < 4; m++) {
      float a0 = alpha_s[m * 16 + q4 + 0];
      float a1 = alpha_s[m * 16 + q4 + 1];
      float a2 = alpha_s[m * 16 + q4 + 2];
      float a3 = alpha_s[m * 16 + q4 + 3];
#pragma unroll
      for (int n = 0; n < 2; n++) {
        acc_o[m][n][0] *= a0; acc_o[m][n][1] *= a1;
        acc_o[m][n][2] *= a2; acc_o[m][n][3] *= a3;
      }
    }
    __syncthreads();
    if (tid < 64) l_run[tid] += red[tid] + red[64 + tid] + red[128 + tid] + red[192 + tid];
#pragma unroll
    for (int kk = 0; kk < 64; kk += 32) {
      bf16x8 pa[4];
#pragma unroll
      for (int m = 0; m < 4; m++)
        pa[m] = *reinterpret_cast<const bf16x8*>(&p_s[(m * 16 + fr) * 72 + kk + k8]);
#pragma unroll
      for (int n = 0; n < 2; n++) {
        bf16x8 vb = *reinterpret_cast<const bf16x8*>(&vT_s[(w * 32 + n * 16 + fr) * 72 + kk + k8]);
#pragma unroll
        for (int m = 0; m < 4; m++)
          acc_o[m][n] = __builtin_amdgcn_mfma_f32_16x16x32_bf16(pa[m], vb, acc_o[m][n], 0, 0, 0);
      }
    }
  }
  __syncthreads();
#pragma unroll
  for (int m = 0; m < 4; m++) {
#pragma unroll
    for (int n = 0; n < 2; n++) {
#pragma unroll
      for (int r = 0; r < 4; r++) {
        int row = m * 16 + q4 + r;
        int srow = qb * 64 + row;
        int d = w * 32 + n * 16 + fr;
        float o = acc_o[m][n][r] / l_run[row];
        size_t oi = (size_t)srow * DIMX + h * HDIM + d;
        if (G) o += G[oi] * CB[(size_t)qb * DIMX + h * HDIM + d];
        Out[oi] = f2bf(o);
      }
    }
  }
}

// ---------------------------------------------------------------------------
__global__ void __launch_bounds__(128) block_mean_kernel(const float* __restrict__ X,
                                                         float* __restrict__ Outc) {
  int n = blockIdx.x, h = blockIdx.y, d = threadIdx.x;
  float s = 0.f;
  for (int t = 0; t < 64; t++) s += X[(size_t)(n * 64 + t) * DIMX + h * HDIM + d];
  Outc[(n * NHEAD + h) * HDIM + d] = s * (1.f / 64.f);
}

__global__ void __launch_bounds__(256) coarse_attn_kernel(const float* __restrict__ qc,
                                                          const float* __restrict__ kc,
                                                          float* __restrict__ pc,
                                                          int* __restrict__ idxout) {
  int h = blockIdx.x, t = threadIdx.x;
  __shared__ float sm[32][32];
  for (int p = t; p < 1024; p += 256) {
    int n = p >> 5, m = p & 31;
    float dot = 0.f;
    for (int d = 0; d < HDIM; d++)
      dot += qc[n * DIMX + h * HDIM + d] * kc[m * DIMX + h * HDIM + d];
    sm[n][m] = dot * SCALE_ATT;
  }
  __syncthreads();
  if (t < 32) {
    int n = t;
    float mx = -1e30f;
#pragma unroll
    for (int m = 0; m < 32; m++) mx = fmaxf(mx, sm[n][m]);
    float pv[32]; float ssum = 0.f;
#pragma unroll
    for (int m = 0; m < 32; m++) { pv[m] = __expf(sm[n][m] - mx); ssum += pv[m]; }
    float inv = 1.f / ssum;
#pragma unroll
    for (int m = 0; m < 32; m++) { pv[m] *= inv; pc[(h * 32 + n) * 32 + m] = pv[m]; }
    unsigned chosen = 0;
    for (int i = 0; i < 8; i++) {
      float best = -1.f; int bi = 0;
#pragma unroll
      for (int m = 0; m < 32; m++)
        if (!((chosen >> m) & 1u) && pv[m] > best) { best = pv[m]; bi = m; }
      chosen |= 1u << bi;
      idxout[(h * 32 + n) * 8 + i] = bi;
    }
  }
}

__global__ void __launch_bounds__(128) coarse_ctx_kernel(const float* __restrict__ pc,
                                                         const float* __restrict__ vc,
                                                         float* __restrict__ cb) {
  int n = blockIdx.x, h = blockIdx.y, d = threadIdx.x;
  float s = 0.f;
  for (int m = 0; m < 32; m++)
    s += pc[(h * 32 + n) * 32 + m] * vc[(m * NHEAD + h) * HDIM + d];
  cb[(n * NHEAD + h) * HDIM + d] = s;
}

// ---------------------------------------------------------------------------
extern "C" void kernel_launch(void* const* d_in, const int* in_sizes, int n_in,
                              void* d_out, int out_size, void* d_ws, size_t ws_size,
                              hipStream_t stream) {
  (void)in_sizes; (void)n_in; (void)out_size; (void)ws_size;
  const float* hidden = (const float*)d_in[0];
  const float* enc    = (const float*)d_in[1];
  const float* temb   = (const float*)d_in[2];
  const float* cosT   = (const float*)d_in[3];
  const float* sinT   = (const float*)d_in[4];
  const float* sst    = (const float*)d_in[5];
  const float* Wq = (const float*)d_in[6];   const float* bq = (const float*)d_in[7];
  const float* Wk = (const float*)d_in[8];   const float* bk = (const float*)d_in[9];
  const float* Wv = (const float*)d_in[10];  const float* bv = (const float*)d_in[11];
  const float* Wg = (const float*)d_in[12];  const float* bg = (const float*)d_in[13];
  const float* Wo = (const float*)d_in[14];  const float* bo = (const float*)d_in[15];
  const float* qnw = (const float*)d_in[16]; const float* knw = (const float*)d_in[17];
  const float* saw = (const float*)d_in[18]; const float* sab = (const float*)d_in[19];
  const float* cWq = (const float*)d_in[20]; const float* cbq = (const float*)d_in[21];
  const float* cWk = (const float*)d_in[22]; const float* cbk = (const float*)d_in[23];
  const float* cWv = (const float*)d_in[24]; const float* cbv = (const float*)d_in[25];
  const float* cWo = (const float*)d_in[26]; const float* cbo = (const float*)d_in[27];
  const float* cqnw = (const float*)d_in[28]; const float* cknw = (const float*)d_in[29];
  const float* W1 = (const float*)d_in[30];  const float* b1 = (const float*)d_in[31];
  const float* W2 = (const float*)d_in[32];  const float* b2 = (const float*)d_in[33];

  char* ws = (char*)d_ws;
  size_t off = 0;
  auto alloc = [&](size_t bytes) -> void* {
    void* p = ws + off;
    off += (bytes + 255) & ~(size_t)255;
    return p;
  };
  const size_t SD = (size_t)SEQ * DIMX * 4;
  const size_t SDh = (size_t)SEQ * DIMX * 2;
  const size_t WSQ = (size_t)DIMX * DIMX * 2;  // bf16 slab, 256-aligned
  float* e     = (float*)alloc(6 * DIMX * 4);
  unsigned short* normb = (unsigned short*)alloc(SDh);
  float* qb_   = (float*)alloc(SD);
  float* kb_   = (float*)alloc(SD);
  float* vb_   = (float*)alloc(SD);
  float* gb_   = (float*)alloc(SD);
  float* qc    = (float*)alloc((size_t)NBLK * DIMX * 4);
  float* kc    = (float*)alloc((size_t)NBLK * DIMX * 4);
  float* vc    = (float*)alloc((size_t)NBLK * DIMX * 4);
  float* pc    = (float*)alloc(NHEAD * 32 * 32 * 4);
  int*   idx   = (int*)alloc(NHEAD * 32 * 8 * 4);
  float* cb    = (float*)alloc((size_t)NBLK * DIMX * 4);
  unsigned short* mixb = (unsigned short*)alloc(SDh);
  float* res   = (float*)alloc(SD);
  unsigned short* encb = (unsigned short*)alloc((size_t)L2X * DIMX * 2);
  unsigned short* wpack = (unsigned short*)alloc(9 * WSQ);  // 9 consecutive DIM^2 slabs
  unsigned short* W1t  = (unsigned short*)alloc((size_t)DIMX * FFNX * 2);
  unsigned short* W2t  = (unsigned short*)alloc((size_t)FFNX * DIMX * 2);
  // aliases (lifetimes disjoint, verified):
  unsigned short* ffh   = (unsigned short*)qb_;   // 36.7MB over qb_+kb_+vb_ (37.75MB)
  unsigned short* crossb = (unsigned short*)gb_;  // 6.3MB <= 12.6MB
  float* part2 = (float*)qb_;                     // 2x12.58MB over qb_+kb_
  float* part4 = (float*)wpack;                   // 4x12.58MB over slabs 0..8 + W1t head
  float* outf  = (float*)d_out;
  const size_t SL = (size_t)DIMX * DIMX;          // shorts per slab
  unsigned short* Wot  = wpack + 4 * SL;
  unsigned short* cWqt = wpack + 5 * SL;
  unsigned short* cKVt = wpack + 6 * SL;          // cWkt(6), cWvt(7) consecutive
  unsigned short* cWot = wpack + 8 * SL;

  // ---- pack ----
  P9 p9; p9.s[0]=Wq; p9.s[1]=Wk; p9.s[2]=Wv; p9.s[3]=Wg; p9.s[4]=Wo;
  p9.s[5]=cWq; p9.s[6]=cWk; p9.s[7]=cWv; p9.s[8]=cWo;
  pack9_kernel<<<dim3(48, 48, 9), 256, 0, stream>>>(p9, wpack);
  pack_t_kernel<<<dim3(FFNX / 32, DIMX / 32), 256, 0, stream>>>(W1, W1t, DIMX, FFNX);
  pack_t_kernel<<<dim3(DIMX / 32, FFNX / 32), 256, 0, stream>>>(W2, W2t, FFNX, DIMX);
  pack_cvt_kernel<<<(L2X * DIMX / 4 + 255) / 256, 256, 0, stream>>>(enc, encb, L2X * DIMX / 4);
  prep_e_kernel<<<36, 256, 0, stream>>>(sst, temb, e);

  // ---- self-attention branch ----
  ln_affine_kernel<<<SEQ, 256, 0, stream>>>(hidden, e + DIMX, e, 1, normb);
  Outs qkvgo = {qb_, kb_, vb_, gb_, bq, bk, bv, bg, nullptr};
  gemm_multi<4, 0, 0><<<dim3(48, 16), 256, 0, stream>>>(normb, wpack, qkvgo, SEQ, 4 * DIMX, DIMX);
  rms_rope_kernel<<<SEQ, 256, 0, stream>>>(qb_, qnw, cosT, sinT, 1);
  rms_rope_kernel<<<SEQ, 256, 0, stream>>>(kb_, knw, cosT, sinT, 1);
  dim3 gbm(NBLK, NHEAD);
  block_mean_kernel<<<gbm, 128, 0, stream>>>(qb_, qc);
  block_mean_kernel<<<gbm, 128, 0, stream>>>(kb_, kc);
  block_mean_kernel<<<gbm, 128, 0, stream>>>(vb_, vc);
  coarse_attn_kernel<<<NHEAD, 256, 0, stream>>>(qc, kc, pc, idx);
  coarse_ctx_kernel<<<gbm, 128, 0, stream>>>(pc, vc, cb);
  attn_kernel<<<dim3(NBLK, NHEAD), 256, 0, stream>>>(qb_, kb_, vb_, idx, gb_, cb, mixb);
  gemm_splitk<<<dim3(12, 16, 2), 256, 0, stream>>>(mixb, Wot, part2, SEQ, DIMX, DIMX, 768);
  reduce_kernel<2><<<1024, 256, 0, stream>>>(part2, bo, hidden, e + 2 * DIMX, res,
                                             SEQ * DIMX / 4, DIMX / 4);
  // ---- cross attention ----
  ln_affine_kernel<<<SEQ, 256, 0, stream>>>(res, saw, sab, 0, normb);
  gemm_splitk<<<dim3(12, 16, 2), 256, 0, stream>>>(normb, cWqt, part2, SEQ, DIMX, DIMX, 768);
  reduce_kernel<2><<<1024, 256, 0, stream>>>(part2, cbq, nullptr, nullptr, qb_,
                                             SEQ * DIMX / 4, DIMX / 4);
  rms_rope_kernel<<<SEQ, 256, 0, stream>>>(qb_, cqnw, cosT, sinT, 0);
  Outs ckvo = {kb_, vb_, nullptr, nullptr, cbk, cbv, nullptr, nullptr, nullptr};
  gemm_multi<2, 0, 0><<<dim3(24, 4), 256, 0, stream>>>(encb, cKVt, ckvo, L2X, 2 * DIMX, DIMX);
  rms_rope_kernel<<<L2X, 256, 0, stream>>>(kb_, cknw, cosT, sinT, 0);
  attn_kernel<<<dim3(NBLK, NHEAD), 256, 0, stream>>>(qb_, kb_, vb_, nullptr, nullptr, nullptr, crossb);
  gemm_splitk<<<dim3(12, 16, 2), 256, 0, stream>>>(crossb, cWot, part2, SEQ, DIMX, DIMX, 768);
  reduce_kernel<2><<<1024, 256, 0, stream>>>(part2, cbo, res, nullptr, outf,
                                             SEQ * DIMX / 4, DIMX / 4);
  // ---- FFN ----
  ln_affine_kernel<<<SEQ, 256, 0, stream>>>(outf, e + 4 * DIMX, e + 3 * DIMX, 1, normb);
  Outs f1o = {nullptr, nullptr, nullptr, nullptr, b1, nullptr, nullptr, nullptr, ffh};
  gemm_multi<1, 1, 1><<<dim3(70, 16), 256, 0, stream>>>(normb, W1t, f1o, SEQ, FFNX, DIMX);
  gemm_splitk<<<dim3(12, 16, 4), 256, 0, stream>>>(ffh, W2t, part4, SEQ, DIMX, FFNX, 2240);
  reduce_kernel<4><<<1024, 256, 0, stream>>>(part4, b2, outf, e + 5 * DIMX, outf,
                                             SEQ * DIMX / 4, DIMX / 4);
}

// Round 4
// 663.907 us; speedup vs baseline: 2.0594x; 1.0697x over previous
//
#include <hip/hip_runtime.h>
#include <hip/hip_bf16.h>
#include <math.h>

#define DIMX 1536
#define SEQ 2048
#define L2X 512
#define NHEAD 12
#define HDIM 128
#define NBLK 32
#define FFNX 8960
#define SCALE_ATT 0.08838834764831845f

typedef __attribute__((ext_vector_type(4))) float f4;
typedef __attribute__((ext_vector_type(4))) float f32x4;
typedef __attribute__((ext_vector_type(8))) short bf16x8;
typedef __attribute__((ext_vector_type(4))) unsigned short us4;
typedef __attribute__((ext_vector_type(8))) unsigned short us8;
typedef unsigned short us;

static __device__ __forceinline__ us f2bf(float f) {
  union { float f; unsigned u; } v; v.f = f;
  unsigned r = v.u + 0x7FFFu + ((v.u >> 16) & 1u);
  return (us)(r >> 16);
}

static __device__ __forceinline__ void gl_lds16(const us* g, us* l) {
  __builtin_amdgcn_global_load_lds(
      (const __attribute__((address_space(1))) void*)g,
      (__attribute__((address_space(3))) void*)l, 16, 0, 0);
}

#define RAW_BAR() asm volatile("s_barrier" ::: "memory")

// bijective XCD swizzle (requires gridDim.x*gridDim.y % 8 == 0)
static __device__ __forceinline__ void xcd_map2(int& bx, int& by) {
  int gx = gridDim.x, gy = gridDim.y;
  int nwg = gx * gy;
  int lin = by * gx + bx;
  int q = nwg >> 3;
  lin = (lin & 7) * q + (lin >> 3);
  bx = lin % gx;
  by = lin / gx;
}

// ---------------------------------------------------------------------------
__global__ void __launch_bounds__(256) prep_e_kernel(const float* __restrict__ sst,
                                                     const float* __restrict__ temb,
                                                     float* __restrict__ e) {
  int i = blockIdx.x * 256 + threadIdx.x;
  if (i < 6 * DIMX) e[i] = sst[i] + temb[i];
}

// ---------------------------------------------------------------------------
struct P9 { const float* s[9]; };
__global__ void __launch_bounds__(256) pack9_kernel(P9 ps, us* __restrict__ dst) {
  const float* __restrict__ W = ps.s[blockIdx.z];
  us* __restrict__ Wt = dst + (size_t)blockIdx.z * DIMX * DIMX;
  __shared__ float t[32][33];
  int n0 = blockIdx.x * 32, k0 = blockIdx.y * 32;
  int tx = threadIdx.x & 31, ty = threadIdx.x >> 5;
#pragma unroll
  for (int i = 0; i < 4; i++)
    t[ty * 4 + i][tx] = W[(size_t)(k0 + ty * 4 + i) * DIMX + n0 + tx];
  __syncthreads();
#pragma unroll
  for (int i = 0; i < 4; i++)
    Wt[(size_t)(n0 + ty * 4 + i) * DIMX + k0 + tx] = f2bf(t[tx][ty * 4 + i]);
}

__global__ void __launch_bounds__(256) pack_t_kernel(const float* __restrict__ W,
                                                     us* __restrict__ Wt,
                                                     int K, int N) {
  __shared__ float t[32][33];
  int n0 = blockIdx.x * 32, k0 = blockIdx.y * 32;
  int tx = threadIdx.x & 31, ty = threadIdx.x >> 5;
#pragma unroll
  for (int i = 0; i < 4; i++)
    t[ty * 4 + i][tx] = W[(size_t)(k0 + ty * 4 + i) * N + n0 + tx];
  __syncthreads();
#pragma unroll
  for (int i = 0; i < 4; i++)
    Wt[(size_t)(n0 + ty * 4 + i) * K + k0 + tx] = f2bf(t[tx][ty * 4 + i]);
}

__global__ void __launch_bounds__(256) pack_cvt_kernel(const float* __restrict__ X,
                                                       us* __restrict__ Y, int n4) {
  int i = blockIdx.x * 256 + threadIdx.x;
  if (i < n4) {
    f4 v = *reinterpret_cast<const f4*>(&X[(size_t)i * 4]);
    us4 h; h[0] = f2bf(v[0]); h[1] = f2bf(v[1]); h[2] = f2bf(v[2]); h[3] = f2bf(v[3]);
    *reinterpret_cast<us4*>(&Y[(size_t)i * 4]) = h;
  }
}

// ---------------------------------------------------------------------------
__global__ void __launch_bounds__(256) ln_affine_kernel(
    const float* __restrict__ X, const float* __restrict__ a,
    const float* __restrict__ b, int add1, us* __restrict__ Out) {
  __shared__ float lds4[4];
  int row = blockIdx.x, t = threadIdx.x;
  const float* x = X + (size_t)row * DIMX;
  float v[6]; float s = 0.f;
#pragma unroll
  for (int i = 0; i < 6; i++) { v[i] = x[t + 256 * i]; s += v[i]; }
  for (int o = 1; o < 64; o <<= 1) s += __shfl_xor(s, o, 64);
  if ((t & 63) == 0) lds4[t >> 6] = s;
  __syncthreads();
  float mean = (lds4[0] + lds4[1] + lds4[2] + lds4[3]) * (1.f / DIMX);
  __syncthreads();
  float s2 = 0.f;
#pragma unroll
  for (int i = 0; i < 6; i++) { float c = v[i] - mean; s2 += c * c; }
  for (int o = 1; o < 64; o <<= 1) s2 += __shfl_xor(s2, o, 64);
  if ((t & 63) == 0) lds4[t >> 6] = s2;
  __syncthreads();
  float var = (lds4[0] + lds4[1] + lds4[2] + lds4[3]) * (1.f / DIMX);
  float rstd = rsqrtf(var + 1e-6f);
#pragma unroll
  for (int i = 0; i < 6; i++) {
    int c = t + 256 * i;
    float av = a[c] + (add1 ? 1.f : 0.f);
    Out[(size_t)row * DIMX + c] = f2bf((v[i] - mean) * rstd * av + b[c]);
  }
}

// ---------------------------------------------------------------------------
__global__ void __launch_bounds__(256) rms_rope_kernel(
    float* __restrict__ X, const float* __restrict__ wgt,
    const float* __restrict__ cosT, const float* __restrict__ sinT, int do_rope) {
  __shared__ float lds4[4];
  int row = blockIdx.x, t = threadIdx.x;
  float* x = X + (size_t)row * DIMX;
  int base = t * 6;
  float v[6]; float s2 = 0.f;
#pragma unroll
  for (int i = 0; i < 6; i++) { v[i] = x[base + i]; s2 += v[i] * v[i]; }
  for (int o = 1; o < 64; o <<= 1) s2 += __shfl_xor(s2, o, 64);
  if ((t & 63) == 0) lds4[t >> 6] = s2;
  __syncthreads();
  float ms = (lds4[0] + lds4[1] + lds4[2] + lds4[3]) * (1.f / DIMX);
  float rstd = rsqrtf(ms + 1e-6f);
#pragma unroll
  for (int i = 0; i < 6; i++) v[i] *= rstd * wgt[base + i];
  if (do_rope) {
#pragma unroll
    for (int j = 0; j < 3; j++) {
      int c = base + 2 * j;
      int pi = (c & (HDIM - 1)) >> 1;
      float cs = cosT[row * (HDIM / 2) + pi], sn = sinT[row * (HDIM / 2) + pi];
      float ev = v[2 * j], ov = v[2 * j + 1];
      v[2 * j] = ev * cs - ov * sn;
      v[2 * j + 1] = ov * cs + ev * sn;
    }
  }
#pragma unroll
  for (int i = 0; i < 6; i++) x[base + i] = v[i];
}

// ---------------------------------------------------------------------------
struct Outs {
  float *o0, *o1, *o2, *o3;
  const float *b0, *b1, *b2, *b3;
  us* ob;
};

// ===========================================================================
// 8-phase 256x256 GEMM, BK=64, 8 waves (2Mx4N), counted vmcnt (T1-T5).
// LDS regions per buf: A-half mh = quadrant rows {mh*64 of each wave-half},
// B-half nh = quadrant cols. Phase order Q(0,0),(1,0),(1,1),(0,1);
// prefetch issue p1:t+1.B1 p2:t+2.A0 p3:t+2.A1 p4:t+2.B0; vmcnt(6) boundary.
// ===========================================================================
template<int NCHUNK, int OUT_BF16, int DO_GELU, int SPLITK>
__global__ void __launch_bounds__(512, 2) gemm8p(
    const us* __restrict__ A, const us* __restrict__ Bt,
    Outs outs, int M, int N, int K, int Kfull) {
  __shared__ __align__(16) us S[65536];  // 128 KiB
  const int tid = threadIdx.x;
  const int lane = tid & 63;
  const int wid = tid >> 6;
  const int wr = wid >> 2, wc = wid & 3;
  const int fr = lane & 15, xo = lane >> 4;
  const int r7 = fr & 7, q4 = xo * 4;
  int bx = blockIdx.x, by = blockIdx.y;
  xcd_map2(bx, by);
  const int tm = by * 256, tn = bx * 256;
  const size_t kb = SPLITK ? (size_t)blockIdx.z * K : 0;

  // staging geometry
  const int r6 = tid >> 3;
  const int sc8 = ((tid & 7) ^ (r6 & 7)) * 8;          // pre-swizzled src chunk
  const int arow0 = tm + r6;                            // + i*128 + mh*64
  const int brow0 = tn + ((r6 >> 5) << 6) + (r6 & 31);  // + i*128 + nh*32
  us* ldsw = S + wid * 512;

  auto stA = [&](int buf, int k0, int mh) {
#pragma unroll
    for (int i = 0; i < 2; i++)
      gl_lds16(A + (size_t)(arow0 + i * 128 + mh * 64) * Kfull + kb + k0 + sc8,
               ldsw + buf * 32768 + (mh * 2 + i) * 4096);
  };
  auto stB = [&](int buf, int k0, int nh) {
#pragma unroll
    for (int i = 0; i < 2; i++)
      gl_lds16(Bt + (size_t)(brow0 + i * 128 + nh * 32) * Kfull + kb + k0 + sc8,
               ldsw + buf * 32768 + 16384 + (nh * 2 + i) * 4096);
  };
  auto rdA = [&](int buf, int mh, int mp, int ks) -> bf16x8 {
    int lr = mh * 128 + wr * 64 + mp * 16 + fr;
    int ko = ((ks * 4 + xo) ^ r7) * 8;
    return *reinterpret_cast<const bf16x8*>(&S[buf * 32768 + lr * 64 + ko]);
  };
  auto rdB = [&](int buf, int nh, int np, int ks) -> bf16x8 {
    int lr = nh * 128 + (wc >> 1) * 64 + (wc & 1) * 32 + np * 16 + fr;
    int ko = ((ks * 4 + xo) ^ r7) * 8;
    return *reinterpret_cast<const bf16x8*>(&S[buf * 32768 + 16384 + lr * 64 + ko]);
  };

  f32x4 acc[2][2][4][2];  // [mh][nh][mp][np]
#pragma unroll
  for (int a = 0; a < 2; a++)
#pragma unroll
    for (int b = 0; b < 2; b++)
#pragma unroll
      for (int c = 0; c < 4; c++)
#pragma unroll
        for (int d = 0; d < 2; d++) acc[a][b][c][d] = (f32x4)(0.f);
  bf16x8 aF[2][4][2], bF[2][2];

  // prologue: tile0 full + tile1 {A0,A1,B0}
  stA(0, 0, 0); stA(0, 0, 1); stB(0, 0, 0); stB(0, 0, 1);
  stA(1, 64, 0); stA(1, 64, 1); stB(1, 64, 0);
  asm volatile("s_waitcnt vmcnt(6)" ::: "memory");
  RAW_BAR();

  const int nt = K >> 6;
  for (int t = 0; t < nt; t++) {
    const int buf = t & 1;
    const int k1 = (t + 1) << 6, k2 = (t + 2) << 6;
    const bool n1 = (t + 1) < nt, n2 = (t + 2) < nt;
    // ---- phase 1: Q(0,0) ----
#pragma unroll
    for (int mp = 0; mp < 4; mp++)
#pragma unroll
      for (int ks = 0; ks < 2; ks++) aF[0][mp][ks] = rdA(buf, 0, mp, ks);
#pragma unroll
    for (int np = 0; np < 2; np++)
#pragma unroll
      for (int ks = 0; ks < 2; ks++) bF[np][ks] = rdB(buf, 0, np, ks);
    if (n1) stB(buf ^ 1, k1, 1);
    RAW_BAR();
    __builtin_amdgcn_s_setprio(1);
#pragma unroll
    for (int ks = 0; ks < 2; ks++)
#pragma unroll
      for (int mp = 0; mp < 4; mp++)
#pragma unroll
        for (int np = 0; np < 2; np++)
          acc[0][0][mp][np] = __builtin_amdgcn_mfma_f32_16x16x32_bf16(
              aF[0][mp][ks], bF[np][ks], acc[0][0][mp][np], 0, 0, 0);
    __builtin_amdgcn_s_setprio(0);
    RAW_BAR();
    // ---- phase 2: Q(1,0) ----
#pragma unroll
    for (int mp = 0; mp < 4; mp++)
#pragma unroll
      for (int ks = 0; ks < 2; ks++) aF[1][mp][ks] = rdA(buf, 1, mp, ks);
    if (n2) stA(buf, k2, 0);
    RAW_BAR();
    __builtin_amdgcn_s_setprio(1);
#pragma unroll
    for (int ks = 0; ks < 2; ks++)
#pragma unroll
      for (int mp = 0; mp < 4; mp++)
#pragma unroll
        for (int np = 0; np < 2; np++)
          acc[1][0][mp][np] = __builtin_amdgcn_mfma_f32_16x16x32_bf16(
              aF[1][mp][ks], bF[np][ks], acc[1][0][mp][np], 0, 0, 0);
    __builtin_amdgcn_s_setprio(0);
    RAW_BAR();
    // ---- phase 3: Q(1,1) ----
#pragma unroll
    for (int np = 0; np < 2; np++)
#pragma unroll
      for (int ks = 0; ks < 2; ks++) bF[np][ks] = rdB(buf, 1, np, ks);
    if (n2) stA(buf, k2, 1);
    RAW_BAR();
    __builtin_amdgcn_s_setprio(1);
#pragma unroll
    for (int ks = 0; ks < 2; ks++)
#pragma unroll
      for (int mp = 0; mp < 4; mp++)
#pragma unroll
        for (int np = 0; np < 2; np++)
          acc[1][1][mp][np] = __builtin_amdgcn_mfma_f32_16x16x32_bf16(
              aF[1][mp][ks], bF[np][ks], acc[1][1][mp][np], 0, 0, 0);
    __builtin_amdgcn_s_setprio(0);
    RAW_BAR();
    // ---- phase 4: Q(0,1) (regs only) ----
    if (n2) stB(buf, k2, 0);
    RAW_BAR();
    __builtin_amdgcn_s_setprio(1);
#pragma unroll
    for (int ks = 0; ks < 2; ks++)
#pragma unroll
      for (int mp = 0; mp < 4; mp++)
#pragma unroll
        for (int np = 0; np < 2; np++)
          acc[0][1][mp][np] = __builtin_amdgcn_mfma_f32_16x16x32_bf16(
              aF[0][mp][ks], bF[np][ks], acc[0][1][mp][np], 0, 0, 0);
    __builtin_amdgcn_s_setprio(0);
    if (n2) asm volatile("s_waitcnt vmcnt(6)" ::: "memory");
    else    asm volatile("s_waitcnt vmcnt(0)" ::: "memory");
    RAW_BAR();
  }

  // epilogue
#pragma unroll
  for (int mh = 0; mh < 2; mh++)
#pragma unroll
    for (int nh = 0; nh < 2; nh++)
#pragma unroll
      for (int mp = 0; mp < 4; mp++)
#pragma unroll
        for (int np = 0; np < 2; np++) {
          int col = tn + wc * 64 + nh * 32 + np * 16 + fr;
          int rowb = tm + wr * 128 + mh * 64 + mp * 16 + q4;
          if (SPLITK) {
            float* P = outs.o0 + (size_t)blockIdx.z * M * N;
#pragma unroll
            for (int r = 0; r < 4; r++)
              P[(size_t)(rowb + r) * N + col] = acc[mh][nh][mp][np][r];
          } else {
            int c2; float* op; const float* bp;
            if constexpr (NCHUNK == 1) {
              c2 = col; op = outs.o0; bp = outs.b0;
            } else {
              int sel = col >= 3 * DIMX ? 3 : (col >= 2 * DIMX ? 2 : (col >= DIMX ? 1 : 0));
              c2 = col - sel * DIMX;
              op = sel == 0 ? outs.o0 : (sel == 1 ? outs.o1 : (sel == 2 ? outs.o2 : outs.o3));
              bp = sel == 0 ? outs.b0 : (sel == 1 ? outs.b1 : (sel == 2 ? outs.b2 : outs.b3));
            }
            float bv = bp[c2];
#pragma unroll
            for (int r = 0; r < 4; r++) {
              float v = acc[mh][nh][mp][np][r] + bv;
              if (DO_GELU) {
                float u = 1.5957691216057308f * (v + 0.044715f * v * v * v);
                v = v / (1.f + __expf(-u));
              }
              if (OUT_BF16)
                outs.ob[(size_t)(rowb + r) * N + col] = f2bf(v);
              else
                op[(size_t)(rowb + r) * DIMX + c2] = v;
            }
          }
        }
}

// ---------------------------------------------------------------------------
// 128x128 kernels (round-3, proven) for the small GEMMs
template<int NCHUNK>
__global__ void __launch_bounds__(256) gemm_multi(
    const us* __restrict__ A, const us* __restrict__ Bt,
    Outs outs, int M, int N, int K) {
  __shared__ __align__(16) us As[128 * 64];
  __shared__ __align__(16) us Bs[128 * 64];
  const int tid = threadIdx.x;
  const int lane = tid & 63;
  const int w = tid >> 6;
  const int wr = w >> 1, wc = w & 1;
  const int fr = lane & 15;
  const int xo = lane >> 4;
  const int r7 = fr & 7;
  const int q4 = xo * 4;
  int bx = blockIdx.x, by = blockIdx.y;
  xcd_map2(bx, by);
  const int tm = by * 128, tn = bx * 128;

  f32x4 acc[4][4];
#pragma unroll
  for (int m = 0; m < 4; m++)
#pragma unroll
    for (int n = 0; n < 4; n++) acc[m][n] = (f32x4)(0.f);

  int srow[4], skc[4];
#pragma unroll
  for (int j = 0; j < 4; j++) {
    int c = j * 256 + tid;
    srow[j] = c >> 3;
    skc[j] = ((c & 7) ^ ((c >> 3) & 7)) * 8;
  }

  for (int k0 = 0; k0 < K; k0 += 64) {
#pragma unroll
    for (int j = 0; j < 4; j++) {
      gl_lds16(A + (size_t)(tm + srow[j]) * K + k0 + skc[j], As + (j * 256 + w * 64) * 8);
      gl_lds16(Bt + (size_t)(tn + srow[j]) * K + k0 + skc[j], Bs + (j * 256 + w * 64) * 8);
    }
    __syncthreads();
    bf16x8 af[2][4], bfv[2][4];
#pragma unroll
    for (int ks = 0; ks < 2; ks++) {
      const int koff = (((ks * 4 + xo) ^ r7) << 3);
#pragma unroll
      for (int m = 0; m < 4; m++)
        af[ks][m] = *reinterpret_cast<const bf16x8*>(&As[(wr * 64 + m * 16 + fr) * 64 + koff]);
#pragma unroll
      for (int n = 0; n < 4; n++)
        bfv[ks][n] = *reinterpret_cast<const bf16x8*>(&Bs[(wc * 64 + n * 16 + fr) * 64 + koff]);
    }
#pragma unroll
    for (int ks = 0; ks < 2; ks++)
#pragma unroll
      for (int m = 0; m < 4; m++)
#pragma unroll
        for (int n = 0; n < 4; n++)
          acc[m][n] = __builtin_amdgcn_mfma_f32_16x16x32_bf16(af[ks][m], bfv[ks][n], acc[m][n], 0, 0, 0);
    __syncthreads();
  }
#pragma unroll
  for (int m = 0; m < 4; m++) {
#pragma unroll
    for (int n = 0; n < 4; n++) {
      int col = tn + wc * 64 + n * 16 + fr;
      int c2; float* op; const float* bp;
      if constexpr (NCHUNK == 2) {
        int sel = col >= DIMX;
        c2 = col - sel * DIMX;
        op = sel ? outs.o1 : outs.o0;
        bp = sel ? outs.b1 : outs.b0;
      } else {
        c2 = col; op = outs.o0; bp = outs.b0;
      }
      float bv = bp[c2];
#pragma unroll
      for (int r = 0; r < 4; r++) {
        int row = tm + wr * 64 + m * 16 + q4 + r;
        op[(size_t)row * DIMX + c2] = acc[m][n][r] + bv;
      }
    }
  }
}

__global__ void __launch_bounds__(256) gemm_splitk(
    const us* __restrict__ A, const us* __restrict__ Bt,
    float* __restrict__ P, int M, int N, int Kfull, int Ks) {
  __shared__ __align__(16) us As[128 * 64];
  __shared__ __align__(16) us Bs[128 * 64];
  const int tid = threadIdx.x;
  const int lane = tid & 63;
  const int w = tid >> 6;
  const int wr = w >> 1, wc = w & 1;
  const int fr = lane & 15;
  const int xo = lane >> 4;
  const int r7 = fr & 7;
  const int q4 = xo * 4;
  int bx = blockIdx.x, by = blockIdx.y;
  xcd_map2(bx, by);
  const int tm = by * 128, tn = bx * 128;
  const int slice = blockIdx.z;
  const int kbase = slice * Ks;
  float* __restrict__ Pout = P + (size_t)slice * M * N;

  f32x4 acc[4][4];
#pragma unroll
  for (int m = 0; m < 4; m++)
#pragma unroll
    for (int n = 0; n < 4; n++) acc[m][n] = (f32x4)(0.f);

  int srow[4], skc[4];
#pragma unroll
  for (int j = 0; j < 4; j++) {
    int c = j * 256 + tid;
    srow[j] = c >> 3;
    skc[j] = ((c & 7) ^ ((c >> 3) & 7)) * 8;
  }

  for (int k0 = 0; k0 < Ks; k0 += 64) {
#pragma unroll
    for (int j = 0; j < 4; j++) {
      gl_lds16(A + (size_t)(tm + srow[j]) * Kfull + kbase + k0 + skc[j], As + (j * 256 + w * 64) * 8);
      gl_lds16(Bt + (size_t)(tn + srow[j]) * Kfull + kbase + k0 + skc[j], Bs + (j * 256 + w * 64) * 8);
    }
    __syncthreads();
    bf16x8 af[2][4], bfv[2][4];
#pragma unroll
    for (int ks = 0; ks < 2; ks++) {
      const int koff = (((ks * 4 + xo) ^ r7) << 3);
#pragma unroll
      for (int m = 0; m < 4; m++)
        af[ks][m] = *reinterpret_cast<const bf16x8*>(&As[(wr * 64 + m * 16 + fr) * 64 + koff]);
#pragma unroll
      for (int n = 0; n < 4; n++)
        bfv[ks][n] = *reinterpret_cast<const bf16x8*>(&Bs[(wc * 64 + n * 16 + fr) * 64 + koff]);
    }
#pragma unroll
    for (int ks = 0; ks < 2; ks++)
#pragma unroll
      for (int m = 0; m < 4; m++)
#pragma unroll
        for (int n = 0; n < 4; n++)
          acc[m][n] = __builtin_amdgcn_mfma_f32_16x16x32_bf16(af[ks][m], bfv[ks][n], acc[m][n], 0, 0, 0);
    __syncthreads();
  }
#pragma unroll
  for (int m = 0; m < 4; m++)
#pragma unroll
    for (int n = 0; n < 4; n++) {
      int col = tn + wc * 64 + n * 16 + fr;
#pragma unroll
      for (int r = 0; r < 4; r++) {
        int row = tm + wr * 64 + m * 16 + q4 + r;
        Pout[(size_t)row * N + col] = acc[m][n][r];
      }
    }
}

template<int S>
__global__ void __launch_bounds__(256) reduce_kernel(
    const float* __restrict__ P, const float* __restrict__ bias,
    const float* __restrict__ R, const float* __restrict__ g,
    float* __restrict__ O, int total4, int ncol4) {
  const f4* P4 = (const f4*)P;
  const f4* R4 = (const f4*)R;
  f4* O4 = (f4*)O;
  for (int i = blockIdx.x * 256 + threadIdx.x; i < total4; i += gridDim.x * 256) {
    f4 s = P4[i];
#pragma unroll
    for (int sl = 1; sl < S; sl++) s += P4[(size_t)sl * total4 + i];
    int c4 = (i % ncol4) * 4;
    s += *reinterpret_cast<const f4*>(&bias[c4]);
    if (R) {
      if (g) {
        f4 gv = *reinterpret_cast<const f4*>(&g[c4]);
        s = R4[i] + gv * s;
      } else {
        s = R4[i] + s;
      }
    }
    O4[i] = s;
  }
}

// ---------------------------------------------------------------------------
__global__ void __launch_bounds__(256) attn_kernel(
    const float* __restrict__ Q, const float* __restrict__ Kx,
    const float* __restrict__ V, const int* __restrict__ idx,
    const float* __restrict__ G, const float* __restrict__ CB,
    us* __restrict__ Out) {
  __shared__ us q_s[64 * 136];
  __shared__ us k_s[64 * 136];
  __shared__ us vT_s[128 * 72];
  __shared__ us p_s[64 * 72];
  __shared__ float red[4 * 64];
  __shared__ float m_run[64], l_run[64], alpha_s[64];

  const int qb = blockIdx.x;
  const int h = blockIdx.y;
  const int tid = threadIdx.x;
  const int lane = tid & 63;
  const int w = tid >> 6;
  const int fr = lane & 15;
  const int k8 = (lane >> 4) * 8;
  const int q4 = (lane >> 4) * 4;

#pragma unroll
  for (int i = 0; i < 8; i++) {
    int s = tid + 256 * i;
    int row = s >> 5, cq = (s & 31) * 4;
    f4 v = *reinterpret_cast<const f4*>(&Q[(size_t)(qb * 64 + row) * DIMX + h * HDIM + cq]);
    us4 hh; hh[0] = f2bf(v[0]); hh[1] = f2bf(v[1]); hh[2] = f2bf(v[2]); hh[3] = f2bf(v[3]);
    *reinterpret_cast<us4*>(&q_s[row * 136 + cq]) = hh;
  }
  if (tid < 64) { m_run[tid] = -1e30f; l_run[tid] = 0.f; }

  f32x4 acc_o[4][2];
#pragma unroll
  for (int m = 0; m < 4; m++)
#pragma unroll
    for (int n = 0; n < 2; n++) acc_o[m][n] = (f32x4)(0.f);

  for (int ib = 0; ib < 8; ib++) {
    int blk = idx ? idx[(h * NBLK + qb) * 8 + ib] : ib;
    __syncthreads();
#pragma unroll
    for (int i = 0; i < 8; i++) {
      int s = tid + 256 * i;
      int row = s >> 5, cq = (s & 31) * 4;
      f4 v = *reinterpret_cast<const f4*>(&Kx[(size_t)(blk * 64 + row) * DIMX + h * HDIM + cq]);
      us4 hh; hh[0] = f2bf(v[0]); hh[1] = f2bf(v[1]); hh[2] = f2bf(v[2]); hh[3] = f2bf(v[3]);
      *reinterpret_cast<us4*>(&k_s[row * 136 + cq]) = hh;
    }
    {
      int d = tid & 127, th = (tid >> 7) * 32;
#pragma unroll
      for (int j = 0; j < 4; j++) {
        us8 hv;
#pragma unroll
        for (int qq = 0; qq < 8; qq++)
          hv[qq] = f2bf(V[(size_t)(blk * 64 + th + j * 8 + qq) * DIMX + h * HDIM + d]);
        *reinterpret_cast<us8*>(&vT_s[d * 72 + th + j * 8]) = hv;
      }
    }
    __syncthreads();
    f32x4 accs[4];
#pragma unroll
    for (int m = 0; m < 4; m++) accs[m] = (f32x4)(0.f);
#pragma unroll
    for (int kk = 0; kk < 128; kk += 32) {
      bf16x8 bfr = *reinterpret_cast<const bf16x8*>(&k_s[(w * 16 + fr) * 136 + kk + k8]);
#pragma unroll
      for (int m = 0; m < 4; m++) {
        bf16x8 afr = *reinterpret_cast<const bf16x8*>(&q_s[(m * 16 + fr) * 136 + kk + k8]);
        accs[m] = __builtin_amdgcn_mfma_f32_16x16x32_bf16(afr, bfr, accs[m], 0, 0, 0);
      }
    }
#pragma unroll
    for (int m = 0; m < 4; m++) {
#pragma unroll
      for (int r = 0; r < 4; r++) {
        accs[m][r] *= SCALE_ATT;
        float v = accs[m][r];
        for (int o = 1; o < 16; o <<= 1) v = fmaxf(v, __shfl_xor(v, o, 64));
        if (fr == 0) red[w * 64 + m * 16 + q4 + r] = v;
      }
    }
    __syncthreads();
    if (tid < 64) {
      float bm = fmaxf(fmaxf(red[tid], red[64 + tid]), fmaxf(red[128 + tid], red[192 + tid]));
      float mo = m_run[tid];
      float mn = fmaxf(mo, bm);
      float al = __expf(mo - mn);
      alpha_s[tid] = al;
      m_run[tid] = mn;
      l_run[tid] *= al;
    }
    __syncthreads();
#pragma unroll
    for (int m = 0; m < 4; m++) {
#pragma unroll
      for (int r = 0; r < 4; r++) {
        int row = m * 16 + q4 + r;
        float p = __expf(accs[m][r] - m_run[row]);
        p_s[row * 72 + w * 16 + fr] = f2bf(p);
        float sv = p;
        for (int o = 1; o < 16; o <<= 1) sv += __shfl_xor(sv, o, 64);
        if (fr == 0) red[w * 64 + row] = sv;
      }
    }
#pragma unroll
    for (int m = 0; m < 4; m++) {
      float a0 = alpha_s[m * 16 + q4 + 0];
      float a1 = alpha_s[m * 16 + q4 + 1];
      float a2 = alpha_s[m * 16 + q4 + 2];
      float a3 = alpha_s[m * 16 + q4 + 3];
#pragma unroll
      for (int n = 0; n < 2; n++) {
        acc_o[m][n][0] *= a0; acc_o[m][n][1] *= a1;
        acc_o[m][n][2] *= a2; acc_o[m][n][3] *= a3;
      }
    }
    __syncthreads();
    if (tid < 64) l_run[tid] += red[tid] + red[64 + tid] + red[128 + tid] + red[192 + tid];
#pragma unroll
    for (int kk = 0; kk < 64; kk += 32) {
      bf16x8 pa[4];
#pragma unroll
      for (int m = 0; m < 4; m++)
        pa[m] = *reinterpret_cast<const bf16x8*>(&p_s[(m * 16 + fr) * 72 + kk + k8]);
#pragma unroll
      for (int n = 0; n < 2; n++) {
        bf16x8 vb = *reinterpret_cast<const bf16x8*>(&vT_s[(w * 32 + n * 16 + fr) * 72 + kk + k8]);
#pragma unroll
        for (int m = 0; m < 4; m++)
          acc_o[m][n] = __builtin_amdgcn_mfma_f32_16x16x32_bf16(pa[m], vb, acc_o[m][n], 0, 0, 0);
      }
    }
  }
  __syncthreads();
#pragma unroll
  for (int m = 0; m < 4; m++) {
#pragma unroll
    for (int n = 0; n < 2; n++) {
#pragma unroll
      for (int r = 0; r < 4; r++) {
        int row = m * 16 + q4 + r;
        int srow = qb * 64 + row;
        int d = w * 32 + n * 16 + fr;
        float o = acc_o[m][n][r] / l_run[row];
        size_t oi = (size_t)srow * DIMX + h * HDIM + d;
        if (G) o += G[oi] * CB[(size_t)qb * DIMX + h * HDIM + d];
        Out[oi] = f2bf(o);
      }
    }
  }
}

// ---------------------------------------------------------------------------
__global__ void __launch_bounds__(128) block_mean_kernel(const float* __restrict__ X,
                                                         float* __restrict__ Outc) {
  int n = blockIdx.x, h = blockIdx.y, d = threadIdx.x;
  float s = 0.f;
  for (int t = 0; t < 64; t++) s += X[(size_t)(n * 64 + t) * DIMX + h * HDIM + d];
  Outc[(n * NHEAD + h) * HDIM + d] = s * (1.f / 64.f);
}

__global__ void __launch_bounds__(256) coarse_attn_kernel(const float* __restrict__ qc,
                                                          const float* __restrict__ kc,
                                                          float* __restrict__ pc,
                                                          int* __restrict__ idxout) {
  int h = blockIdx.x, t = threadIdx.x;
  __shared__ float sm[32][32];
  for (int p = t; p < 1024; p += 256) {
    int n = p >> 5, m = p & 31;
    float dot = 0.f;
    for (int d = 0; d < HDIM; d++)
      dot += qc[n * DIMX + h * HDIM + d] * kc[m * DIMX + h * HDIM + d];
    sm[n][m] = dot * SCALE_ATT;
  }
  __syncthreads();
  if (t < 32) {
    int n = t;
    float mx = -1e30f;
#pragma unroll
    for (int m = 0; m < 32; m++) mx = fmaxf(mx, sm[n][m]);
    float pv[32]; float ssum = 0.f;
#pragma unroll
    for (int m = 0; m < 32; m++) { pv[m] = __expf(sm[n][m] - mx); ssum += pv[m]; }
    float inv = 1.f / ssum;
#pragma unroll
    for (int m = 0; m < 32; m++) { pv[m] *= inv; pc[(h * 32 + n) * 32 + m] = pv[m]; }
    unsigned chosen = 0;
    for (int i = 0; i < 8; i++) {
      float best = -1.f; int bi = 0;
#pragma unroll
      for (int m = 0; m < 32; m++)
        if (!((chosen >> m) & 1u) && pv[m] > best) { best = pv[m]; bi = m; }
      chosen |= 1u << bi;
      idxout[(h * 32 + n) * 8 + i] = bi;
    }
  }
}

__global__ void __launch_bounds__(128) coarse_ctx_kernel(const float* __restrict__ pc,
                                                         const float* __restrict__ vc,
                                                         float* __restrict__ cb) {
  int n = blockIdx.x, h = blockIdx.y, d = threadIdx.x;
  float s = 0.f;
  for (int m = 0; m < 32; m++)
    s += pc[(h * 32 + n) * 32 + m] * vc[(m * NHEAD + h) * HDIM + d];
  cb[(n * NHEAD + h) * HDIM + d] = s;
}

// ---------------------------------------------------------------------------
extern "C" void kernel_launch(void* const* d_in, const int* in_sizes, int n_in,
                              void* d_out, int out_size, void* d_ws, size_t ws_size,
                              hipStream_t stream) {
  (void)in_sizes; (void)n_in; (void)out_size; (void)ws_size;
  const float* hidden = (const float*)d_in[0];
  const float* enc    = (const float*)d_in[1];
  const float* temb   = (const float*)d_in[2];
  const float* cosT   = (const float*)d_in[3];
  const float* sinT   = (const float*)d_in[4];
  const float* sst    = (const float*)d_in[5];
  const float* Wq = (const float*)d_in[6];   const float* bq = (const float*)d_in[7];
  const float* Wk = (const float*)d_in[8];   const float* bk = (const float*)d_in[9];
  const float* Wv = (const float*)d_in[10];  const float* bv = (const float*)d_in[11];
  const float* Wg = (const float*)d_in[12];  const float* bg = (const float*)d_in[13];
  const float* Wo = (const float*)d_in[14];  const float* bo = (const float*)d_in[15];
  const float* qnw = (const float*)d_in[16]; const float* knw = (const float*)d_in[17];
  const float* saw = (const float*)d_in[18]; const float* sab = (const float*)d_in[19];
  const float* cWq = (const float*)d_in[20]; const float* cbq = (const float*)d_in[21];
  const float* cWk = (const float*)d_in[22]; const float* cbk = (const float*)d_in[23];
  const float* cWv = (const float*)d_in[24]; const float* cbv = (const float*)d_in[25];
  const float* cWo = (const float*)d_in[26]; const float* cbo = (const float*)d_in[27];
  const float* cqnw = (const float*)d_in[28]; const float* cknw = (const float*)d_in[29];
  const float* W1 = (const float*)d_in[30];  const float* b1 = (const float*)d_in[31];
  const float* W2 = (const float*)d_in[32];  const float* b2 = (const float*)d_in[33];

  char* ws = (char*)d_ws;
  size_t off = 0;
  auto alloc = [&](size_t bytes) -> void* {
    void* p = ws + off;
    off += (bytes + 255) & ~(size_t)255;
    return p;
  };
  const size_t SD = (size_t)SEQ * DIMX * 4;
  const size_t SDh = (size_t)SEQ * DIMX * 2;
  const size_t WSQ = (size_t)DIMX * DIMX * 2;
  float* e     = (float*)alloc(6 * DIMX * 4);
  us* normb    = (us*)alloc(SDh);
  float* qb_   = (float*)alloc(SD);
  float* kb_   = (float*)alloc(SD);
  float* vb_   = (float*)alloc(SD);
  float* gb_   = (float*)alloc(SD);
  float* qc    = (float*)alloc((size_t)NBLK * DIMX * 4);
  float* kc    = (float*)alloc((size_t)NBLK * DIMX * 4);
  float* vc    = (float*)alloc((size_t)NBLK * DIMX * 4);
  float* pc    = (float*)alloc(NHEAD * 32 * 32 * 4);
  int*   idx   = (int*)alloc(NHEAD * 32 * 8 * 4);
  float* cb    = (float*)alloc((size_t)NBLK * DIMX * 4);
  us* mixb     = (us*)alloc(SDh);
  float* res   = (float*)alloc(SD);
  us* encb     = (us*)alloc((size_t)L2X * DIMX * 2);
  us* wpack    = (us*)alloc(9 * WSQ);
  us* W1t      = (us*)alloc((size_t)DIMX * FFNX * 2);
  us* W2t      = (us*)alloc((size_t)FFNX * DIMX * 2);
  // aliases (lifetimes disjoint):
  us* ffh    = (us*)qb_;        // 36.7MB over qb_+kb_+vb_ (37.75MB)
  us* crossb = (us*)gb_;        // 6.3MB <= 12.6MB
  float* part2 = (float*)qb_;   // 2x12.58MB over qb_+kb_
  float* part5 = (float*)wpack; // 5x12.58MB=62.9MB over wpack(42.5)+W1t(27.5); both dead at FFN2
  float* outf  = (float*)d_out;
  const size_t SL = (size_t)DIMX * DIMX;
  us* Wot  = wpack + 4 * SL;
  us* cWqt = wpack + 5 * SL;
  us* cKVt = wpack + 6 * SL;
  us* cWot = wpack + 8 * SL;

  // ---- pack ----
  P9 p9; p9.s[0]=Wq; p9.s[1]=Wk; p9.s[2]=Wv; p9.s[3]=Wg; p9.s[4]=Wo;
  p9.s[5]=cWq; p9.s[6]=cWk; p9.s[7]=cWv; p9.s[8]=cWo;
  pack9_kernel<<<dim3(48, 48, 9), 256, 0, stream>>>(p9, wpack);
  pack_t_kernel<<<dim3(FFNX / 32, DIMX / 32), 256, 0, stream>>>(W1, W1t, DIMX, FFNX);
  pack_t_kernel<<<dim3(DIMX / 32, FFNX / 32), 256, 0, stream>>>(W2, W2t, FFNX, DIMX);
  pack_cvt_kernel<<<(L2X * DIMX / 4 + 255) / 256, 256, 0, stream>>>(enc, encb, L2X * DIMX / 4);
  prep_e_kernel<<<36, 256, 0, stream>>>(sst, temb, e);

  // ---- self-attention branch ----
  ln_affine_kernel<<<SEQ, 256, 0, stream>>>(hidden, e + DIMX, e, 1, normb);
  Outs qkvgo = {qb_, kb_, vb_, gb_, bq, bk, bv, bg, nullptr};
  gemm8p<4, 0, 0, 0><<<dim3(24, 8), 512, 0, stream>>>(normb, wpack, qkvgo, SEQ, 4 * DIMX, DIMX, DIMX);
  rms_rope_kernel<<<SEQ, 256, 0, stream>>>(qb_, qnw, cosT, sinT, 1);
  rms_rope_kernel<<<SEQ, 256, 0, stream>>>(kb_, knw, cosT, sinT, 1);
  dim3 gbm(NBLK, NHEAD);
  block_mean_kernel<<<gbm, 128, 0, stream>>>(qb_, qc);
  block_mean_kernel<<<gbm, 128, 0, stream>>>(kb_, kc);
  block_mean_kernel<<<gbm, 128, 0, stream>>>(vb_, vc);
  coarse_attn_kernel<<<NHEAD, 256, 0, stream>>>(qc, kc, pc, idx);
  coarse_ctx_kernel<<<gbm, 128, 0, stream>>>(pc, vc, cb);
  attn_kernel<<<dim3(NBLK, NHEAD), 256, 0, stream>>>(qb_, kb_, vb_, idx, gb_, cb, mixb);
  gemm_splitk<<<dim3(12, 16, 2), 256, 0, stream>>>(mixb, Wot, part2, SEQ, DIMX, DIMX, 768);
  reduce_kernel<2><<<1024, 256, 0, stream>>>(part2, bo, hidden, e + 2 * DIMX, res,
                                             SEQ * DIMX / 4, DIMX / 4);
  // ---- cross attention ----
  ln_affine_kernel<<<SEQ, 256, 0, stream>>>(res, saw, sab, 0, normb);
  gemm_splitk<<<dim3(12, 16, 2), 256, 0, stream>>>(normb, cWqt, part2, SEQ, DIMX, DIMX, 768);
  reduce_kernel<2><<<1024, 256, 0, stream>>>(part2, cbq, nullptr, nullptr, qb_,
                                             SEQ * DIMX / 4, DIMX / 4);
  rms_rope_kernel<<<SEQ, 256, 0, stream>>>(qb_, cqnw, cosT, sinT, 0);
  Outs ckvo = {kb_, vb_, nullptr, nullptr, cbk, cbv, nullptr, nullptr, nullptr};
  gemm_multi<2><<<dim3(24, 4), 256, 0, stream>>>(encb, cKVt, ckvo, L2X, 2 * DIMX, DIMX);
  rms_rope_kernel<<<L2X, 256, 0, stream>>>(kb_, cknw, cosT, sinT, 0);
  attn_kernel<<<dim3(NBLK, NHEAD), 256, 0, stream>>>(qb_, kb_, vb_, nullptr, nullptr, nullptr, crossb);
  gemm_splitk<<<dim3(12, 16, 2), 256, 0, stream>>>(crossb, cWot, part2, SEQ, DIMX, DIMX, 768);
  reduce_kernel<2><<<1024, 256, 0, stream>>>(part2, cbo, res, nullptr, outf,
                                             SEQ * DIMX / 4, DIMX / 4);
  // ---- FFN ----
  ln_affine_kernel<<<SEQ, 256, 0, stream>>>(outf, e + 4 * DIMX, e + 3 * DIMX, 1, normb);
  Outs f1o = {nullptr, nullptr, nullptr, nullptr, b1, nullptr, nullptr, nullptr, ffh};
  gemm8p<1, 1, 1, 0><<<dim3(35, 8), 512, 0, stream>>>(normb, W1t, f1o, SEQ, FFNX, DIMX, DIMX);
  Outs f2o = {part5, nullptr, nullptr, nullptr, nullptr, nullptr, nullptr, nullptr, nullptr};
  gemm8p<1, 0, 0, 1><<<dim3(6, 8, 5), 512, 0, stream>>>(ffh, W2t, f2o, SEQ, DIMX, 1792, FFNX);
  reduce_kernel<5><<<1024, 256, 0, stream>>>(part5, b2, outf, e + 5 * DIMX, outf,
                                             SEQ * DIMX / 4, DIMX / 4);
}

// Round 5
// 631.882 us; speedup vs baseline: 2.1638x; 1.0507x over previous
//
#include <hip/hip_runtime.h>
#include <hip/hip_bf16.h>
#include <math.h>

#define DIMX 1536
#define SEQ 2048
#define L2X 512
#define NHEAD 12
#define HDIM 128
#define NBLK 32
#define FFNX 8960
#define SCALE_ATT 0.08838834764831845f

typedef __attribute__((ext_vector_type(4))) float f4;
typedef __attribute__((ext_vector_type(4))) float f32x4;
typedef __attribute__((ext_vector_type(8))) short bf16x8;
typedef __attribute__((ext_vector_type(4))) unsigned short us4;
typedef __attribute__((ext_vector_type(8))) unsigned short us8;
typedef unsigned short us;

static __device__ __forceinline__ us f2bf(float f) {
  union { float f; unsigned u; } v; v.f = f;
  unsigned r = v.u + 0x7FFFu + ((v.u >> 16) & 1u);
  return (us)(r >> 16);
}

static __device__ __forceinline__ void gl_lds16(const us* g, us* l) {
  __builtin_amdgcn_global_load_lds(
      (const __attribute__((address_space(1))) void*)g,
      (__attribute__((address_space(3))) void*)l, 16, 0, 0);
}

#define RAW_BAR() asm volatile("s_barrier" ::: "memory")

// bijective XCD swizzle (requires gridDim.x*gridDim.y % 8 == 0)
static __device__ __forceinline__ void xcd_map2(int& bx, int& by) {
  int gx = gridDim.x, gy = gridDim.y;
  int nwg = gx * gy;
  int lin = by * gx + bx;
  int q = nwg >> 3;
  lin = (lin & 7) * q + (lin >> 3);
  bx = lin % gx;
  by = lin / gx;
}

// ---------------------------------------------------------------------------
__global__ void __launch_bounds__(256) prep_e_kernel(const float* __restrict__ sst,
                                                     const float* __restrict__ temb,
                                                     float* __restrict__ e) {
  int i = blockIdx.x * 256 + threadIdx.x;
  if (i < 6 * DIMX) e[i] = sst[i] + temb[i];
}

// ---------------------------------------------------------------------------
struct P9 { const float* s[9]; };
__global__ void __launch_bounds__(256) pack9_kernel(P9 ps, us* __restrict__ dst) {
  const float* __restrict__ W = ps.s[blockIdx.z];
  us* __restrict__ Wt = dst + (size_t)blockIdx.z * DIMX * DIMX;
  __shared__ float t[32][33];
  int n0 = blockIdx.x * 32, k0 = blockIdx.y * 32;
  int tx = threadIdx.x & 31, ty = threadIdx.x >> 5;
#pragma unroll
  for (int i = 0; i < 4; i++)
    t[ty * 4 + i][tx] = W[(size_t)(k0 + ty * 4 + i) * DIMX + n0 + tx];
  __syncthreads();
#pragma unroll
  for (int i = 0; i < 4; i++)
    Wt[(size_t)(n0 + ty * 4 + i) * DIMX + k0 + tx] = f2bf(t[tx][ty * 4 + i]);
}

__global__ void __launch_bounds__(256) pack_t_kernel(const float* __restrict__ W,
                                                     us* __restrict__ Wt,
                                                     int K, int N) {
  __shared__ float t[32][33];
  int n0 = blockIdx.x * 32, k0 = blockIdx.y * 32;
  int tx = threadIdx.x & 31, ty = threadIdx.x >> 5;
#pragma unroll
  for (int i = 0; i < 4; i++)
    t[ty * 4 + i][tx] = W[(size_t)(k0 + ty * 4 + i) * N + n0 + tx];
  __syncthreads();
#pragma unroll
  for (int i = 0; i < 4; i++)
    Wt[(size_t)(n0 + ty * 4 + i) * K + k0 + tx] = f2bf(t[tx][ty * 4 + i]);
}

__global__ void __launch_bounds__(256) pack_cvt_kernel(const float* __restrict__ X,
                                                       us* __restrict__ Y, int n4) {
  int i = blockIdx.x * 256 + threadIdx.x;
  if (i < n4) {
    f4 v = *reinterpret_cast<const f4*>(&X[(size_t)i * 4]);
    us4 h; h[0] = f2bf(v[0]); h[1] = f2bf(v[1]); h[2] = f2bf(v[2]); h[3] = f2bf(v[3]);
    *reinterpret_cast<us4*>(&Y[(size_t)i * 4]) = h;
  }
}

// ---------------------------------------------------------------------------
__global__ void __launch_bounds__(256) ln_affine_kernel(
    const float* __restrict__ X, const float* __restrict__ a,
    const float* __restrict__ b, int add1, us* __restrict__ Out) {
  __shared__ float lds4[4];
  int row = blockIdx.x, t = threadIdx.x;
  const float* x = X + (size_t)row * DIMX;
  float v[6]; float s = 0.f;
#pragma unroll
  for (int i = 0; i < 6; i++) { v[i] = x[t + 256 * i]; s += v[i]; }
  for (int o = 1; o < 64; o <<= 1) s += __shfl_xor(s, o, 64);
  if ((t & 63) == 0) lds4[t >> 6] = s;
  __syncthreads();
  float mean = (lds4[0] + lds4[1] + lds4[2] + lds4[3]) * (1.f / DIMX);
  __syncthreads();
  float s2 = 0.f;
#pragma unroll
  for (int i = 0; i < 6; i++) { float c = v[i] - mean; s2 += c * c; }
  for (int o = 1; o < 64; o <<= 1) s2 += __shfl_xor(s2, o, 64);
  if ((t & 63) == 0) lds4[t >> 6] = s2;
  __syncthreads();
  float var = (lds4[0] + lds4[1] + lds4[2] + lds4[3]) * (1.f / DIMX);
  float rstd = rsqrtf(var + 1e-6f);
#pragma unroll
  for (int i = 0; i < 6; i++) {
    int c = t + 256 * i;
    float av = a[c] + (add1 ? 1.f : 0.f);
    Out[(size_t)row * DIMX + c] = f2bf((v[i] - mean) * rstd * av + b[c]);
  }
}

// ---------------------------------------------------------------------------
__global__ void __launch_bounds__(256) rms_rope_kernel(
    float* __restrict__ X, const float* __restrict__ wgt,
    const float* __restrict__ cosT, const float* __restrict__ sinT, int do_rope) {
  __shared__ float lds4[4];
  int row = blockIdx.x, t = threadIdx.x;
  float* x = X + (size_t)row * DIMX;
  int base = t * 6;
  float v[6]; float s2 = 0.f;
#pragma unroll
  for (int i = 0; i < 6; i++) { v[i] = x[base + i]; s2 += v[i] * v[i]; }
  for (int o = 1; o < 64; o <<= 1) s2 += __shfl_xor(s2, o, 64);
  if ((t & 63) == 0) lds4[t >> 6] = s2;
  __syncthreads();
  float ms = (lds4[0] + lds4[1] + lds4[2] + lds4[3]) * (1.f / DIMX);
  float rstd = rsqrtf(ms + 1e-6f);
#pragma unroll
  for (int i = 0; i < 6; i++) v[i] *= rstd * wgt[base + i];
  if (do_rope) {
#pragma unroll
    for (int j = 0; j < 3; j++) {
      int c = base + 2 * j;
      int pi = (c & (HDIM - 1)) >> 1;
      float cs = cosT[row * (HDIM / 2) + pi], sn = sinT[row * (HDIM / 2) + pi];
      float ev = v[2 * j], ov = v[2 * j + 1];
      v[2 * j] = ev * cs - ov * sn;
      v[2 * j + 1] = ov * cs + ev * sn;
    }
  }
#pragma unroll
  for (int i = 0; i < 6; i++) x[base + i] = v[i];
}

// ---------------------------------------------------------------------------
struct Outs {
  float *o0, *o1, *o2, *o3;
  const float *b0, *b1, *b2, *b3;
  us* ob;
};

// ===========================================================================
// gemm8pN: 8-wave (4M x 2N) 256 x (NP*32) tile, BK=64, 4 phases/K-tile,
// counted vmcnt tail-pinning. A(t+2) issued only in ph3 (A-buf reads done at
// ph2, barrier-separated); B(t+1) issued in ph0 into the opposite buffer.
// ===========================================================================
template<int NP, int NCHUNK, int OUT_BF16, int DO_GELU>
__global__ void __launch_bounds__(512, 2) gemm8pN(
    const us* __restrict__ A, const us* __restrict__ Bt,
    Outs outs, int M, int N, int K) {
  constexpr int NT = NP * 32;                 // N-tile
  constexpr int TOT = 16384 + NT * 64;        // elems per buffer (A + B)
  constexpr int BI = (NT * 8 + 511) / 512;    // B staging issues per thread
  constexpr int NH0 = NP / 2;
  __shared__ __align__(16) us S[2 * TOT];
  const int tid = threadIdx.x;
  const int lane = tid & 63;
  const int wid = tid >> 6;
  const int wr = wid >> 1, wc = wid & 1;       // 4M x 2N
  const int fr = lane & 15, xo = lane >> 4;
  const int r7 = fr & 7, q4 = xo * 4;
  int bx = blockIdx.x, by = blockIdx.y;
  xcd_map2(bx, by);
  const int tm = by * 256, tn = bx * NT;

  auto stA = [&](int buf, int k0) {
#pragma unroll
    for (int i = 0; i < 4; i++) {
      int c = i * 512 + tid;
      gl_lds16(A + (size_t)(tm + (c >> 3)) * K + k0 + (((c & 7) ^ ((c >> 3) & 7)) * 8),
               S + buf * TOT + (i * 512 + wid * 64) * 8);
    }
  };
  auto stB = [&](int buf, int k0) {
#pragma unroll
    for (int i = 0; i < BI; i++) {
      int c = i * 512 + tid;
      if (c < NT * 8)
        gl_lds16(Bt + (size_t)(tn + (c >> 3)) * K + k0 + (((c & 7) ^ ((c >> 3) & 7)) * 8),
                 S + buf * TOT + 16384 + (i * 512 + wid * 64) * 8);
    }
  };
  auto rdA = [&](int buf, int mp, int ks) -> bf16x8 {
    int r = wr * 64 + mp * 16 + fr;
    int ko = ((ks * 4 + xo) ^ r7) * 8;
    return *reinterpret_cast<const bf16x8*>(&S[buf * TOT + r * 64 + ko]);
  };
  auto rdB = [&](int buf, int np, int ks) -> bf16x8 {
    int r = wc * (NP * 16) + np * 16 + fr;
    int ko = ((ks * 4 + xo) ^ r7) * 8;
    return *reinterpret_cast<const bf16x8*>(&S[buf * TOT + 16384 + r * 64 + ko]);
  };

  f32x4 acc[4][NP];
#pragma unroll
  for (int m = 0; m < 4; m++)
#pragma unroll
    for (int n = 0; n < NP; n++) acc[m][n] = (f32x4)(0.f);
  bf16x8 aF[4], bF[NP];

  const int nt = K >> 6;
  // prologue: tile0 A+B, tile1 A
  stA(0, 0); stB(0, 0); stA(1, 64);
  asm volatile("s_waitcnt vmcnt(4)" ::: "memory");
  RAW_BAR();

  for (int t = 0; t < nt; t++) {
    const int buf = t & 1;
    const int k1 = (t + 1) << 6, k2 = (t + 2) << 6;
    // ---- ph0: ks0, np [0,NH0) ----
#pragma unroll
    for (int m = 0; m < 4; m++) aF[m] = rdA(buf, m, 0);
#pragma unroll
    for (int n = 0; n < NH0; n++) bF[n] = rdB(buf, n, 0);
    if (t + 1 < nt) stB(buf ^ 1, k1);
    RAW_BAR();
    __builtin_amdgcn_s_setprio(1);
#pragma unroll
    for (int m = 0; m < 4; m++)
#pragma unroll
      for (int n = 0; n < NH0; n++)
        acc[m][n] = __builtin_amdgcn_mfma_f32_16x16x32_bf16(aF[m], bF[n], acc[m][n], 0, 0, 0);
    __builtin_amdgcn_s_setprio(0);
    RAW_BAR();
    // ---- ph1: ks0, np [NH0,NP) ----
#pragma unroll
    for (int n = NH0; n < NP; n++) bF[n] = rdB(buf, n, 0);
    RAW_BAR();
    __builtin_amdgcn_s_setprio(1);
#pragma unroll
    for (int m = 0; m < 4; m++)
#pragma unroll
      for (int n = NH0; n < NP; n++)
        acc[m][n] = __builtin_amdgcn_mfma_f32_16x16x32_bf16(aF[m], bF[n], acc[m][n], 0, 0, 0);
    __builtin_amdgcn_s_setprio(0);
    RAW_BAR();
    // ---- ph2: ks1, np [0,NH0) ----
#pragma unroll
    for (int m = 0; m < 4; m++) aF[m] = rdA(buf, m, 1);
#pragma unroll
    for (int n = 0; n < NH0; n++) bF[n] = rdB(buf, n, 1);
    RAW_BAR();
    __builtin_amdgcn_s_setprio(1);
#pragma unroll
    for (int m = 0; m < 4; m++)
#pragma unroll
      for (int n = 0; n < NH0; n++)
        acc[m][n] = __builtin_amdgcn_mfma_f32_16x16x32_bf16(aF[m], bF[n], acc[m][n], 0, 0, 0);
    __builtin_amdgcn_s_setprio(0);
    RAW_BAR();
    // ---- ph3: ks1, np [NH0,NP) ----  (A-buf fully read at ph2 -> safe to issue)
#pragma unroll
    for (int n = NH0; n < NP; n++) bF[n] = rdB(buf, n, 1);
    if (t + 2 < nt) stA(buf, k2);
    RAW_BAR();
    __builtin_amdgcn_s_setprio(1);
#pragma unroll
    for (int m = 0; m < 4; m++)
#pragma unroll
      for (int n = NH0; n < NP; n++)
        acc[m][n] = __builtin_amdgcn_mfma_f32_16x16x32_bf16(aF[m], bF[n], acc[m][n], 0, 0, 0);
    __builtin_amdgcn_s_setprio(0);
    if (t + 2 < nt) asm volatile("s_waitcnt vmcnt(4)" ::: "memory");
    else            asm volatile("s_waitcnt vmcnt(0)" ::: "memory");
    RAW_BAR();
  }

  // epilogue
#pragma unroll
  for (int m = 0; m < 4; m++)
#pragma unroll
    for (int n = 0; n < NP; n++) {
      int col = tn + wc * (NP * 16) + n * 16 + fr;
      int rowb = tm + wr * 64 + m * 16 + q4;
      int c2; float* op; const float* bp;
      if constexpr (NCHUNK == 1) {
        c2 = col; op = outs.o0; bp = outs.b0;
      } else {
        int sel = col >= 3 * DIMX ? 3 : (col >= 2 * DIMX ? 2 : (col >= DIMX ? 1 : 0));
        c2 = col - sel * DIMX;
        op = sel == 0 ? outs.o0 : (sel == 1 ? outs.o1 : (sel == 2 ? outs.o2 : outs.o3));
        bp = sel == 0 ? outs.b0 : (sel == 1 ? outs.b1 : (sel == 2 ? outs.b2 : outs.b3));
      }
      float bv = bp[c2];
#pragma unroll
      for (int r = 0; r < 4; r++) {
        float v = acc[m][n][r] + bv;
        if (DO_GELU) {
          float u = 1.5957691216057308f * (v + 0.044715f * v * v * v);
          v = v / (1.f + __expf(-u));
        }
        if (OUT_BF16)
          outs.ob[(size_t)(rowb + r) * N + col] = f2bf(v);
        else
          op[(size_t)(rowb + r) * DIMX + c2] = v;
      }
    }
}

// ===========================================================================
// round-4 verified 256^2 8-phase (kept for FFN2 split-K; grid 240 = 94% fill)
// ===========================================================================
template<int NCHUNK, int OUT_BF16, int DO_GELU, int SPLITK>
__global__ void __launch_bounds__(512, 2) gemm8p(
    const us* __restrict__ A, const us* __restrict__ Bt,
    Outs outs, int M, int N, int K, int Kfull) {
  __shared__ __align__(16) us S[65536];
  const int tid = threadIdx.x;
  const int lane = tid & 63;
  const int wid = tid >> 6;
  const int wr = wid >> 2, wc = wid & 3;
  const int fr = lane & 15, xo = lane >> 4;
  const int r7 = fr & 7, q4 = xo * 4;
  int bx = blockIdx.x, by = blockIdx.y;
  xcd_map2(bx, by);
  const int tm = by * 256, tn = bx * 256;
  const size_t kb = SPLITK ? (size_t)blockIdx.z * K : 0;

  const int r6 = tid >> 3;
  const int sc8 = ((tid & 7) ^ (r6 & 7)) * 8;
  const int arow0 = tm + r6;
  const int brow0 = tn + ((r6 >> 5) << 6) + (r6 & 31);
  us* ldsw = S + wid * 512;

  auto stA = [&](int buf, int k0, int mh) {
#pragma unroll
    for (int i = 0; i < 2; i++)
      gl_lds16(A + (size_t)(arow0 + i * 128 + mh * 64) * Kfull + kb + k0 + sc8,
               ldsw + buf * 32768 + (mh * 2 + i) * 4096);
  };
  auto stB = [&](int buf, int k0, int nh) {
#pragma unroll
    for (int i = 0; i < 2; i++)
      gl_lds16(Bt + (size_t)(brow0 + i * 128 + nh * 32) * Kfull + kb + k0 + sc8,
               ldsw + buf * 32768 + 16384 + (nh * 2 + i) * 4096);
  };
  auto rdA = [&](int buf, int mh, int mp, int ks) -> bf16x8 {
    int lr = mh * 128 + wr * 64 + mp * 16 + fr;
    int ko = ((ks * 4 + xo) ^ r7) * 8;
    return *reinterpret_cast<const bf16x8*>(&S[buf * 32768 + lr * 64 + ko]);
  };
  auto rdB = [&](int buf, int nh, int np, int ks) -> bf16x8 {
    int lr = nh * 128 + (wc >> 1) * 64 + (wc & 1) * 32 + np * 16 + fr;
    int ko = ((ks * 4 + xo) ^ r7) * 8;
    return *reinterpret_cast<const bf16x8*>(&S[buf * 32768 + 16384 + lr * 64 + ko]);
  };

  f32x4 acc[2][2][4][2];
#pragma unroll
  for (int a = 0; a < 2; a++)
#pragma unroll
    for (int b = 0; b < 2; b++)
#pragma unroll
      for (int c = 0; c < 4; c++)
#pragma unroll
        for (int d = 0; d < 2; d++) acc[a][b][c][d] = (f32x4)(0.f);
  bf16x8 aF[2][4][2], bF[2][2];

  stA(0, 0, 0); stA(0, 0, 1); stB(0, 0, 0); stB(0, 0, 1);
  stA(1, 64, 0); stA(1, 64, 1); stB(1, 64, 0);
  asm volatile("s_waitcnt vmcnt(6)" ::: "memory");
  RAW_BAR();

  const int nt = K >> 6;
  for (int t = 0; t < nt; t++) {
    const int buf = t & 1;
    const int k1 = (t + 1) << 6, k2 = (t + 2) << 6;
    const bool n1 = (t + 1) < nt, n2 = (t + 2) < nt;
#pragma unroll
    for (int mp = 0; mp < 4; mp++)
#pragma unroll
      for (int ks = 0; ks < 2; ks++) aF[0][mp][ks] = rdA(buf, 0, mp, ks);
#pragma unroll
    for (int np = 0; np < 2; np++)
#pragma unroll
      for (int ks = 0; ks < 2; ks++) bF[np][ks] = rdB(buf, 0, np, ks);
    if (n1) stB(buf ^ 1, k1, 1);
    RAW_BAR();
    __builtin_amdgcn_s_setprio(1);
#pragma unroll
    for (int ks = 0; ks < 2; ks++)
#pragma unroll
      for (int mp = 0; mp < 4; mp++)
#pragma unroll
        for (int np = 0; np < 2; np++)
          acc[0][0][mp][np] = __builtin_amdgcn_mfma_f32_16x16x32_bf16(
              aF[0][mp][ks], bF[np][ks], acc[0][0][mp][np], 0, 0, 0);
    __builtin_amdgcn_s_setprio(0);
    RAW_BAR();
#pragma unroll
    for (int mp = 0; mp < 4; mp++)
#pragma unroll
      for (int ks = 0; ks < 2; ks++) aF[1][mp][ks] = rdA(buf, 1, mp, ks);
    if (n2) stA(buf, k2, 0);
    RAW_BAR();
    __builtin_amdgcn_s_setprio(1);
#pragma unroll
    for (int ks = 0; ks < 2; ks++)
#pragma unroll
      for (int mp = 0; mp < 4; mp++)
#pragma unroll
        for (int np = 0; np < 2; np++)
          acc[1][0][mp][np] = __builtin_amdgcn_mfma_f32_16x16x32_bf16(
              aF[1][mp][ks], bF[np][ks], acc[1][0][mp][np], 0, 0, 0);
    __builtin_amdgcn_s_setprio(0);
    RAW_BAR();
#pragma unroll
    for (int np = 0; np < 2; np++)
#pragma unroll
      for (int ks = 0; ks < 2; ks++) bF[np][ks] = rdB(buf, 1, np, ks);
    if (n2) stA(buf, k2, 1);
    RAW_BAR();
    __builtin_amdgcn_s_setprio(1);
#pragma unroll
    for (int ks = 0; ks < 2; ks++)
#pragma unroll
      for (int mp = 0; mp < 4; mp++)
#pragma unroll
        for (int np = 0; np < 2; np++)
          acc[1][1][mp][np] = __builtin_amdgcn_mfma_f32_16x16x32_bf16(
              aF[1][mp][ks], bF[np][ks], acc[1][1][mp][np], 0, 0, 0);
    __builtin_amdgcn_s_setprio(0);
    RAW_BAR();
    if (n2) stB(buf, k2, 0);
    RAW_BAR();
    __builtin_amdgcn_s_setprio(1);
#pragma unroll
    for (int ks = 0; ks < 2; ks++)
#pragma unroll
      for (int mp = 0; mp < 4; mp++)
#pragma unroll
        for (int np = 0; np < 2; np++)
          acc[0][1][mp][np] = __builtin_amdgcn_mfma_f32_16x16x32_bf16(
              aF[0][mp][ks], bF[np][ks], acc[0][1][mp][np], 0, 0, 0);
    __builtin_amdgcn_s_setprio(0);
    if (n2) asm volatile("s_waitcnt vmcnt(6)" ::: "memory");
    else    asm volatile("s_waitcnt vmcnt(0)" ::: "memory");
    RAW_BAR();
  }

#pragma unroll
  for (int mh = 0; mh < 2; mh++)
#pragma unroll
    for (int nh = 0; nh < 2; nh++)
#pragma unroll
      for (int mp = 0; mp < 4; mp++)
#pragma unroll
        for (int np = 0; np < 2; np++) {
          int col = tn + wc * 64 + nh * 32 + np * 16 + fr;
          int rowb = tm + wr * 128 + mh * 64 + mp * 16 + q4;
          if (SPLITK) {
            float* P = outs.o0 + (size_t)blockIdx.z * M * N;
#pragma unroll
            for (int r = 0; r < 4; r++)
              P[(size_t)(rowb + r) * N + col] = acc[mh][nh][mp][np][r];
          } else {
            int c2; float* op; const float* bp;
            if constexpr (NCHUNK == 1) {
              c2 = col; op = outs.o0; bp = outs.b0;
            } else {
              int sel = col >= 3 * DIMX ? 3 : (col >= 2 * DIMX ? 2 : (col >= DIMX ? 1 : 0));
              c2 = col - sel * DIMX;
              op = sel == 0 ? outs.o0 : (sel == 1 ? outs.o1 : (sel == 2 ? outs.o2 : outs.o3));
              bp = sel == 0 ? outs.b0 : (sel == 1 ? outs.b1 : (sel == 2 ? outs.b2 : outs.b3));
            }
            float bv = bp[c2];
#pragma unroll
            for (int r = 0; r < 4; r++) {
              float v = acc[mh][nh][mp][np][r] + bv;
              if (DO_GELU) {
                float u = 1.5957691216057308f * (v + 0.044715f * v * v * v);
                v = v / (1.f + __expf(-u));
              }
              if (OUT_BF16)
                outs.ob[(size_t)(rowb + r) * N + col] = f2bf(v);
              else
                op[(size_t)(rowb + r) * DIMX + c2] = v;
            }
          }
        }
}

// ---------------------------------------------------------------------------
// 128x128 kernels for the small GEMMs
template<int NCHUNK>
__global__ void __launch_bounds__(256) gemm_multi(
    const us* __restrict__ A, const us* __restrict__ Bt,
    Outs outs, int M, int N, int K) {
  __shared__ __align__(16) us As[128 * 64];
  __shared__ __align__(16) us Bs[128 * 64];
  const int tid = threadIdx.x;
  const int lane = tid & 63;
  const int w = tid >> 6;
  const int wr = w >> 1, wc = w & 1;
  const int fr = lane & 15;
  const int xo = lane >> 4;
  const int r7 = fr & 7;
  const int q4 = xo * 4;
  int bx = blockIdx.x, by = blockIdx.y;
  xcd_map2(bx, by);
  const int tm = by * 128, tn = bx * 128;

  f32x4 acc[4][4];
#pragma unroll
  for (int m = 0; m < 4; m++)
#pragma unroll
    for (int n = 0; n < 4; n++) acc[m][n] = (f32x4)(0.f);

  int srow[4], skc[4];
#pragma unroll
  for (int j = 0; j < 4; j++) {
    int c = j * 256 + tid;
    srow[j] = c >> 3;
    skc[j] = ((c & 7) ^ ((c >> 3) & 7)) * 8;
  }

  for (int k0 = 0; k0 < K; k0 += 64) {
#pragma unroll
    for (int j = 0; j < 4; j++) {
      gl_lds16(A + (size_t)(tm + srow[j]) * K + k0 + skc[j], As + (j * 256 + w * 64) * 8);
      gl_lds16(Bt + (size_t)(tn + srow[j]) * K + k0 + skc[j], Bs + (j * 256 + w * 64) * 8);
    }
    __syncthreads();
    bf16x8 af[2][4], bfv[2][4];
#pragma unroll
    for (int ks = 0; ks < 2; ks++) {
      const int koff = (((ks * 4 + xo) ^ r7) << 3);
#pragma unroll
      for (int m = 0; m < 4; m++)
        af[ks][m] = *reinterpret_cast<const bf16x8*>(&As[(wr * 64 + m * 16 + fr) * 64 + koff]);
#pragma unroll
      for (int n = 0; n < 4; n++)
        bfv[ks][n] = *reinterpret_cast<const bf16x8*>(&Bs[(wc * 64 + n * 16 + fr) * 64 + koff]);
    }
#pragma unroll
    for (int ks = 0; ks < 2; ks++)
#pragma unroll
      for (int m = 0; m < 4; m++)
#pragma unroll
        for (int n = 0; n < 4; n++)
          acc[m][n] = __builtin_amdgcn_mfma_f32_16x16x32_bf16(af[ks][m], bfv[ks][n], acc[m][n], 0, 0, 0);
    __syncthreads();
  }
#pragma unroll
  for (int m = 0; m < 4; m++) {
#pragma unroll
    for (int n = 0; n < 4; n++) {
      int col = tn + wc * 64 + n * 16 + fr;
      int c2; float* op; const float* bp;
      if constexpr (NCHUNK == 2) {
        int sel = col >= DIMX;
        c2 = col - sel * DIMX;
        op = sel ? outs.o1 : outs.o0;
        bp = sel ? outs.b1 : outs.b0;
      } else {
        c2 = col; op = outs.o0; bp = outs.b0;
      }
      float bv = bp[c2];
#pragma unroll
      for (int r = 0; r < 4; r++) {
        int row = tm + wr * 64 + m * 16 + q4 + r;
        op[(size_t)row * DIMX + c2] = acc[m][n][r] + bv;
      }
    }
  }
}

__global__ void __launch_bounds__(256) gemm_splitk(
    const us* __restrict__ A, const us* __restrict__ Bt,
    float* __restrict__ P, int M, int N, int Kfull, int Ks) {
  __shared__ __align__(16) us As[128 * 64];
  __shared__ __align__(16) us Bs[128 * 64];
  const int tid = threadIdx.x;
  const int lane = tid & 63;
  const int w = tid >> 6;
  const int wr = w >> 1, wc = w & 1;
  const int fr = lane & 15;
  const int xo = lane >> 4;
  const int r7 = fr & 7;
  const int q4 = xo * 4;
  int bx = blockIdx.x, by = blockIdx.y;
  xcd_map2(bx, by);
  const int tm = by * 128, tn = bx * 128;
  const int slice = blockIdx.z;
  const int kbase = slice * Ks;
  float* __restrict__ Pout = P + (size_t)slice * M * N;

  f32x4 acc[4][4];
#pragma unroll
  for (int m = 0; m < 4; m++)
#pragma unroll
    for (int n = 0; n < 4; n++) acc[m][n] = (f32x4)(0.f);

  int srow[4], skc[4];
#pragma unroll
  for (int j = 0; j < 4; j++) {
    int c = j * 256 + tid;
    srow[j] = c >> 3;
    skc[j] = ((c & 7) ^ ((c >> 3) & 7)) * 8;
  }

  for (int k0 = 0; k0 < Ks; k0 += 64) {
#pragma unroll
    for (int j = 0; j < 4; j++) {
      gl_lds16(A + (size_t)(tm + srow[j]) * Kfull + kbase + k0 + skc[j], As + (j * 256 + w * 64) * 8);
      gl_lds16(Bt + (size_t)(tn + srow[j]) * Kfull + kbase + k0 + skc[j], Bs + (j * 256 + w * 64) * 8);
    }
    __syncthreads();
    bf16x8 af[2][4], bfv[2][4];
#pragma unroll
    for (int ks = 0; ks < 2; ks++) {
      const int koff = (((ks * 4 + xo) ^ r7) << 3);
#pragma unroll
      for (int m = 0; m < 4; m++)
        af[ks][m] = *reinterpret_cast<const bf16x8*>(&As[(wr * 64 + m * 16 + fr) * 64 + koff]);
#pragma unroll
      for (int n = 0; n < 4; n++)
        bfv[ks][n] = *reinterpret_cast<const bf16x8*>(&Bs[(wc * 64 + n * 16 + fr) * 64 + koff]);
    }
#pragma unroll
    for (int ks = 0; ks < 2; ks++)
#pragma unroll
      for (int m = 0; m < 4; m++)
#pragma unroll
        for (int n = 0; n < 4; n++)
          acc[m][n] = __builtin_amdgcn_mfma_f32_16x16x32_bf16(af[ks][m], bfv[ks][n], acc[m][n], 0, 0, 0);
    __syncthreads();
  }
#pragma unroll
  for (int m = 0; m < 4; m++)
#pragma unroll
    for (int n = 0; n < 4; n++) {
      int col = tn + wc * 64 + n * 16 + fr;
#pragma unroll
      for (int r = 0; r < 4; r++) {
        int row = tm + wr * 64 + m * 16 + q4 + r;
        Pout[(size_t)row * N + col] = acc[m][n][r];
      }
    }
}

template<int S>
__global__ void __launch_bounds__(256) reduce_kernel(
    const float* __restrict__ P, const float* __restrict__ bias,
    const float* __restrict__ R, const float* __restrict__ g,
    float* __restrict__ O, int total4, int ncol4) {
  const f4* P4 = (const f4*)P;
  const f4* R4 = (const f4*)R;
  f4* O4 = (f4*)O;
  for (int i = blockIdx.x * 256 + threadIdx.x; i < total4; i += gridDim.x * 256) {
    f4 s = P4[i];
#pragma unroll
    for (int sl = 1; sl < S; sl++) s += P4[(size_t)sl * total4 + i];
    int c4 = (i % ncol4) * 4;
    s += *reinterpret_cast<const f4*>(&bias[c4]);
    if (R) {
      if (g) {
        f4 gv = *reinterpret_cast<const f4*>(&g[c4]);
        s = R4[i] + gv * s;
      } else {
        s = R4[i] + s;
      }
    }
    O4[i] = s;
  }
}

// ---------------------------------------------------------------------------
__global__ void __launch_bounds__(256) attn_kernel(
    const float* __restrict__ Q, const float* __restrict__ Kx,
    const float* __restrict__ V, const int* __restrict__ idx,
    const float* __restrict__ G, const float* __restrict__ CB,
    us* __restrict__ Out) {
  __shared__ us q_s[64 * 136];
  __shared__ us k_s[64 * 136];
  __shared__ us vT_s[128 * 72];
  __shared__ us p_s[64 * 72];
  __shared__ float red[4 * 64];
  __shared__ float m_run[64], l_run[64], alpha_s[64];

  const int qb = blockIdx.x;
  const int h = blockIdx.y;
  const int tid = threadIdx.x;
  const int lane = tid & 63;
  const int w = tid >> 6;
  const int fr = lane & 15;
  const int k8 = (lane >> 4) * 8;
  const int q4 = (lane >> 4) * 4;

#pragma unroll
  for (int i = 0; i < 8; i++) {
    int s = tid + 256 * i;
    int row = s >> 5, cq = (s & 31) * 4;
    f4 v = *reinterpret_cast<const f4*>(&Q[(size_t)(qb * 64 + row) * DIMX + h * HDIM + cq]);
    us4 hh; hh[0] = f2bf(v[0]); hh[1] = f2bf(v[1]); hh[2] = f2bf(v[2]); hh[3] = f2bf(v[3]);
    *reinterpret_cast<us4*>(&q_s[row * 136 + cq]) = hh;
  }
  if (tid < 64) { m_run[tid] = -1e30f; l_run[tid] = 0.f; }

  f32x4 acc_o[4][2];
#pragma unroll
  for (int m = 0; m < 4; m++)
#pragma unroll
    for (int n = 0; n < 2; n++) acc_o[m][n] = (f32x4)(0.f);

  for (int ib = 0; ib < 8; ib++) {
    int blk = idx ? idx[(h * NBLK + qb) * 8 + ib] : ib;
    __syncthreads();
#pragma unroll
    for (int i = 0; i < 8; i++) {
      int s = tid + 256 * i;
      int row = s >> 5, cq = (s & 31) * 4;
      f4 v = *reinterpret_cast<const f4*>(&Kx[(size_t)(blk * 64 + row) * DIMX + h * HDIM + cq]);
      us4 hh; hh[0] = f2bf(v[0]); hh[1] = f2bf(v[1]); hh[2] = f2bf(v[2]); hh[3] = f2bf(v[3]);
      *reinterpret_cast<us4*>(&k_s[row * 136 + cq]) = hh;
    }
    {
      int d = tid & 127, th = (tid >> 7) * 32;
#pragma unroll
      for (int j = 0; j < 4; j++) {
        us8 hv;
#pragma unroll
        for (int qq = 0; qq < 8; qq++)
          hv[qq] = f2bf(V[(size_t)(blk * 64 + th + j * 8 + qq) * DIMX + h * HDIM + d]);
        *reinterpret_cast<us8*>(&vT_s[d * 72 + th + j * 8]) = hv;
      }
    }
    __syncthreads();
    f32x4 accs[4];
#pragma unroll
    for (int m = 0; m < 4; m++) accs[m] = (f32x4)(0.f);
#pragma unroll
    for (int kk = 0; kk < 128; kk += 32) {
      bf16x8 bfr = *reinterpret_cast<const bf16x8*>(&k_s[(w * 16 + fr) * 136 + kk + k8]);
#pragma unroll
      for (int m = 0; m < 4; m++) {
        bf16x8 afr = *reinterpret_cast<const bf16x8*>(&q_s[(m * 16 + fr) * 136 + kk + k8]);
        accs[m] = __builtin_amdgcn_mfma_f32_16x16x32_bf16(afr, bfr, accs[m], 0, 0, 0);
      }
    }
#pragma unroll
    for (int m = 0; m < 4; m++) {
#pragma unroll
      for (int r = 0; r < 4; r++) {
        accs[m][r] *= SCALE_ATT;
        float v = accs[m][r];
        for (int o = 1; o < 16; o <<= 1) v = fmaxf(v, __shfl_xor(v, o, 64));
        if (fr == 0) red[w * 64 + m * 16 + q4 + r] = v;
      }
    }
    __syncthreads();
    if (tid < 64) {
      float bm = fmaxf(fmaxf(red[tid], red[64 + tid]), fmaxf(red[128 + tid], red[192 + tid]));
      float mo = m_run[tid];
      float mn = fmaxf(mo, bm);
      float al = __expf(mo - mn);
      alpha_s[tid] = al;
      m_run[tid] = mn;
      l_run[tid] *= al;
    }
    __syncthreads();
#pragma unroll
    for (int m = 0; m < 4; m++) {
#pragma unroll
      for (int r = 0; r < 4; r++) {
        int row = m * 16 + q4 + r;
        float p = __expf(accs[m][r] - m_run[row]);
        p_s[row * 72 + w * 16 + fr] = f2bf(p);
        float sv = p;
        for (int o = 1; o < 16; o <<= 1) sv += __shfl_xor(sv, o, 64);
        if (fr == 0) red[w * 64 + row] = sv;
      }
    }
#pragma unroll
    for (int m = 0; m < 4; m++) {
      float a0 = alpha_s[m * 16 + q4 + 0];
      float a1 = alpha_s[m * 16 + q4 + 1];
      float a2 = alpha_s[m * 16 + q4 + 2];
      float a3 = alpha_s[m * 16 + q4 + 3];
#pragma unroll
      for (int n = 0; n < 2; n++) {
        acc_o[m][n][0] *= a0; acc_o[m][n][1] *= a1;
        acc_o[m][n][2] *= a2; acc_o[m][n][3] *= a3;
      }
    }
    __syncthreads();
    if (tid < 64) l_run[tid] += red[tid] + red[64 + tid] + red[128 + tid] + red[192 + tid];
#pragma unroll
    for (int kk = 0; kk < 64; kk += 32) {
      bf16x8 pa[4];
#pragma unroll
      for (int m = 0; m < 4; m++)
        pa[m] = *reinterpret_cast<const bf16x8*>(&p_s[(m * 16 + fr) * 72 + kk + k8]);
#pragma unroll
      for (int n = 0; n < 2; n++) {
        bf16x8 vb = *reinterpret_cast<const bf16x8*>(&vT_s[(w * 32 + n * 16 + fr) * 72 + kk + k8]);
#pragma unroll
        for (int m = 0; m < 4; m++)
          acc_o[m][n] = __builtin_amdgcn_mfma_f32_16x16x32_bf16(pa[m], vb, acc_o[m][n], 0, 0, 0);
      }
    }
  }
  __syncthreads();
#pragma unroll
  for (int m = 0; m < 4; m++) {
#pragma unroll
    for (int n = 0; n < 2; n++) {
#pragma unroll
      for (int r = 0; r < 4; r++) {
        int row = m * 16 + q4 + r;
        int srow = qb * 64 + row;
        int d = w * 32 + n * 16 + fr;
        float o = acc_o[m][n][r] / l_run[row];
        size_t oi = (size_t)srow * DIMX + h * HDIM + d;
        if (G) o += G[oi] * CB[(size_t)qb * DIMX + h * HDIM + d];
        Out[oi] = f2bf(o);
      }
    }
  }
}

// ---------------------------------------------------------------------------
__global__ void __launch_bounds__(128) block_mean_kernel(const float* __restrict__ X,
                                                         float* __restrict__ Outc) {
  int n = blockIdx.x, h = blockIdx.y, d = threadIdx.x;
  float s = 0.f;
  for (int t = 0; t < 64; t++) s += X[(size_t)(n * 64 + t) * DIMX + h * HDIM + d];
  Outc[(n * NHEAD + h) * HDIM + d] = s * (1.f / 64.f);
}

__global__ void __launch_bounds__(256) coarse_attn_kernel(const float* __restrict__ qc,
                                                          const float* __restrict__ kc,
                                                          float* __restrict__ pc,
                                                          int* __restrict__ idxout) {
  int h = blockIdx.x, t = threadIdx.x;
  __shared__ float sm[32][32];
  for (int p = t; p < 1024; p += 256) {
    int n = p >> 5, m = p & 31;
    float dot = 0.f;
    for (int d = 0; d < HDIM; d++)
      dot += qc[n * DIMX + h * HDIM + d] * kc[m * DIMX + h * HDIM + d];
    sm[n][m] = dot * SCALE_ATT;
  }
  __syncthreads();
  if (t < 32) {
    int n = t;
    float mx = -1e30f;
#pragma unroll
    for (int m = 0; m < 32; m++) mx = fmaxf(mx, sm[n][m]);
    float pv[32]; float ssum = 0.f;
#pragma unroll
    for (int m = 0; m < 32; m++) { pv[m] = __expf(sm[n][m] - mx); ssum += pv[m]; }
    float inv = 1.f / ssum;
#pragma unroll
    for (int m = 0; m < 32; m++) { pv[m] *= inv; pc[(h * 32 + n) * 32 + m] = pv[m]; }
    unsigned chosen = 0;
    for (int i = 0; i < 8; i++) {
      float best = -1.f; int bi = 0;
#pragma unroll
      for (int m = 0; m < 32; m++)
        if (!((chosen >> m) & 1u) && pv[m] > best) { best = pv[m]; bi = m; }
      chosen |= 1u << bi;
      idxout[(h * 32 + n) * 8 + i] = bi;
    }
  }
}

__global__ void __launch_bounds__(128) coarse_ctx_kernel(const float* __restrict__ pc,
                                                         const float* __restrict__ vc,
                                                         float* __restrict__ cb) {
  int n = blockIdx.x, h = blockIdx.y, d = threadIdx.x;
  float s = 0.f;
  for (int m = 0; m < 32; m++)
    s += pc[(h * 32 + n) * 32 + m] * vc[(m * NHEAD + h) * HDIM + d];
  cb[(n * NHEAD + h) * HDIM + d] = s;
}

// ---------------------------------------------------------------------------
extern "C" void kernel_launch(void* const* d_in, const int* in_sizes, int n_in,
                              void* d_out, int out_size, void* d_ws, size_t ws_size,
                              hipStream_t stream) {
  (void)in_sizes; (void)n_in; (void)out_size; (void)ws_size;
  const float* hidden = (const float*)d_in[0];
  const float* enc    = (const float*)d_in[1];
  const float* temb   = (const float*)d_in[2];
  const float* cosT   = (const float*)d_in[3];
  const float* sinT   = (const float*)d_in[4];
  const float* sst    = (const float*)d_in[5];
  const float* Wq = (const float*)d_in[6];   const float* bq = (const float*)d_in[7];
  const float* Wk = (const float*)d_in[8];   const float* bk = (const float*)d_in[9];
  const float* Wv = (const float*)d_in[10];  const float* bv = (const float*)d_in[11];
  const float* Wg = (const float*)d_in[12];  const float* bg = (const float*)d_in[13];
  const float* Wo = (const float*)d_in[14];  const float* bo = (const float*)d_in[15];
  const float* qnw = (const float*)d_in[16]; const float* knw = (const float*)d_in[17];
  const float* saw = (const float*)d_in[18]; const float* sab = (const float*)d_in[19];
  const float* cWq = (const float*)d_in[20]; const float* cbq = (const float*)d_in[21];
  const float* cWk = (const float*)d_in[22]; const float* cbk = (const float*)d_in[23];
  const float* cWv = (const float*)d_in[24]; const float* cbv = (const float*)d_in[25];
  const float* cWo = (const float*)d_in[26]; const float* cbo = (const float*)d_in[27];
  const float* cqnw = (const float*)d_in[28]; const float* cknw = (const float*)d_in[29];
  const float* W1 = (const float*)d_in[30];  const float* b1 = (const float*)d_in[31];
  const float* W2 = (const float*)d_in[32];  const float* b2 = (const float*)d_in[33];

  char* ws = (char*)d_ws;
  size_t off = 0;
  auto alloc = [&](size_t bytes) -> void* {
    void* p = ws + off;
    off += (bytes + 255) & ~(size_t)255;
    return p;
  };
  const size_t SD = (size_t)SEQ * DIMX * 4;
  const size_t SDh = (size_t)SEQ * DIMX * 2;
  const size_t WSQ = (size_t)DIMX * DIMX * 2;
  float* e     = (float*)alloc(6 * DIMX * 4);
  us* normb    = (us*)alloc(SDh);
  float* qb_   = (float*)alloc(SD);
  float* kb_   = (float*)alloc(SD);
  float* vb_   = (float*)alloc(SD);
  float* gb_   = (float*)alloc(SD);
  float* qc    = (float*)alloc((size_t)NBLK * DIMX * 4);
  float* kc    = (float*)alloc((size_t)NBLK * DIMX * 4);
  float* vc    = (float*)alloc((size_t)NBLK * DIMX * 4);
  float* pc    = (float*)alloc(NHEAD * 32 * 32 * 4);
  int*   idx   = (int*)alloc(NHEAD * 32 * 8 * 4);
  float* cb    = (float*)alloc((size_t)NBLK * DIMX * 4);
  us* mixb     = (us*)alloc(SDh);
  float* res   = (float*)alloc(SD);
  us* encb     = (us*)alloc((size_t)L2X * DIMX * 2);
  us* wpack    = (us*)alloc(9 * WSQ);
  us* W1t      = (us*)alloc((size_t)DIMX * FFNX * 2);
  us* W2t      = (us*)alloc((size_t)FFNX * DIMX * 2);
  // aliases (lifetimes disjoint):
  us* ffh    = (us*)qb_;        // 36.7MB over qb_+kb_+vb_ (37.75MB)
  us* crossb = (us*)gb_;        // 6.3MB <= 12.6MB
  float* part2 = (float*)qb_;   // 2x12.58MB over qb_+kb_
  float* part5 = (float*)wpack; // 5x12.58MB over wpack(42.5)+W1t; both dead at FFN2
  float* outf  = (float*)d_out;
  const size_t SL = (size_t)DIMX * DIMX;
  us* Wot  = wpack + 4 * SL;
  us* cWqt = wpack + 5 * SL;
  us* cKVt = wpack + 6 * SL;
  us* cWot = wpack + 8 * SL;

  // ---- pack ----
  P9 p9; p9.s[0]=Wq; p9.s[1]=Wk; p9.s[2]=Wv; p9.s[3]=Wg; p9.s[4]=Wo;
  p9.s[5]=cWq; p9.s[6]=cWk; p9.s[7]=cWv; p9.s[8]=cWo;
  pack9_kernel<<<dim3(48, 48, 9), 256, 0, stream>>>(p9, wpack);
  pack_t_kernel<<<dim3(FFNX / 32, DIMX / 32), 256, 0, stream>>>(W1, W1t, DIMX, FFNX);
  pack_t_kernel<<<dim3(DIMX / 32, FFNX / 32), 256, 0, stream>>>(W2, W2t, FFNX, DIMX);
  pack_cvt_kernel<<<(L2X * DIMX / 4 + 255) / 256, 256, 0, stream>>>(enc, encb, L2X * DIMX / 4);
  prep_e_kernel<<<36, 256, 0, stream>>>(sst, temb, e);

  // ---- self-attention branch ----
  ln_affine_kernel<<<SEQ, 256, 0, stream>>>(hidden, e + DIMX, e, 1, normb);
  Outs qkvgo = {qb_, kb_, vb_, gb_, bq, bk, bv, bg, nullptr};
  gemm8pN<6, 4, 0, 0><<<dim3(32, 8), 512, 0, stream>>>(normb, wpack, qkvgo, SEQ, 4 * DIMX, DIMX);
  rms_rope_kernel<<<SEQ, 256, 0, stream>>>(qb_, qnw, cosT, sinT, 1);
  rms_rope_kernel<<<SEQ, 256, 0, stream>>>(kb_, knw, cosT, sinT, 1);
  dim3 gbm(NBLK, NHEAD);
  block_mean_kernel<<<gbm, 128, 0, stream>>>(qb_, qc);
  block_mean_kernel<<<gbm, 128, 0, stream>>>(kb_, kc);
  block_mean_kernel<<<gbm, 128, 0, stream>>>(vb_, vc);
  coarse_attn_kernel<<<NHEAD, 256, 0, stream>>>(qc, kc, pc, idx);
  coarse_ctx_kernel<<<gbm, 128, 0, stream>>>(pc, vc, cb);
  attn_kernel<<<dim3(NBLK, NHEAD), 256, 0, stream>>>(qb_, kb_, vb_, idx, gb_, cb, mixb);
  gemm_splitk<<<dim3(12, 16, 2), 256, 0, stream>>>(mixb, Wot, part2, SEQ, DIMX, DIMX, 768);
  reduce_kernel<2><<<1024, 256, 0, stream>>>(part2, bo, hidden, e + 2 * DIMX, res,
                                             SEQ * DIMX / 4, DIMX / 4);
  // ---- cross attention ----
  ln_affine_kernel<<<SEQ, 256, 0, stream>>>(res, saw, sab, 0, normb);
  gemm_splitk<<<dim3(12, 16, 2), 256, 0, stream>>>(normb, cWqt, part2, SEQ, DIMX, DIMX, 768);
  reduce_kernel<2><<<1024, 256, 0, stream>>>(part2, cbq, nullptr, nullptr, qb_,
                                             SEQ * DIMX / 4, DIMX / 4);
  rms_rope_kernel<<<SEQ, 256, 0, stream>>>(qb_, cqnw, cosT, sinT, 0);
  Outs ckvo = {kb_, vb_, nullptr, nullptr, cbk, cbv, nullptr, nullptr, nullptr};
  gemm_multi<2><<<dim3(24, 4), 256, 0, stream>>>(encb, cKVt, ckvo, L2X, 2 * DIMX, DIMX);
  rms_rope_kernel<<<L2X, 256, 0, stream>>>(kb_, cknw, cosT, sinT, 0);
  attn_kernel<<<dim3(NBLK, NHEAD), 256, 0, stream>>>(qb_, kb_, vb_, nullptr, nullptr, nullptr, crossb);
  gemm_splitk<<<dim3(12, 16, 2), 256, 0, stream>>>(crossb, cWot, part2, SEQ, DIMX, DIMX, 768);
  reduce_kernel<2><<<1024, 256, 0, stream>>>(part2, cbo, res, nullptr, outf,
                                             SEQ * DIMX / 4, DIMX / 4);
  // ---- FFN ----
  ln_affine_kernel<<<SEQ, 256, 0, stream>>>(outf, e + 4 * DIMX, e + 3 * DIMX, 1, normb);
  Outs f1o = {nullptr, nullptr, nullptr, nullptr, b1, nullptr, nullptr, nullptr, ffh};
  gemm8pN<5, 1, 1, 1><<<dim3(56, 8), 512, 0, stream>>>(normb, W1t, f1o, SEQ, FFNX, DIMX);
  Outs f2o = {part5, nullptr, nullptr, nullptr, nullptr, nullptr, nullptr, nullptr, nullptr};
  gemm8p<1, 0, 0, 1><<<dim3(6, 8, 5), 512, 0, stream>>>(ffh, W2t, f2o, SEQ, DIMX, 1792, FFNX);
  reduce_kernel<5><<<1024, 256, 0, stream>>>(part5, b2, outf, e + 5 * DIMX, outf,
                                             SEQ * DIMX / 4, DIMX / 4);
}

// Round 6
// 622.546 us; speedup vs baseline: 2.1962x; 1.0150x over previous
//
#include <hip/hip_runtime.h>
#include <hip/hip_bf16.h>
#include <math.h>

#define DIMX 1536
#define SEQ 2048
#define L2X 512
#define NHEAD 12
#define HDIM 128
#define NBLK 32
#define FFNX 8960
#define SCALE_ATT 0.08838834764831845f

typedef __attribute__((ext_vector_type(4))) float f4;
typedef __attribute__((ext_vector_type(4))) float f32x4;
typedef __attribute__((ext_vector_type(8))) short bf16x8;
typedef __attribute__((ext_vector_type(4))) unsigned short us4;
typedef __attribute__((ext_vector_type(8))) unsigned short us8;
typedef unsigned short us;

static __device__ __forceinline__ us f2bf(float f) {
  union { float f; unsigned u; } v; v.f = f;
  unsigned r = v.u + 0x7FFFu + ((v.u >> 16) & 1u);
  return (us)(r >> 16);
}

static __device__ __forceinline__ void gl_lds16(const us* g, us* l) {
  __builtin_amdgcn_global_load_lds(
      (const __attribute__((address_space(1))) void*)g,
      (__attribute__((address_space(3))) void*)l, 16, 0, 0);
}

#define RAW_BAR() asm volatile("s_barrier" ::: "memory")

// bijective XCD swizzle (requires gridDim.x*gridDim.y % 8 == 0)
static __device__ __forceinline__ void xcd_map2(int& bx, int& by) {
  int gx = gridDim.x, gy = gridDim.y;
  int nwg = gx * gy;
  int lin = by * gx + bx;
  int q = nwg >> 3;
  lin = (lin & 7) * q + (lin >> 3);
  bx = lin % gx;
  by = lin / gx;
}

// ---------------------------------------------------------------------------
__global__ void __launch_bounds__(256) prep_e_kernel(const float* __restrict__ sst,
                                                     const float* __restrict__ temb,
                                                     float* __restrict__ e) {
  int i = blockIdx.x * 256 + threadIdx.x;
  if (i < 6 * DIMX) e[i] = sst[i] + temb[i];
}

// ---------------------------------------------------------------------------
// 64x64 vectorized transpose-pack: W[K][N] f32 -> Wt[N][K] bf16
struct P9 { const float* s[9]; };

__global__ void __launch_bounds__(256) pack64_9(P9 ps, us* __restrict__ dst) {
  const float* __restrict__ W = ps.s[blockIdx.z];
  us* __restrict__ Wt = dst + (size_t)blockIdx.z * DIMX * DIMX;
  __shared__ float t[64][65];
  int n0 = blockIdx.x * 64, k0 = blockIdx.y * 64;
  int tid = threadIdx.x;
#pragma unroll
  for (int i = 0; i < 4; i++) {
    int c = i * 256 + tid;
    int row = c >> 4, c4 = (c & 15) * 4;
    *reinterpret_cast<f4*>(&t[row][c4]) =
        *reinterpret_cast<const f4*>(&W[(size_t)(k0 + row) * DIMX + n0 + c4]);
  }
  __syncthreads();
#pragma unroll
  for (int i = 0; i < 2; i++) {
    int c = i * 256 + tid;
    int n = c >> 3, kc = (c & 7) * 8;
    us8 h;
#pragma unroll
    for (int j = 0; j < 8; j++) h[j] = f2bf(t[kc + j][n]);
    *reinterpret_cast<us8*>(&Wt[(size_t)(n0 + n) * DIMX + k0 + kc]) = h;
  }
}

__global__ void __launch_bounds__(256) pack64_g(const float* __restrict__ W,
                                                us* __restrict__ Wt, int K, int N) {
  __shared__ float t[64][65];
  int n0 = blockIdx.x * 64, k0 = blockIdx.y * 64;
  int tid = threadIdx.x;
#pragma unroll
  for (int i = 0; i < 4; i++) {
    int c = i * 256 + tid;
    int row = c >> 4, c4 = (c & 15) * 4;
    *reinterpret_cast<f4*>(&t[row][c4]) =
        *reinterpret_cast<const f4*>(&W[(size_t)(k0 + row) * N + n0 + c4]);
  }
  __syncthreads();
#pragma unroll
  for (int i = 0; i < 2; i++) {
    int c = i * 256 + tid;
    int n = c >> 3, kc = (c & 7) * 8;
    us8 h;
#pragma unroll
    for (int j = 0; j < 8; j++) h[j] = f2bf(t[kc + j][n]);
    *reinterpret_cast<us8*>(&Wt[(size_t)(n0 + n) * K + k0 + kc]) = h;
  }
}

__global__ void __launch_bounds__(256) pack_cvt_kernel(const float* __restrict__ X,
                                                       us* __restrict__ Y, int n4) {
  int i = blockIdx.x * 256 + threadIdx.x;
  if (i < n4) {
    f4 v = *reinterpret_cast<const f4*>(&X[(size_t)i * 4]);
    us4 h; h[0] = f2bf(v[0]); h[1] = f2bf(v[1]); h[2] = f2bf(v[2]); h[3] = f2bf(v[3]);
    *reinterpret_cast<us4*>(&Y[(size_t)i * 4]) = h;
  }
}

// ---------------------------------------------------------------------------
__global__ void __launch_bounds__(256) ln_affine_kernel(
    const float* __restrict__ X, const float* __restrict__ a,
    const float* __restrict__ b, int add1, us* __restrict__ Out) {
  __shared__ float lds4[4];
  int row = blockIdx.x, t = threadIdx.x;
  const float* x = X + (size_t)row * DIMX;
  float v[6]; float s = 0.f;
#pragma unroll
  for (int i = 0; i < 6; i++) { v[i] = x[t + 256 * i]; s += v[i]; }
  for (int o = 1; o < 64; o <<= 1) s += __shfl_xor(s, o, 64);
  if ((t & 63) == 0) lds4[t >> 6] = s;
  __syncthreads();
  float mean = (lds4[0] + lds4[1] + lds4[2] + lds4[3]) * (1.f / DIMX);
  __syncthreads();
  float s2 = 0.f;
#pragma unroll
  for (int i = 0; i < 6; i++) { float c = v[i] - mean; s2 += c * c; }
  for (int o = 1; o < 64; o <<= 1) s2 += __shfl_xor(s2, o, 64);
  if ((t & 63) == 0) lds4[t >> 6] = s2;
  __syncthreads();
  float var = (lds4[0] + lds4[1] + lds4[2] + lds4[3]) * (1.f / DIMX);
  float rstd = rsqrtf(var + 1e-6f);
#pragma unroll
  for (int i = 0; i < 6; i++) {
    int c = t + 256 * i;
    float av = a[c] + (add1 ? 1.f : 0.f);
    Out[(size_t)row * DIMX + c] = f2bf((v[i] - mean) * rstd * av + b[c]);
  }
}

// ---------------------------------------------------------------------------
__global__ void __launch_bounds__(256) rms_rope_kernel(
    float* __restrict__ X, const float* __restrict__ wgt,
    const float* __restrict__ cosT, const float* __restrict__ sinT, int do_rope) {
  __shared__ float lds4[4];
  int row = blockIdx.x, t = threadIdx.x;
  float* x = X + (size_t)row * DIMX;
  int base = t * 6;
  float v[6]; float s2 = 0.f;
#pragma unroll
  for (int i = 0; i < 6; i++) { v[i] = x[base + i]; s2 += v[i] * v[i]; }
  for (int o = 1; o < 64; o <<= 1) s2 += __shfl_xor(s2, o, 64);
  if ((t & 63) == 0) lds4[t >> 6] = s2;
  __syncthreads();
  float ms = (lds4[0] + lds4[1] + lds4[2] + lds4[3]) * (1.f / DIMX);
  float rstd = rsqrtf(ms + 1e-6f);
#pragma unroll
  for (int i = 0; i < 6; i++) v[i] *= rstd * wgt[base + i];
  if (do_rope) {
#pragma unroll
    for (int j = 0; j < 3; j++) {
      int c = base + 2 * j;
      int pi = (c & (HDIM - 1)) >> 1;
      float cs = cosT[row * (HDIM / 2) + pi], sn = sinT[row * (HDIM / 2) + pi];
      float ev = v[2 * j], ov = v[2 * j + 1];
      v[2 * j] = ev * cs - ov * sn;
      v[2 * j + 1] = ov * cs + ev * sn;
    }
  }
#pragma unroll
  for (int i = 0; i < 6; i++) x[base + i] = v[i];
}

// ---------------------------------------------------------------------------
struct Outs {
  float *o0, *o1, *o2, *o3;
  const float *b0, *b1, *b2, *b3;
  us* ob;
};

// ===========================================================================
// gemm2ph: 8-wave (4M x 2N) 256 x (NP*32) tile, BK=64, 2 phases/K-tile.
// ph0: read all aF + bF[0..NH0), issue stB(t+1); bar; MFMA; bar.
// ph1: read bF[NH0..NP), issue stA(t+2); bar; MFMA; vmcnt(4); bar.
// Boundary vmcnt(4) drains exactly stA(t+1)+stB(t+1), pins stA(t+2).
// ===========================================================================
template<int NP, int NCHUNK, int OUT_BF16, int DO_GELU, int SPLITK>
__global__ void __launch_bounds__(512, 2) gemm2ph(
    const us* __restrict__ A, const us* __restrict__ Bt,
    Outs outs, int M, int N, int K, int Kfull) {
  constexpr int NT = NP * 32;
  constexpr int TOT = 16384 + NT * 64;
  constexpr int BI = (NT * 8 + 511) / 512;
  constexpr int NH0 = NP / 2;
  constexpr int NH1 = NP - NH0;
  __shared__ __align__(16) us S[2 * TOT];
  const int tid = threadIdx.x;
  const int lane = tid & 63;
  const int wid = tid >> 6;
  const int wr = wid >> 1, wc = wid & 1;   // 4M x 2N
  const int fr = lane & 15, xo = lane >> 4;
  const int r7 = fr & 7, q4 = xo * 4;
  int bx = blockIdx.x, by = blockIdx.y;
  xcd_map2(bx, by);
  const int tm = by * 256, tn = bx * NT;
  const size_t kb = SPLITK ? (size_t)blockIdx.z * K : 0;

  auto stA = [&](int buf, int k0) {
#pragma unroll
    for (int i = 0; i < 4; i++) {
      int c = i * 512 + tid;
      gl_lds16(A + (size_t)(tm + (c >> 3)) * Kfull + kb + k0 + (((c & 7) ^ ((c >> 3) & 7)) * 8),
               S + buf * TOT + (i * 512 + wid * 64) * 8);
    }
  };
  auto stB = [&](int buf, int k0) {
#pragma unroll
    for (int i = 0; i < BI; i++) {
      int c = i * 512 + tid;
      if (c < NT * 8)
        gl_lds16(Bt + (size_t)(tn + (c >> 3)) * Kfull + kb + k0 + (((c & 7) ^ ((c >> 3) & 7)) * 8),
                 S + buf * TOT + 16384 + (i * 512 + wid * 64) * 8);
    }
  };
  auto rdA = [&](int buf, int mp, int ks) -> bf16x8 {
    int r = wr * 64 + mp * 16 + fr;
    int ko = ((ks * 4 + xo) ^ r7) * 8;
    return *reinterpret_cast<const bf16x8*>(&S[buf * TOT + r * 64 + ko]);
  };
  auto rdB = [&](int buf, int np, int ks) -> bf16x8 {
    int r = wc * (NP * 16) + np * 16 + fr;
    int ko = ((ks * 4 + xo) ^ r7) * 8;
    return *reinterpret_cast<const bf16x8*>(&S[buf * TOT + 16384 + r * 64 + ko]);
  };

  f32x4 acc[4][NP];
#pragma unroll
  for (int m = 0; m < 4; m++)
#pragma unroll
    for (int n = 0; n < NP; n++) acc[m][n] = (f32x4)(0.f);
  bf16x8 aF[2][4], bFr[2][NH1 > NH0 ? NH1 : NH0];

  const int nt = K >> 6;
  // prologue: tile0 A+B, tile1 A
  stA(0, 0); stB(0, 0); stA(1, 64);
  asm volatile("s_waitcnt vmcnt(4)" ::: "memory");
  RAW_BAR();

  for (int t = 0; t < nt; t++) {
    const int buf = t & 1;
    const int k1 = (t + 1) << 6, k2 = (t + 2) << 6;
    // ---- ph0: all aF, bF[0..NH0) ----
#pragma unroll
    for (int ks = 0; ks < 2; ks++)
#pragma unroll
      for (int m = 0; m < 4; m++) aF[ks][m] = rdA(buf, m, ks);
#pragma unroll
    for (int ks = 0; ks < 2; ks++)
#pragma unroll
      for (int n = 0; n < NH0; n++) bFr[ks][n] = rdB(buf, n, ks);
    if (t + 1 < nt) stB(buf ^ 1, k1);
    RAW_BAR();
    __builtin_amdgcn_s_setprio(1);
#pragma unroll
    for (int ks = 0; ks < 2; ks++)
#pragma unroll
      for (int m = 0; m < 4; m++)
#pragma unroll
        for (int n = 0; n < NH0; n++)
          acc[m][n] = __builtin_amdgcn_mfma_f32_16x16x32_bf16(aF[ks][m], bFr[ks][n], acc[m][n], 0, 0, 0);
    __builtin_amdgcn_s_setprio(0);
    RAW_BAR();
    // ---- ph1: bF[NH0..NP) ; A-buf fully consumed -> safe to restage ----
#pragma unroll
    for (int ks = 0; ks < 2; ks++)
#pragma unroll
      for (int n = 0; n < NH1; n++) bFr[ks][n] = rdB(buf, NH0 + n, ks);
    if (t + 2 < nt) stA(buf, k2);
    RAW_BAR();
    __builtin_amdgcn_s_setprio(1);
#pragma unroll
    for (int ks = 0; ks < 2; ks++)
#pragma unroll
      for (int m = 0; m < 4; m++)
#pragma unroll
        for (int n = 0; n < NH1; n++)
          acc[m][NH0 + n] = __builtin_amdgcn_mfma_f32_16x16x32_bf16(aF[ks][m], bFr[ks][n], acc[m][NH0 + n], 0, 0, 0);
    __builtin_amdgcn_s_setprio(0);
    if (t + 2 < nt) asm volatile("s_waitcnt vmcnt(4)" ::: "memory");
    else            asm volatile("s_waitcnt vmcnt(0)" ::: "memory");
    RAW_BAR();
  }

  // epilogue
#pragma unroll
  for (int m = 0; m < 4; m++)
#pragma unroll
    for (int n = 0; n < NP; n++) {
      int col = tn + wc * (NP * 16) + n * 16 + fr;
      int rowb = tm + wr * 64 + m * 16 + q4;
      if (SPLITK) {
        float* P = outs.o0 + (size_t)blockIdx.z * M * N;
#pragma unroll
        for (int r = 0; r < 4; r++)
          P[(size_t)(rowb + r) * N + col] = acc[m][n][r];
      } else {
        int c2; float* op; const float* bp;
        if constexpr (NCHUNK == 1) {
          c2 = col; op = outs.o0; bp = outs.b0;
        } else {
          int sel = col >= 3 * DIMX ? 3 : (col >= 2 * DIMX ? 2 : (col >= DIMX ? 1 : 0));
          c2 = col - sel * DIMX;
          op = sel == 0 ? outs.o0 : (sel == 1 ? outs.o1 : (sel == 2 ? outs.o2 : outs.o3));
          bp = sel == 0 ? outs.b0 : (sel == 1 ? outs.b1 : (sel == 2 ? outs.b2 : outs.b3));
        }
        float bv = bp[c2];
#pragma unroll
        for (int r = 0; r < 4; r++) {
          float v = acc[m][n][r] + bv;
          if (DO_GELU) {
            float u = 1.5957691216057308f * (v + 0.044715f * v * v * v);
            v = v / (1.f + __expf(-u));
          }
          if (OUT_BF16)
            outs.ob[(size_t)(rowb + r) * N + col] = f2bf(v);
          else
            op[(size_t)(rowb + r) * DIMX + c2] = v;
        }
      }
    }
}

// ---------------------------------------------------------------------------
// 128x128 kernels for the small GEMMs
template<int NCHUNK>
__global__ void __launch_bounds__(256) gemm_multi(
    const us* __restrict__ A, const us* __restrict__ Bt,
    Outs outs, int M, int N, int K) {
  __shared__ __align__(16) us As[128 * 64];
  __shared__ __align__(16) us Bs[128 * 64];
  const int tid = threadIdx.x;
  const int lane = tid & 63;
  const int w = tid >> 6;
  const int wr = w >> 1, wc = w & 1;
  const int fr = lane & 15;
  const int xo = lane >> 4;
  const int r7 = fr & 7;
  const int q4 = xo * 4;
  int bx = blockIdx.x, by = blockIdx.y;
  xcd_map2(bx, by);
  const int tm = by * 128, tn = bx * 128;

  f32x4 acc[4][4];
#pragma unroll
  for (int m = 0; m < 4; m++)
#pragma unroll
    for (int n = 0; n < 4; n++) acc[m][n] = (f32x4)(0.f);

  int srow[4], skc[4];
#pragma unroll
  for (int j = 0; j < 4; j++) {
    int c = j * 256 + tid;
    srow[j] = c >> 3;
    skc[j] = ((c & 7) ^ ((c >> 3) & 7)) * 8;
  }

  for (int k0 = 0; k0 < K; k0 += 64) {
#pragma unroll
    for (int j = 0; j < 4; j++) {
      gl_lds16(A + (size_t)(tm + srow[j]) * K + k0 + skc[j], As + (j * 256 + w * 64) * 8);
      gl_lds16(Bt + (size_t)(tn + srow[j]) * K + k0 + skc[j], Bs + (j * 256 + w * 64) * 8);
    }
    __syncthreads();
    bf16x8 af[2][4], bfv[2][4];
#pragma unroll
    for (int ks = 0; ks < 2; ks++) {
      const int koff = (((ks * 4 + xo) ^ r7) << 3);
#pragma unroll
      for (int m = 0; m < 4; m++)
        af[ks][m] = *reinterpret_cast<const bf16x8*>(&As[(wr * 64 + m * 16 + fr) * 64 + koff]);
#pragma unroll
      for (int n = 0; n < 4; n++)
        bfv[ks][n] = *reinterpret_cast<const bf16x8*>(&Bs[(wc * 64 + n * 16 + fr) * 64 + koff]);
    }
#pragma unroll
    for (int ks = 0; ks < 2; ks++)
#pragma unroll
      for (int m = 0; m < 4; m++)
#pragma unroll
        for (int n = 0; n < 4; n++)
          acc[m][n] = __builtin_amdgcn_mfma_f32_16x16x32_bf16(af[ks][m], bfv[ks][n], acc[m][n], 0, 0, 0);
    __syncthreads();
  }
#pragma unroll
  for (int m = 0; m < 4; m++) {
#pragma unroll
    for (int n = 0; n < 4; n++) {
      int col = tn + wc * 64 + n * 16 + fr;
      int c2; float* op; const float* bp;
      if constexpr (NCHUNK == 2) {
        int sel = col >= DIMX;
        c2 = col - sel * DIMX;
        op = sel ? outs.o1 : outs.o0;
        bp = sel ? outs.b1 : outs.b0;
      } else {
        c2 = col; op = outs.o0; bp = outs.b0;
      }
      float bv = bp[c2];
#pragma unroll
      for (int r = 0; r < 4; r++) {
        int row = tm + wr * 64 + m * 16 + q4 + r;
        op[(size_t)row * DIMX + c2] = acc[m][n][r] + bv;
      }
    }
  }
}

__global__ void __launch_bounds__(256) gemm_splitk(
    const us* __restrict__ A, const us* __restrict__ Bt,
    float* __restrict__ P, int M, int N, int Kfull, int Ks) {
  __shared__ __align__(16) us As[128 * 64];
  __shared__ __align__(16) us Bs[128 * 64];
  const int tid = threadIdx.x;
  const int lane = tid & 63;
  const int w = tid >> 6;
  const int wr = w >> 1, wc = w & 1;
  const int fr = lane & 15;
  const int xo = lane >> 4;
  const int r7 = fr & 7;
  const int q4 = xo * 4;
  int bx = blockIdx.x, by = blockIdx.y;
  xcd_map2(bx, by);
  const int tm = by * 128, tn = bx * 128;
  const int slice = blockIdx.z;
  const int kbase = slice * Ks;
  float* __restrict__ Pout = P + (size_t)slice * M * N;

  f32x4 acc[4][4];
#pragma unroll
  for (int m = 0; m < 4; m++)
#pragma unroll
    for (int n = 0; n < 4; n++) acc[m][n] = (f32x4)(0.f);

  int srow[4], skc[4];
#pragma unroll
  for (int j = 0; j < 4; j++) {
    int c = j * 256 + tid;
    srow[j] = c >> 3;
    skc[j] = ((c & 7) ^ ((c >> 3) & 7)) * 8;
  }

  for (int k0 = 0; k0 < Ks; k0 += 64) {
#pragma unroll
    for (int j = 0; j < 4; j++) {
      gl_lds16(A + (size_t)(tm + srow[j]) * Kfull + kbase + k0 + skc[j], As + (j * 256 + w * 64) * 8);
      gl_lds16(Bt + (size_t)(tn + srow[j]) * Kfull + kbase + k0 + skc[j], Bs + (j * 256 + w * 64) * 8);
    }
    __syncthreads();
    bf16x8 af[2][4], bfv[2][4];
#pragma unroll
    for (int ks = 0; ks < 2; ks++) {
      const int koff = (((ks * 4 + xo) ^ r7) << 3);
#pragma unroll
      for (int m = 0; m < 4; m++)
        af[ks][m] = *reinterpret_cast<const bf16x8*>(&As[(wr * 64 + m * 16 + fr) * 64 + koff]);
#pragma unroll
      for (int n = 0; n < 4; n++)
        bfv[ks][n] = *reinterpret_cast<const bf16x8*>(&Bs[(wc * 64 + n * 16 + fr) * 64 + koff]);
    }
#pragma unroll
    for (int ks = 0; ks < 2; ks++)
#pragma unroll
      for (int m = 0; m < 4; m++)
#pragma unroll
        for (int n = 0; n < 4; n++)
          acc[m][n] = __builtin_amdgcn_mfma_f32_16x16x32_bf16(af[ks][m], bfv[ks][n], acc[m][n], 0, 0, 0);
    __syncthreads();
  }
#pragma unroll
  for (int m = 0; m < 4; m++)
#pragma unroll
    for (int n = 0; n < 4; n++) {
      int col = tn + wc * 64 + n * 16 + fr;
#pragma unroll
      for (int r = 0; r < 4; r++) {
        int row = tm + wr * 64 + m * 16 + q4 + r;
        Pout[(size_t)row * N + col] = acc[m][n][r];
      }
    }
}

template<int S>
__global__ void __launch_bounds__(256) reduce_kernel(
    const float* __restrict__ P, const float* __restrict__ bias,
    const float* __restrict__ R, const float* __restrict__ g,
    float* __restrict__ O, int total4, int ncol4) {
  const f4* P4 = (const f4*)P;
  const f4* R4 = (const f4*)R;
  f4* O4 = (f4*)O;
  for (int i = blockIdx.x * 256 + threadIdx.x; i < total4; i += gridDim.x * 256) {
    f4 s = P4[i];
#pragma unroll
    for (int sl = 1; sl < S; sl++) s += P4[(size_t)sl * total4 + i];
    int c4 = (i % ncol4) * 4;
    s += *reinterpret_cast<const f4*>(&bias[c4]);
    if (R) {
      if (g) {
        f4 gv = *reinterpret_cast<const f4*>(&g[c4]);
        s = R4[i] + gv * s;
      } else {
        s = R4[i] + s;
      }
    }
    O4[i] = s;
  }
}

// ---------------------------------------------------------------------------
__global__ void __launch_bounds__(256) attn_kernel(
    const float* __restrict__ Q, const float* __restrict__ Kx,
    const float* __restrict__ V, const int* __restrict__ idx,
    const float* __restrict__ G, const float* __restrict__ CB,
    us* __restrict__ Out) {
  __shared__ us q_s[64 * 136];
  __shared__ us k_s[64 * 136];
  __shared__ us vT_s[128 * 72];
  __shared__ us p_s[64 * 72];
  __shared__ float red[4 * 64];
  __shared__ float m_run[64], l_run[64], alpha_s[64];

  const int qb = blockIdx.x;
  const int h = blockIdx.y;
  const int tid = threadIdx.x;
  const int lane = tid & 63;
  const int w = tid >> 6;
  const int fr = lane & 15;
  const int k8 = (lane >> 4) * 8;
  const int q4 = (lane >> 4) * 4;

#pragma unroll
  for (int i = 0; i < 8; i++) {
    int s = tid + 256 * i;
    int row = s >> 5, cq = (s & 31) * 4;
    f4 v = *reinterpret_cast<const f4*>(&Q[(size_t)(qb * 64 + row) * DIMX + h * HDIM + cq]);
    us4 hh; hh[0] = f2bf(v[0]); hh[1] = f2bf(v[1]); hh[2] = f2bf(v[2]); hh[3] = f2bf(v[3]);
    *reinterpret_cast<us4*>(&q_s[row * 136 + cq]) = hh;
  }
  if (tid < 64) { m_run[tid] = -1e30f; l_run[tid] = 0.f; }

  f32x4 acc_o[4][2];
#pragma unroll
  for (int m = 0; m < 4; m++)
#pragma unroll
    for (int n = 0; n < 2; n++) acc_o[m][n] = (f32x4)(0.f);

  for (int ib = 0; ib < 8; ib++) {
    int blk = idx ? idx[(h * NBLK + qb) * 8 + ib] : ib;
    __syncthreads();
#pragma unroll
    for (int i = 0; i < 8; i++) {
      int s = tid + 256 * i;
      int row = s >> 5, cq = (s & 31) * 4;
      f4 v = *reinterpret_cast<const f4*>(&Kx[(size_t)(blk * 64 + row) * DIMX + h * HDIM + cq]);
      us4 hh; hh[0] = f2bf(v[0]); hh[1] = f2bf(v[1]); hh[2] = f2bf(v[2]); hh[3] = f2bf(v[3]);
      *reinterpret_cast<us4*>(&k_s[row * 136 + cq]) = hh;
    }
    {
      int d = tid & 127, th = (tid >> 7) * 32;
#pragma unroll
      for (int j = 0; j < 4; j++) {
        us8 hv;
#pragma unroll
        for (int qq = 0; qq < 8; qq++)
          hv[qq] = f2bf(V[(size_t)(blk * 64 + th + j * 8 + qq) * DIMX + h * HDIM + d]);
        *reinterpret_cast<us8*>(&vT_s[d * 72 + th + j * 8]) = hv;
      }
    }
    __syncthreads();
    f32x4 accs[4];
#pragma unroll
    for (int m = 0; m < 4; m++) accs[m] = (f32x4)(0.f);
#pragma unroll
    for (int kk = 0; kk < 128; kk += 32) {
      bf16x8 bfr = *reinterpret_cast<const bf16x8*>(&k_s[(w * 16 + fr) * 136 + kk + k8]);
#pragma unroll
      for (int m = 0; m < 4; m++) {
        bf16x8 afr = *reinterpret_cast<const bf16x8*>(&q_s[(m * 16 + fr) * 136 + kk + k8]);
        accs[m] = __builtin_amdgcn_mfma_f32_16x16x32_bf16(afr, bfr, accs[m], 0, 0, 0);
      }
    }
#pragma unroll
    for (int m = 0; m < 4; m++) {
#pragma unroll
      for (int r = 0; r < 4; r++) {
        accs[m][r] *= SCALE_ATT;
        float v = accs[m][r];
        for (int o = 1; o < 16; o <<= 1) v = fmaxf(v, __shfl_xor(v, o, 64));
        if (fr == 0) red[w * 64 + m * 16 + q4 + r] = v;
      }
    }
    __syncthreads();
    if (tid < 64) {
      float bm = fmaxf(fmaxf(red[tid], red[64 + tid]), fmaxf(red[128 + tid], red[192 + tid]));
      float mo = m_run[tid];
      float mn = fmaxf(mo, bm);
      float al = __expf(mo - mn);
      alpha_s[tid] = al;
      m_run[tid] = mn;
      l_run[tid] *= al;
    }
    __syncthreads();
#pragma unroll
    for (int m = 0; m < 4; m++) {
#pragma unroll
      for (int r = 0; r < 4; r++) {
        int row = m * 16 + q4 + r;
        float p = __expf(accs[m][r] - m_run[row]);
        p_s[row * 72 + w * 16 + fr] = f2bf(p);
        float sv = p;
        for (int o = 1; o < 16; o <<= 1) sv += __shfl_xor(sv, o, 64);
        if (fr == 0) red[w * 64 + row] = sv;
      }
    }
#pragma unroll
    for (int m = 0; m < 4; m++) {
      float a0 = alpha_s[m * 16 + q4 + 0];
      float a1 = alpha_s[m * 16 + q4 + 1];
      float a2 = alpha_s[m * 16 + q4 + 2];
      float a3 = alpha_s[m * 16 + q4 + 3];
#pragma unroll
      for (int n = 0; n < 2; n++) {
        acc_o[m][n][0] *= a0; acc_o[m][n][1] *= a1;
        acc_o[m][n][2] *= a2; acc_o[m][n][3] *= a3;
      }
    }
    __syncthreads();
    if (tid < 64) l_run[tid] += red[tid] + red[64 + tid] + red[128 + tid] + red[192 + tid];
#pragma unroll
    for (int kk = 0; kk < 64; kk += 32) {
      bf16x8 pa[4];
#pragma unroll
      for (int m = 0; m < 4; m++)
        pa[m] = *reinterpret_cast<const bf16x8*>(&p_s[(m * 16 + fr) * 72 + kk + k8]);
#pragma unroll
      for (int n = 0; n < 2; n++) {
        bf16x8 vb = *reinterpret_cast<const bf16x8*>(&vT_s[(w * 32 + n * 16 + fr) * 72 + kk + k8]);
#pragma unroll
        for (int m = 0; m < 4; m++)
          acc_o[m][n] = __builtin_amdgcn_mfma_f32_16x16x32_bf16(pa[m], vb, acc_o[m][n], 0, 0, 0);
      }
    }
  }
  __syncthreads();
#pragma unroll
  for (int m = 0; m < 4; m++) {
#pragma unroll
    for (int n = 0; n < 2; n++) {
#pragma unroll
      for (int r = 0; r < 4; r++) {
        int row = m * 16 + q4 + r;
        int srow = qb * 64 + row;
        int d = w * 32 + n * 16 + fr;
        float o = acc_o[m][n][r] / l_run[row];
        size_t oi = (size_t)srow * DIMX + h * HDIM + d;
        if (G) o += G[oi] * CB[(size_t)qb * DIMX + h * HDIM + d];
        Out[oi] = f2bf(o);
      }
    }
  }
}

// ---------------------------------------------------------------------------
__global__ void __launch_bounds__(128) block_mean_kernel(const float* __restrict__ X,
                                                         float* __restrict__ Outc) {
  int n = blockIdx.x, h = blockIdx.y, d = threadIdx.x;
  float s = 0.f;
  for (int t = 0; t < 64; t++) s += X[(size_t)(n * 64 + t) * DIMX + h * HDIM + d];
  Outc[(n * NHEAD + h) * HDIM + d] = s * (1.f / 64.f);
}

__global__ void __launch_bounds__(256) coarse_attn_kernel(const float* __restrict__ qc,
                                                          const float* __restrict__ kc,
                                                          float* __restrict__ pc,
                                                          int* __restrict__ idxout) {
  int h = blockIdx.x, t = threadIdx.x;
  __shared__ float sm[32][32];
  for (int p = t; p < 1024; p += 256) {
    int n = p >> 5, m = p & 31;
    float dot = 0.f;
    for (int d = 0; d < HDIM; d++)
      dot += qc[n * DIMX + h * HDIM + d] * kc[m * DIMX + h * HDIM + d];
    sm[n][m] = dot * SCALE_ATT;
  }
  __syncthreads();
  if (t < 32) {
    int n = t;
    float mx = -1e30f;
#pragma unroll
    for (int m = 0; m < 32; m++) mx = fmaxf(mx, sm[n][m]);
    float pv[32]; float ssum = 0.f;
#pragma unroll
    for (int m = 0; m < 32; m++) { pv[m] = __expf(sm[n][m] - mx); ssum += pv[m]; }
    float inv = 1.f / ssum;
#pragma unroll
    for (int m = 0; m < 32; m++) { pv[m] *= inv; pc[(h * 32 + n) * 32 + m] = pv[m]; }
    unsigned chosen = 0;
    for (int i = 0; i < 8; i++) {
      float best = -1.f; int bi = 0;
#pragma unroll
      for (int m = 0; m < 32; m++)
        if (!((chosen >> m) & 1u) && pv[m] > best) { best = pv[m]; bi = m; }
      chosen |= 1u << bi;
      idxout[(h * 32 + n) * 8 + i] = bi;
    }
  }
}

__global__ void __launch_bounds__(128) coarse_ctx_kernel(const float* __restrict__ pc,
                                                         const float* __restrict__ vc,
                                                         float* __restrict__ cb) {
  int n = blockIdx.x, h = blockIdx.y, d = threadIdx.x;
  float s = 0.f;
  for (int m = 0; m < 32; m++)
    s += pc[(h * 32 + n) * 32 + m] * vc[(m * NHEAD + h) * HDIM + d];
  cb[(n * NHEAD + h) * HDIM + d] = s;
}

// ---------------------------------------------------------------------------
extern "C" void kernel_launch(void* const* d_in, const int* in_sizes, int n_in,
                              void* d_out, int out_size, void* d_ws, size_t ws_size,
                              hipStream_t stream) {
  (void)in_sizes; (void)n_in; (void)out_size; (void)ws_size;
  const float* hidden = (const float*)d_in[0];
  const float* enc    = (const float*)d_in[1];
  const float* temb   = (const float*)d_in[2];
  const float* cosT   = (const float*)d_in[3];
  const float* sinT   = (const float*)d_in[4];
  const float* sst    = (const float*)d_in[5];
  const float* Wq = (const float*)d_in[6];   const float* bq = (const float*)d_in[7];
  const float* Wk = (const float*)d_in[8];   const float* bk = (const float*)d_in[9];
  const float* Wv = (const float*)d_in[10];  const float* bv = (const float*)d_in[11];
  const float* Wg = (const float*)d_in[12];  const float* bg = (const float*)d_in[13];
  const float* Wo = (const float*)d_in[14];  const float* bo = (const float*)d_in[15];
  const float* qnw = (const float*)d_in[16]; const float* knw = (const float*)d_in[17];
  const float* saw = (const float*)d_in[18]; const float* sab = (const float*)d_in[19];
  const float* cWq = (const float*)d_in[20]; const float* cbq = (const float*)d_in[21];
  const float* cWk = (const float*)d_in[22]; const float* cbk = (const float*)d_in[23];
  const float* cWv = (const float*)d_in[24]; const float* cbv = (const float*)d_in[25];
  const float* cWo = (const float*)d_in[26]; const float* cbo = (const float*)d_in[27];
  const float* cqnw = (const float*)d_in[28]; const float* cknw = (const float*)d_in[29];
  const float* W1 = (const float*)d_in[30];  const float* b1 = (const float*)d_in[31];
  const float* W2 = (const float*)d_in[32];  const float* b2 = (const float*)d_in[33];

  char* ws = (char*)d_ws;
  size_t off = 0;
  auto alloc = [&](size_t bytes) -> void* {
    void* p = ws + off;
    off += (bytes + 255) & ~(size_t)255;
    return p;
  };
  const size_t SD = (size_t)SEQ * DIMX * 4;
  const size_t SDh = (size_t)SEQ * DIMX * 2;
  const size_t WSQ = (size_t)DIMX * DIMX * 2;
  float* e     = (float*)alloc(6 * DIMX * 4);
  us* normb    = (us*)alloc(SDh);
  float* qb_   = (float*)alloc(SD);
  float* kb_   = (float*)alloc(SD);
  float* vb_   = (float*)alloc(SD);
  float* gb_   = (float*)alloc(SD);
  float* qc    = (float*)alloc((size_t)NBLK * DIMX * 4);
  float* kc    = (float*)alloc((size_t)NBLK * DIMX * 4);
  float* vc    = (float*)alloc((size_t)NBLK * DIMX * 4);
  float* pc    = (float*)alloc(NHEAD * 32 * 32 * 4);
  int*   idx   = (int*)alloc(NHEAD * 32 * 8 * 4);
  float* cb    = (float*)alloc((size_t)NBLK * DIMX * 4);
  us* mixb     = (us*)alloc(SDh);
  float* res   = (float*)alloc(SD);
  us* encb     = (us*)alloc((size_t)L2X * DIMX * 2);
  us* wpack    = (us*)alloc(9 * WSQ);
  us* W1t      = (us*)alloc((size_t)DIMX * FFNX * 2);
  us* W2t      = (us*)alloc((size_t)FFNX * DIMX * 2);
  // aliases (lifetimes disjoint):
  us* ffh    = (us*)qb_;        // 36.7MB over qb_+kb_+vb_ (37.75MB)
  us* crossb = (us*)gb_;        // 6.3MB <= 12.6MB
  float* part2 = (float*)qb_;   // 2x12.58MB over qb_+kb_
  float* part4 = (float*)wpack; // 4x12.58MB over wpack(42.5MB); dead at FFN2
  float* outf  = (float*)d_out;
  const size_t SL = (size_t)DIMX * DIMX;
  us* Wot  = wpack + 4 * SL;
  us* cWqt = wpack + 5 * SL;
  us* cKVt = wpack + 6 * SL;
  us* cWot = wpack + 8 * SL;

  // ---- pack ----
  P9 p9; p9.s[0]=Wq; p9.s[1]=Wk; p9.s[2]=Wv; p9.s[3]=Wg; p9.s[4]=Wo;
  p9.s[5]=cWq; p9.s[6]=cWk; p9.s[7]=cWv; p9.s[8]=cWo;
  pack64_9<<<dim3(DIMX / 64, DIMX / 64, 9), 256, 0, stream>>>(p9, wpack);
  pack64_g<<<dim3(FFNX / 64, DIMX / 64), 256, 0, stream>>>(W1, W1t, DIMX, FFNX);
  pack64_g<<<dim3(DIMX / 64, FFNX / 64), 256, 0, stream>>>(W2, W2t, FFNX, DIMX);
  pack_cvt_kernel<<<(L2X * DIMX / 4 + 255) / 256, 256, 0, stream>>>(enc, encb, L2X * DIMX / 4);
  prep_e_kernel<<<36, 256, 0, stream>>>(sst, temb, e);

  // ---- self-attention branch ----
  ln_affine_kernel<<<SEQ, 256, 0, stream>>>(hidden, e + DIMX, e, 1, normb);
  Outs qkvgo = {qb_, kb_, vb_, gb_, bq, bk, bv, bg, nullptr};
  gemm2ph<6, 4, 0, 0, 0><<<dim3(32, 8), 512, 0, stream>>>(normb, wpack, qkvgo, SEQ, 4 * DIMX, DIMX, DIMX);
  rms_rope_kernel<<<SEQ, 256, 0, stream>>>(qb_, qnw, cosT, sinT, 1);
  rms_rope_kernel<<<SEQ, 256, 0, stream>>>(kb_, knw, cosT, sinT, 1);
  dim3 gbm(NBLK, NHEAD);
  block_mean_kernel<<<gbm, 128, 0, stream>>>(qb_, qc);
  block_mean_kernel<<<gbm, 128, 0, stream>>>(kb_, kc);
  block_mean_kernel<<<gbm, 128, 0, stream>>>(vb_, vc);
  coarse_attn_kernel<<<NHEAD, 256, 0, stream>>>(qc, kc, pc, idx);
  coarse_ctx_kernel<<<gbm, 128, 0, stream>>>(pc, vc, cb);
  attn_kernel<<<dim3(NBLK, NHEAD), 256, 0, stream>>>(qb_, kb_, vb_, idx, gb_, cb, mixb);
  gemm_splitk<<<dim3(12, 16, 2), 256, 0, stream>>>(mixb, Wot, part2, SEQ, DIMX, DIMX, 768);
  reduce_kernel<2><<<1024, 256, 0, stream>>>(part2, bo, hidden, e + 2 * DIMX, res,
                                             SEQ * DIMX / 4, DIMX / 4);
  // ---- cross attention ----
  ln_affine_kernel<<<SEQ, 256, 0, stream>>>(res, saw, sab, 0, normb);
  gemm_splitk<<<dim3(12, 16, 2), 256, 0, stream>>>(normb, cWqt, part2, SEQ, DIMX, DIMX, 768);
  reduce_kernel<2><<<1024, 256, 0, stream>>>(part2, cbq, nullptr, nullptr, qb_,
                                             SEQ * DIMX / 4, DIMX / 4);
  rms_rope_kernel<<<SEQ, 256, 0, stream>>>(qb_, cqnw, cosT, sinT, 0);
  Outs ckvo = {kb_, vb_, nullptr, nullptr, cbk, cbv, nullptr, nullptr, nullptr};
  gemm_multi<2><<<dim3(24, 4), 256, 0, stream>>>(encb, cKVt, ckvo, L2X, 2 * DIMX, DIMX);
  rms_rope_kernel<<<L2X, 256, 0, stream>>>(kb_, cknw, cosT, sinT, 0);
  attn_kernel<<<dim3(NBLK, NHEAD), 256, 0, stream>>>(qb_, kb_, vb_, nullptr, nullptr, nullptr, crossb);
  gemm_splitk<<<dim3(12, 16, 2), 256, 0, stream>>>(crossb, cWot, part2, SEQ, DIMX, DIMX, 768);
  reduce_kernel<2><<<1024, 256, 0, stream>>>(part2, cbo, res, nullptr, outf,
                                             SEQ * DIMX / 4, DIMX / 4);
  // ---- FFN ----
  ln_affine_kernel<<<SEQ, 256, 0, stream>>>(outf, e + 4 * DIMX, e + 3 * DIMX, 1, normb);
  Outs f1o = {nullptr, nullptr, nullptr, nullptr, b1, nullptr, nullptr, nullptr, ffh};
  gemm2ph<5, 1, 1, 1, 0><<<dim3(56, 8), 512, 0, stream>>>(normb, W1t, f1o, SEQ, FFNX, DIMX, DIMX);
  Outs f2o = {part4, nullptr, nullptr, nullptr, nullptr, nullptr, nullptr, nullptr, nullptr};
  gemm2ph<6, 1, 0, 0, 1><<<dim3(8, 8, 4), 512, 0, stream>>>(ffh, W2t, f2o, SEQ, DIMX, 2240, FFNX);
  reduce_kernel<4><<<1024, 256, 0, stream>>>(part4, b2, outf, e + 5 * DIMX, outf,
                                             SEQ * DIMX / 4, DIMX / 4);
}